// Round 1
// baseline (3859.562 us; speedup 1.0000x reference)
//
#include <hip/hip_runtime.h>
#include <math.h>

// Problem constants
constexpr int CB = 4, CS = 512, CD = 768, CFF = 3072, CH = 12, CHD = 64;
constexpr int CT = CB * CS;            // 2048 tokens
constexpr int PH = 4, KD = 512, NK = 128, KNN = 32, HALF = 256;

// ---------------------------------------------------------------- GEMM ----
// C[M,N] = A[M,K] @ W[K,N] + bias ; act==1 -> exact GELU
constexpr int BM = 128, BN = 128, BK = 16;

__global__ __launch_bounds__(256) void gemm_bias(const float* __restrict__ A,
    const float* __restrict__ W, const float* __restrict__ bias,
    float* __restrict__ C, int M, int N, int K, int act)
{
    __shared__ float As[BK][BM + 1];
    __shared__ float Bs[BK][BN + 1];
    const int tid = threadIdx.x;
    const int tx = tid & 15, ty = tid >> 4;
    const int bx = blockIdx.x, by = blockIdx.y;
    float acc[8][8];
#pragma unroll
    for (int i = 0; i < 8; i++)
#pragma unroll
        for (int j = 0; j < 8; j++) acc[i][j] = 0.f;

    for (int k0 = 0; k0 < K; k0 += BK) {
#pragma unroll
        for (int i = 0; i < 8; i++) {            // A tile 128x16 -> As[k][m]
            int idx = tid + i * 256;
            int r = idx >> 4, c = idx & 15;
            As[c][r] = A[(size_t)(by * BM + r) * K + (k0 + c)];
        }
#pragma unroll
        for (int i = 0; i < 8; i++) {            // B tile 16x128
            int idx = tid + i * 256;
            int r = idx >> 7, c = idx & 127;
            Bs[r][c] = W[(size_t)(k0 + r) * N + (bx * BN + c)];
        }
        __syncthreads();
#pragma unroll
        for (int kk = 0; kk < BK; kk++) {
            float a[8], b[8];
#pragma unroll
            for (int i = 0; i < 8; i++) a[i] = As[kk][ty * 8 + i];
#pragma unroll
            for (int j = 0; j < 8; j++) b[j] = Bs[kk][tx * 8 + j];
#pragma unroll
            for (int i = 0; i < 8; i++)
#pragma unroll
                for (int j = 0; j < 8; j++) acc[i][j] = fmaf(a[i], b[j], acc[i][j]);
        }
        __syncthreads();
    }
    const int row0 = by * BM + ty * 8, col0 = bx * BN + tx * 8;
#pragma unroll
    for (int i = 0; i < 8; i++) {
#pragma unroll
        for (int j = 0; j < 8; j++) {
            float v = acc[i][j] + bias[col0 + j];
            if (act == 1) v = 0.5f * v * (1.0f + erff(v * 0.70710678118654752f));
            C[(size_t)(row0 + i) * N + (col0 + j)] = v;
        }
    }
}

// ----------------------------------------------------------- attention ----
// one block per (b,h,s): scores over 512 keys, softmax, ctx = a @ v
__global__ __launch_bounds__(256) void attn_kernel(const float* __restrict__ q,
    const float* __restrict__ k, const float* __restrict__ v,
    float* __restrict__ ctx)
{
    const int s = blockIdx.x, h = blockIdx.y, b = blockIdx.z;
    const int t0 = b * CS;
    const int tq = t0 + s;
    const int tid = threadIdx.x;
    __shared__ float qs[CHD];
    __shared__ float sc[CS];
    __shared__ float red[256];

    if (tid < CHD) qs[tid] = q[(size_t)tq * CD + h * CHD + tid];
    __syncthreads();

    for (int t = tid; t < CS; t += 256) {
        const float* kr = &k[(size_t)(t0 + t) * CD + h * CHD];
        float a = 0.f;
#pragma unroll
        for (int d = 0; d < CHD; d++) a = fmaf(qs[d], kr[d], a);
        sc[t] = a * 0.125f;   // 1/sqrt(64)
    }
    __syncthreads();

    float m = -1e30f;
    for (int t = tid; t < CS; t += 256) m = fmaxf(m, sc[t]);
    red[tid] = m; __syncthreads();
    for (int o = 128; o > 0; o >>= 1) { if (tid < o) red[tid] = fmaxf(red[tid], red[tid + o]); __syncthreads(); }
    m = red[0]; __syncthreads();

    float sum = 0.f;
    for (int t = tid; t < CS; t += 256) { float e = expf(sc[t] - m); sc[t] = e; sum += e; }
    red[tid] = sum; __syncthreads();
    for (int o = 128; o > 0; o >>= 1) { if (tid < o) red[tid] += red[tid + o]; __syncthreads(); }
    const float inv = 1.0f / red[0];
    __syncthreads();

    // ctx: 64 dims x 4 groups of 128 keys
    const int d = tid & 63, g = tid >> 6;
    float a = 0.f;
    for (int t = g * 128; t < (g + 1) * 128; ++t)
        a = fmaf(sc[t], v[(size_t)(t0 + t) * CD + h * CHD + d], a);
    red[tid] = a; __syncthreads();
    if (tid < 64) {
        float r = red[tid] + red[tid + 64] + red[tid + 128] + red[tid + 192];
        ctx[(size_t)tq * CD + h * CHD + tid] = r * inv;
    }
}

// ----------------------------------------------------------- layernorm ----
// out[t] = LN(a[t] (+ b2[t]) (+ c[t])) * g + bb   (var is biased /D, EPS=1e-12)
__global__ __launch_bounds__(256) void ln_kernel(float* __restrict__ out,
    const float* __restrict__ a, const float* __restrict__ b2,
    const float* __restrict__ c, const float* __restrict__ g,
    const float* __restrict__ bb)
{
    const int t = blockIdx.x, tid = threadIdx.x;
    __shared__ float buf[CD];
    __shared__ float red[256];
    float l = 0.f;
    for (int d = tid; d < CD; d += 256) {
        float v = a[(size_t)t * CD + d];
        if (b2) v += b2[(size_t)t * CD + d];
        if (c)  v += c[(size_t)t * CD + d];
        buf[d] = v; l += v;
    }
    red[tid] = l; __syncthreads();
    for (int o = 128; o > 0; o >>= 1) { if (tid < o) red[tid] += red[tid + o]; __syncthreads(); }
    const float mean = red[0] * (1.0f / CD); __syncthreads();
    float l2 = 0.f;
    for (int d = tid; d < CD; d += 256) { float dd = buf[d] - mean; l2 += dd * dd; }
    red[tid] = l2; __syncthreads();
    for (int o = 128; o > 0; o >>= 1) { if (tid < o) red[tid] += red[tid + o]; __syncthreads(); }
    const float inv = rsqrtf(red[0] * (1.0f / CD) + 1e-12f);
    for (int d = tid; d < CD; d += 256)
        out[(size_t)t * CD + d] = (buf[d] - mean) * inv * g[d] + bb[d];
}

// ---------------------------------------------------------- PKM scores ----
// block per (t,h): s1[n]=q1.keys[h,0,n], s2[n]=q2.keys[h,1,n]
__global__ __launch_bounds__(256) void pkm_score_kernel(const float* __restrict__ pq,
    const float* __restrict__ keys, float* __restrict__ sc)
{
    const int t = blockIdx.x >> 2, h = blockIdx.x & 3;
    const int tid = threadIdx.x;
    __shared__ float qb[KD];
    for (int i = tid; i < KD; i += 256) qb[i] = pq[(size_t)t * (PH * KD) + h * KD + i];
    __syncthreads();
    const int half = tid >> 7, n = tid & 127;
    const float* kr = &keys[(((size_t)h * 2 + half) * NK + n) * HALF];
    const float* qh = &qb[half * HALF];
    float a = 0.f;
#pragma unroll 8
    for (int d = 0; d < HALF; d++) a = fmaf(qh[d], kr[d], a);
    sc[((size_t)t * PH + h) * (2 * NK) + half * NK + n] = a;
}

// ------------------------------------------------------- top-k stage 1 ----
// one thread per (t,h,half): top-32 of 128, sorted desc, stable (low idx first)
__global__ void topk1_kernel(const float* __restrict__ sc,
    float* __restrict__ tv, int* __restrict__ ti)
{
    const int gid = blockIdx.x * blockDim.x + threadIdx.x;
    if (gid >= CT * PH * 2) return;
    const float* s = &sc[(size_t)gid * NK];
    float val[KNN]; int idx[KNN]; int cnt = 0;
    for (int n = 0; n < NK; n++) {
        float v = s[n];
        if (cnt < KNN) {
            int p = cnt++;
            while (p > 0 && val[p - 1] < v) { val[p] = val[p - 1]; idx[p] = idx[p - 1]; p--; }
            val[p] = v; idx[p] = n;
        } else if (v > val[KNN - 1]) {
            int p = KNN - 1;
            while (p > 0 && val[p - 1] < v) { val[p] = val[p - 1]; idx[p] = idx[p - 1]; p--; }
            val[p] = v; idx[p] = n;
        }
    }
    for (int i = 0; i < KNN; i++) { tv[(size_t)gid * KNN + i] = val[i]; ti[(size_t)gid * KNN + i] = idx[i]; }
}

// ----------------------------------------- cartesian top-k + softmax ------
// one thread per (t,h): top-32 of 32x32 sums, then softmax weights + indices
__global__ void cart_topk_kernel(const float* __restrict__ tv, const int* __restrict__ ti,
    float* __restrict__ w, int* __restrict__ ind)
{
    const int gid = blockIdx.x * blockDim.x + threadIdx.x;
    if (gid >= CT * PH) return;
    const float* v1 = &tv[(size_t)gid * 2 * KNN];
    const float* v2 = v1 + KNN;
    const int* i1 = &ti[(size_t)gid * 2 * KNN];
    const int* i2 = i1 + KNN;
    float val[KNN]; int idx[KNN]; int cnt = 0;
    for (int i = 0; i < KNN; i++) {
        float a = v1[i];
        if (cnt == KNN && a + v2[0] <= val[KNN - 1]) break;   // v1 desc
        for (int j = 0; j < KNN; j++) {
            float c = a + v2[j];
            if (cnt < KNN) {
                int p = cnt++;
                while (p > 0 && val[p - 1] < c) { val[p] = val[p - 1]; idx[p] = idx[p - 1]; p--; }
                val[p] = c; idx[p] = i * KNN + j;
            } else if (c > val[KNN - 1]) {
                int p = KNN - 1;
                while (p > 0 && val[p - 1] < c) { val[p] = val[p - 1]; idx[p] = idx[p - 1]; p--; }
                val[p] = c; idx[p] = i * KNN + j;
            } else break;                                      // v2 desc
        }
    }
    const float mx = val[0];
    float e[KNN], ssum = 0.f;
    for (int i = 0; i < KNN; i++) { e[i] = expf(val[i] - mx); ssum += e[i]; }
    const float invs = 1.0f / ssum;
    for (int i = 0; i < KNN; i++) {
        int ii = idx[i] / KNN, jj = idx[i] % KNN;
        w[(size_t)gid * KNN + i] = e[i] * invs;
        ind[(size_t)gid * KNN + i] = i1[ii] * NK + i2[jj];
    }
}

// --------------------------------------------------------- PKM gather -----
// block per token: out[t] = sum over 4 heads x 32 picks of w * values[ind]
__global__ __launch_bounds__(256) void pkm_gather_kernel(const float* __restrict__ w,
    const int* __restrict__ ind, const float* __restrict__ values,
    float* __restrict__ out)
{
    const int t = blockIdx.x, tid = threadIdx.x;
    __shared__ float ws[PH * KNN];
    __shared__ int   is[PH * KNN];
    if (tid < PH * KNN) {
        ws[tid] = w[(size_t)t * PH * KNN + tid];
        is[tid] = ind[(size_t)t * PH * KNN + tid];
    }
    __syncthreads();
    float acc0 = 0.f, acc1 = 0.f, acc2 = 0.f;
    for (int i = 0; i < PH * KNN; i++) {
        const float* vr = &values[(size_t)is[i] * CD];
        const float wi = ws[i];
        acc0 = fmaf(wi, vr[tid], acc0);
        acc1 = fmaf(wi, vr[tid + 256], acc1);
        acc2 = fmaf(wi, vr[tid + 512], acc2);
    }
    out[(size_t)t * CD + tid] = acc0;
    out[(size_t)t * CD + tid + 256] = acc1;
    out[(size_t)t * CD + tid + 512] = acc2;
}

// ------------------------------------------------------------- launch -----
extern "C" void kernel_launch(void* const* d_in, const int* in_sizes, int n_in,
                              void* d_out, int out_size, void* d_ws, size_t ws_size,
                              hipStream_t stream)
{
    const float* x      = (const float*)d_in[0];
    const float* Wq     = (const float*)d_in[1];
    const float* bq     = (const float*)d_in[2];
    const float* Wk     = (const float*)d_in[3];
    const float* bk     = (const float*)d_in[4];
    const float* Wv     = (const float*)d_in[5];
    const float* bv     = (const float*)d_in[6];
    const float* Wo     = (const float*)d_in[7];
    const float* bo     = (const float*)d_in[8];
    const float* ln1_g  = (const float*)d_in[9];
    const float* ln1_b  = (const float*)d_in[10];
    const float* Wi     = (const float*)d_in[11];
    const float* bi     = (const float*)d_in[12];
    const float* Wd     = (const float*)d_in[13];
    const float* bd     = (const float*)d_in[14];
    const float* ln2_g  = (const float*)d_in[15];
    const float* ln2_b  = (const float*)d_in[16];
    const float* Wpq    = (const float*)d_in[17];
    const float* bpq    = (const float*)d_in[18];
    const float* keys   = (const float*)d_in[19];
    const float* values = (const float*)d_in[20];

    float* ws = (float*)d_ws;
    // workspace layout (floats); reuse: qkv->pq, ctx->pkm_out, tmp->dense
    float* qb   = ws;                    // 2048*768
    float* kb   = ws + 1572864;          // 2048*768
    float* vb   = ws + 3145728;          // 2048*768
    float* pq   = ws;                    // 2048*2048 (after attention, qkv dead)
    float* ctx  = ws + 4718592;          // 2048*768 ; later pkm_out
    float* tmp  = ws + 6291456;          // 2048*768 ; later dense
    float* attn = ws + 7864320;          // 2048*768
    float* inter= ws + 9437184;          // 2048*3072
    float* sbuf = ws + 15728640;         // 2048*4*256
    float* tv   = ws + 17825792;         // 2048*4*2*32
    int*   ti   = (int*)(ws + 18350080); // 2048*4*2*32
    float* wgt  = ws + 18874368;         // 2048*4*32
    int*   ind  = (int*)(ws + 19136512); // 2048*4*32

    const dim3 blk(256);

    // QKV projections
    gemm_bias<<<dim3(CD / BN, CT / BM), blk, 0, stream>>>(x, Wq, bq, qb, CT, CD, CD, 0);
    gemm_bias<<<dim3(CD / BN, CT / BM), blk, 0, stream>>>(x, Wk, bk, kb, CT, CD, CD, 0);
    gemm_bias<<<dim3(CD / BN, CT / BM), blk, 0, stream>>>(x, Wv, bv, vb, CT, CD, CD, 0);

    // attention
    attn_kernel<<<dim3(CS, CH, CB), blk, 0, stream>>>(qb, kb, vb, ctx);

    // output proj + LN1 (residual x)
    gemm_bias<<<dim3(CD / BN, CT / BM), blk, 0, stream>>>(ctx, Wo, bo, tmp, CT, CD, CD, 0);
    ln_kernel<<<CT, blk, 0, stream>>>(attn, tmp, x, nullptr, ln1_g, ln1_b);

    // FFN up (fused exact GELU)
    gemm_bias<<<dim3(CFF / BN, CT / BM), blk, 0, stream>>>(attn, Wi, bi, inter, CT, CFF, CD, 1);
    // FFN down -> tmp (dense)
    gemm_bias<<<dim3(CD / BN, CT / BM), blk, 0, stream>>>(inter, Wd, bd, tmp, CT, CD, CFF, 0);
    // PKM query proj -> pq (reuses qkv region)
    gemm_bias<<<dim3((PH * KD) / BN, CT / BM), blk, 0, stream>>>(inter, Wpq, bpq, pq, CT, PH * KD, CFF, 0);

    // PKM scores, two-stage top-k, gather
    pkm_score_kernel<<<CT * PH, blk, 0, stream>>>(pq, keys, sbuf);
    topk1_kernel<<<(CT * PH * 2 + 255) / 256, blk, 0, stream>>>(sbuf, tv, ti);
    cart_topk_kernel<<<(CT * PH + 255) / 256, blk, 0, stream>>>(tv, ti, wgt, ind);
    pkm_gather_kernel<<<CT, blk, 0, stream>>>(wgt, ind, values, ctx);

    // final LN over dense + pkm + attn_out
    ln_kernel<<<CT, blk, 0, stream>>>((float*)d_out, tmp, ctx, attn, ln2_g, ln2_b);
}

// Round 2
// 1333.887 us; speedup vs baseline: 2.8935x; 2.8935x over previous
//
#include <hip/hip_runtime.h>
#include <math.h>

// Problem constants
constexpr int CB = 4, CS = 512, CD = 768, CFF = 3072, CH = 12, CHD = 64;
constexpr int CT = CB * CS;            // 2048 tokens
constexpr int PH = 4, KD = 512, NK = 128, KNN = 32, HALF = 256;

typedef __attribute__((ext_vector_type(8))) short short8_t;   // 8 bf16 (4 VGPRs)
typedef __attribute__((ext_vector_type(4))) float f32x4;      // MFMA accumulator

__device__ __forceinline__ unsigned short f2bf(float f) {
    unsigned int u = __float_as_uint(f);
    unsigned int r = (u + 0x7FFF + ((u >> 16) & 1)) >> 16;    // RNE
    return (unsigned short)r;
}

// ------------------------------------------------------- weight transpose --
// W fp32 [K][N] -> WT bf16 [N][K]
__global__ __launch_bounds__(256) void transpose_w(const float* __restrict__ W,
    unsigned short* __restrict__ WT, int K, int N)
{
    __shared__ unsigned short ts[32][33];
    const int n0 = blockIdx.x * 32, k0 = blockIdx.y * 32;
    const int c = threadIdx.x & 31, rr = threadIdx.x >> 5;
#pragma unroll
    for (int i = 0; i < 4; i++) {
        int r = rr + i * 8;
        ts[c][r] = f2bf(W[(size_t)(k0 + r) * N + n0 + c]);   // ts[a][b]=W[k0+b][n0+a]
    }
    __syncthreads();
#pragma unroll
    for (int i = 0; i < 4; i++) {
        int rw = rr + i * 8;
        WT[(size_t)(n0 + rw) * K + k0 + c] = ts[rw][c];
    }
}

// ------------------------------------------------------------ fp32->bf16 --
__global__ __launch_bounds__(256) void cvt_bf16_kernel(const float* __restrict__ in,
    unsigned short* __restrict__ out, int n)
{
    for (int i = blockIdx.x * 256 + threadIdx.x; i < n; i += gridDim.x * 256)
        out[i] = f2bf(in[i]);
}

// ---------------------------------------------------------------- MFMA GEMM
// C[M,N] = A[M,K] @ B[K,N] + bias, B given transposed (BT bf16 [N][K]).
// A fp32 (converted during staging) or bf16. C fp32 or bf16. ACT==1: exact GELU.
// PKM mode: blockIdx.z selects (h,half): A+=z-offset, BT+=z*NK*HALF, C+=z*NK.
constexpr int LSTR = 56;   // 32 + 24 pad (rows stay 16B aligned, banks spread)

template<int A_BF16, int C_BF16, int ACT, int PKMM>
__global__ __launch_bounds__(256) void gemm_mfma(const void* __restrict__ Ag,
    const unsigned short* __restrict__ BT, const float* __restrict__ bias,
    void* __restrict__ Cg, int M, int N, int K, int lda, int ldc)
{
    __shared__ unsigned short As[128 * LSTR];
    __shared__ unsigned short Bs[128 * LSTR];
    const int tid = threadIdx.x;
    const int lane = tid & 63, w = tid >> 6;
    const int wr = w >> 1, wc = w & 1;
    const int l15 = lane & 15, l4 = lane >> 4;

    size_t aoff = 0, boff = 0, coff = 0;
    if (PKMM) {
        int z = blockIdx.z;
        aoff = (size_t)(z >> 1) * KD + (size_t)(z & 1) * HALF;
        boff = (size_t)z * NK * HALF;
        coff = (size_t)z * NK;
    }
    const int rowA0 = blockIdx.y * 128, rowB0 = blockIdx.x * 128;

    f32x4 acc[4][4];
#pragma unroll
    for (int i = 0; i < 4; i++)
#pragma unroll
        for (int j = 0; j < 4; j++) acc[i][j] = (f32x4){0.f, 0.f, 0.f, 0.f};

    const unsigned short* Abf = (const unsigned short*)Ag;
    const float* Af = (const float*)Ag;

    for (int k0 = 0; k0 < K; k0 += 32) {
        // ---- stage A tile: 128 rows x 32 k (bf16 in LDS)
#pragma unroll
        for (int it = 0; it < 2; ++it) {
            int e = it * 256 + tid;          // 0..511, 8 elems each
            int r = e >> 2, c8 = e & 3;
            if (A_BF16) {
                uint4 v = *(const uint4*)(Abf + aoff + (size_t)(rowA0 + r) * lda + k0 + c8 * 8);
                *(uint4*)&As[r * LSTR + c8 * 8] = v;
            } else {
                const float* src = Af + aoff + (size_t)(rowA0 + r) * lda + k0 + c8 * 8;
                float4 v0 = *(const float4*)src;
                float4 v1 = *(const float4*)(src + 4);
                unsigned short t[8] = {f2bf(v0.x), f2bf(v0.y), f2bf(v0.z), f2bf(v0.w),
                                       f2bf(v1.x), f2bf(v1.y), f2bf(v1.z), f2bf(v1.w)};
                *(uint4*)&As[r * LSTR + c8 * 8] = *(uint4*)t;
            }
        }
        // ---- stage BT tile: 128 rows(n) x 32 k
#pragma unroll
        for (int it = 0; it < 2; ++it) {
            int e = it * 256 + tid;
            int r = e >> 2, c8 = e & 3;
            uint4 v = *(const uint4*)(BT + boff + (size_t)(rowB0 + r) * K + k0 + c8 * 8);
            *(uint4*)&Bs[r * LSTR + c8 * 8] = v;
        }
        __syncthreads();

        short8_t af[4], bf[4];
#pragma unroll
        for (int i = 0; i < 4; i++)
            af[i] = *(const short8_t*)&As[(wr * 64 + i * 16 + l15) * LSTR + l4 * 8];
#pragma unroll
        for (int j = 0; j < 4; j++)
            bf[j] = *(const short8_t*)&Bs[(wc * 64 + j * 16 + l15) * LSTR + l4 * 8];
#pragma unroll
        for (int i = 0; i < 4; i++)
#pragma unroll
            for (int j = 0; j < 4; j++)
                acc[i][j] = __builtin_amdgcn_mfma_f32_16x16x32_bf16(af[i], bf[j], acc[i][j], 0, 0, 0);
        __syncthreads();
    }

    // ---- epilogue: bias (+GELU) + store; D: col=lane&15, row=(lane>>4)*4+reg
#pragma unroll
    for (int i = 0; i < 4; i++) {
#pragma unroll
        for (int j = 0; j < 4; j++) {
            const int row = rowA0 + wr * 64 + i * 16 + l4 * 4;
            const int col = rowB0 + wc * 64 + j * 16 + l15;
            const float bv = PKMM ? 0.f : bias[col];
#pragma unroll
            for (int jj = 0; jj < 4; jj++) {
                float v = acc[i][j][jj] + bv;
                if (ACT == 1) v = 0.5f * v * (1.0f + erff(v * 0.70710678118654752f));
                if (C_BF16)
                    ((unsigned short*)Cg)[coff + (size_t)(row + jj) * ldc + col] = f2bf(v);
                else
                    ((float*)Cg)[coff + (size_t)(row + jj) * ldc + col] = v;
            }
        }
    }
}

// ----------------------------------------------------------- attention ----
// 64-query tile per block; K/V tiles of 64 staged in LDS; online softmax.
constexpr int AP = 68;   // padded stride (16B aligned rows, spread banks)

__global__ __launch_bounds__(256) void attn_kernel(const float* __restrict__ q,
    const float* __restrict__ k, const float* __restrict__ v,
    float* __restrict__ ctx)
{
    __shared__ float Qs[64 * AP], Ks[64 * AP], Vs[64 * AP], Ss[64 * AP];
    __shared__ float mA[64], cfA[64], lA[64];
    __shared__ float red[4][64];
    const int tid = threadIdx.x, lane = tid & 63, g = tid >> 6;
    const int h = blockIdx.y, b = blockIdx.z;
    const int q0 = blockIdx.x * 64;
    const size_t base = (size_t)(b * CS) * CD + h * CHD;

#pragma unroll
    for (int i = 0; i < 16; i++) {
        int e = i * 256 + tid;
        int r = e >> 6, d = e & 63;
        Qs[r * AP + d] = q[base + (size_t)(q0 + r) * CD + d];
    }
    if (tid < 64) { mA[tid] = -1e30f; lA[tid] = 0.f; }
    float acc[16];
#pragma unroll
    for (int i = 0; i < 16; i++) acc[i] = 0.f;
    __syncthreads();

    for (int kt = 0; kt < 8; ++kt) {
#pragma unroll
        for (int i = 0; i < 16; i++) {
            int e = i * 256 + tid;
            int r = e >> 6, d = e & 63;
            Ks[r * AP + d] = k[base + (size_t)(kt * 64 + r) * CD + d];
            Vs[r * AP + d] = v[base + (size_t)(kt * 64 + r) * CD + d];
        }
        __syncthreads();

        // scores: wave g owns keys g*16..+15, lane = query row
        float s[16];
#pragma unroll
        for (int ki = 0; ki < 16; ki++) s[ki] = 0.f;
        for (int d4 = 0; d4 < 16; ++d4) {
            float4 qv = *(const float4*)&Qs[lane * AP + d4 * 4];
#pragma unroll
            for (int ki = 0; ki < 16; ki++) {
                float4 kv = *(const float4*)&Ks[(g * 16 + ki) * AP + d4 * 4];
                s[ki] += qv.x * kv.x + qv.y * kv.y + qv.z * kv.z + qv.w * kv.w;
            }
        }
        float lm = -1e30f;
#pragma unroll
        for (int ki = 0; ki < 16; ki++) { s[ki] *= 0.125f; lm = fmaxf(lm, s[ki]); }
        red[g][lane] = lm;
        __syncthreads();
        if (g == 0) {
            float mt = fmaxf(fmaxf(red[0][lane], red[1][lane]), fmaxf(red[2][lane], red[3][lane]));
            float mo = mA[lane];
            float mn = fmaxf(mo, mt);
            cfA[lane] = __expf(mo - mn);
            mA[lane] = mn;
        }
        __syncthreads();
        const float mn = mA[lane];
        float ls = 0.f;
#pragma unroll
        for (int ki = 0; ki < 16; ki++) {
            float e = __expf(s[ki] - mn);
            Ss[lane * AP + g * 16 + ki] = e;
            ls += e;
        }
        red[g][lane] = ls;
        __syncthreads();

        // PV: wave g owns dims g*16..+15, lane = query row
        const float cf = cfA[lane];
#pragma unroll
        for (int i = 0; i < 16; i++) acc[i] *= cf;
        for (int t4 = 0; t4 < 16; ++t4) {
            float4 pv = *(const float4*)&Ss[lane * AP + t4 * 4];
#pragma unroll
            for (int tt = 0; tt < 4; ++tt) {
                const float p = (tt == 0) ? pv.x : (tt == 1) ? pv.y : (tt == 2) ? pv.z : pv.w;
                const float* vr = &Vs[(t4 * 4 + tt) * AP + g * 16];
                float4 v0 = *(const float4*)(vr);
                float4 v1 = *(const float4*)(vr + 4);
                float4 v2 = *(const float4*)(vr + 8);
                float4 v3 = *(const float4*)(vr + 12);
                acc[0] += p * v0.x; acc[1] += p * v0.y; acc[2] += p * v0.z; acc[3] += p * v0.w;
                acc[4] += p * v1.x; acc[5] += p * v1.y; acc[6] += p * v1.z; acc[7] += p * v1.w;
                acc[8] += p * v2.x; acc[9] += p * v2.y; acc[10] += p * v2.z; acc[11] += p * v2.w;
                acc[12] += p * v3.x; acc[13] += p * v3.y; acc[14] += p * v3.z; acc[15] += p * v3.w;
            }
        }
        if (g == 0)
            lA[lane] = lA[lane] * cf + (red[0][lane] + red[1][lane] + red[2][lane] + red[3][lane]);
        __syncthreads();
    }
    const float linv = 1.0f / lA[lane];
#pragma unroll
    for (int i = 0; i < 16; i++)
        ctx[base + (size_t)(q0 + lane) * CD + g * 16 + i] = acc[i] * linv;
}

// ----------------------------------------------------------- layernorm ----
__global__ __launch_bounds__(256) void ln_kernel(float* __restrict__ out,
    const float* __restrict__ a, const float* __restrict__ b2,
    const float* __restrict__ c, const float* __restrict__ g,
    const float* __restrict__ bb)
{
    const int t = blockIdx.x, tid = threadIdx.x;
    __shared__ float buf[CD];
    __shared__ float red[256];
    float l = 0.f;
    for (int d = tid; d < CD; d += 256) {
        float v = a[(size_t)t * CD + d];
        if (b2) v += b2[(size_t)t * CD + d];
        if (c)  v += c[(size_t)t * CD + d];
        buf[d] = v; l += v;
    }
    red[tid] = l; __syncthreads();
    for (int o = 128; o > 0; o >>= 1) { if (tid < o) red[tid] += red[tid + o]; __syncthreads(); }
    const float mean = red[0] * (1.0f / CD); __syncthreads();
    float l2 = 0.f;
    for (int d = tid; d < CD; d += 256) { float dd = buf[d] - mean; l2 += dd * dd; }
    red[tid] = l2; __syncthreads();
    for (int o = 128; o > 0; o >>= 1) { if (tid < o) red[tid] += red[tid + o]; __syncthreads(); }
    const float inv = rsqrtf(red[0] * (1.0f / CD) + 1e-12f);
    for (int d = tid; d < CD; d += 256)
        out[(size_t)t * CD + d] = (buf[d] - mean) * inv * g[d] + bb[d];
}

// ------------------------------------------------------- top-k stage 1 ----
__global__ void topk1_kernel(const float* __restrict__ sc,
    float* __restrict__ tv, int* __restrict__ ti)
{
    const int gid = blockIdx.x * blockDim.x + threadIdx.x;
    if (gid >= CT * PH * 2) return;
    const float* s = &sc[(size_t)gid * NK];
    float val[KNN]; int idx[KNN]; int cnt = 0;
    for (int n = 0; n < NK; n++) {
        float v = s[n];
        if (cnt < KNN) {
            int p = cnt++;
            while (p > 0 && val[p - 1] < v) { val[p] = val[p - 1]; idx[p] = idx[p - 1]; p--; }
            val[p] = v; idx[p] = n;
        } else if (v > val[KNN - 1]) {
            int p = KNN - 1;
            while (p > 0 && val[p - 1] < v) { val[p] = val[p - 1]; idx[p] = idx[p - 1]; p--; }
            val[p] = v; idx[p] = n;
        }
    }
    for (int i = 0; i < KNN; i++) { tv[(size_t)gid * KNN + i] = val[i]; ti[(size_t)gid * KNN + i] = idx[i]; }
}

// ----------------------------------------- cartesian top-k + softmax ------
__global__ void cart_topk_kernel(const float* __restrict__ tv, const int* __restrict__ ti,
    float* __restrict__ w, int* __restrict__ ind)
{
    const int gid = blockIdx.x * blockDim.x + threadIdx.x;
    if (gid >= CT * PH) return;
    const float* v1 = &tv[(size_t)gid * 2 * KNN];
    const float* v2 = v1 + KNN;
    const int* i1 = &ti[(size_t)gid * 2 * KNN];
    const int* i2 = i1 + KNN;
    float val[KNN]; int idx[KNN]; int cnt = 0;
    for (int i = 0; i < KNN; i++) {
        float a = v1[i];
        if (cnt == KNN && a + v2[0] <= val[KNN - 1]) break;
        for (int j = 0; j < KNN; j++) {
            float c = a + v2[j];
            if (cnt < KNN) {
                int p = cnt++;
                while (p > 0 && val[p - 1] < c) { val[p] = val[p - 1]; idx[p] = idx[p - 1]; p--; }
                val[p] = c; idx[p] = i * KNN + j;
            } else if (c > val[KNN - 1]) {
                int p = KNN - 1;
                while (p > 0 && val[p - 1] < c) { val[p] = val[p - 1]; idx[p] = idx[p - 1]; p--; }
                val[p] = c; idx[p] = i * KNN + j;
            } else break;
        }
    }
    const float mx = val[0];
    float e[KNN], ssum = 0.f;
    for (int i = 0; i < KNN; i++) { e[i] = expf(val[i] - mx); ssum += e[i]; }
    const float invs = 1.0f / ssum;
    for (int i = 0; i < KNN; i++) {
        int ii = idx[i] / KNN, jj = idx[i] % KNN;
        w[(size_t)gid * KNN + i] = e[i] * invs;
        ind[(size_t)gid * KNN + i] = i1[ii] * NK + i2[jj];
    }
}

// --------------------------------------------------------- PKM gather -----
__global__ __launch_bounds__(256) void pkm_gather_kernel(const float* __restrict__ w,
    const int* __restrict__ ind, const float* __restrict__ values,
    float* __restrict__ out)
{
    const int t = blockIdx.x, tid = threadIdx.x;
    __shared__ float ws[PH * KNN];
    __shared__ int   is[PH * KNN];
    if (tid < PH * KNN) {
        ws[tid] = w[(size_t)t * PH * KNN + tid];
        is[tid] = ind[(size_t)t * PH * KNN + tid];
    }
    __syncthreads();
    float acc0 = 0.f, acc1 = 0.f, acc2 = 0.f;
    for (int i = 0; i < PH * KNN; i++) {
        const float* vr = &values[(size_t)is[i] * CD];
        const float wi = ws[i];
        acc0 = fmaf(wi, vr[tid], acc0);
        acc1 = fmaf(wi, vr[tid + 256], acc1);
        acc2 = fmaf(wi, vr[tid + 512], acc2);
    }
    out[(size_t)t * CD + tid] = acc0;
    out[(size_t)t * CD + tid + 256] = acc1;
    out[(size_t)t * CD + tid + 512] = acc2;
}

// ------------------------------------------------------------- launch -----
extern "C" void kernel_launch(void* const* d_in, const int* in_sizes, int n_in,
                              void* d_out, int out_size, void* d_ws, size_t ws_size,
                              hipStream_t stream)
{
    const float* x      = (const float*)d_in[0];
    const float* Wq     = (const float*)d_in[1];
    const float* bq     = (const float*)d_in[2];
    const float* Wk     = (const float*)d_in[3];
    const float* bk     = (const float*)d_in[4];
    const float* Wv     = (const float*)d_in[5];
    const float* bv     = (const float*)d_in[6];
    const float* Wo     = (const float*)d_in[7];
    const float* bo     = (const float*)d_in[8];
    const float* ln1_g  = (const float*)d_in[9];
    const float* ln1_b  = (const float*)d_in[10];
    const float* Wi     = (const float*)d_in[11];
    const float* bi     = (const float*)d_in[12];
    const float* Wd     = (const float*)d_in[13];
    const float* bd     = (const float*)d_in[14];
    const float* ln2_g  = (const float*)d_in[15];
    const float* ln2_b  = (const float*)d_in[16];
    const float* Wpq    = (const float*)d_in[17];
    const float* bpq    = (const float*)d_in[18];
    const float* keys   = (const float*)d_in[19];
    const float* values = (const float*)d_in[20];

    float* ws = (float*)d_ws;
    // workspace layout (float units)
    float*          qb    = ws;                       // 2048*768
    float*          kb    = ws + 1572864;
    float*          vb    = ws + 3145728;
    unsigned short* pq    = (unsigned short*)ws;      // bf16 2048*2048 (qkv dead)
    float*          ctx   = ws + 4718592;             // later: pkm_out
    float*          tmp   = ws + 6291456;             // later: dense
    float*          attn  = ws + 7864320;
    unsigned short* inter = (unsigned short*)(ws + 9437184);   // bf16 2048*3072
    float*          sbuf  = ws + 12582912;            // 2048*1024
    float*          tv    = ws + 14680064;
    int*            ti    = (int*)(ws + 15204352);
    float*          wgt   = ws + 15728640;
    int*            ind   = (int*)(ws + 15990784);
    unsigned short* wt    = (unsigned short*)(ws + 16252928);  // bf16 <=3072*2048
    unsigned short* keysb = (unsigned short*)(ws + 19398656);  // bf16 262144

    const dim3 blk(256);

    // keys -> bf16
    cvt_bf16_kernel<<<1024, blk, 0, stream>>>(keys, keysb, PH * 2 * NK * HALF);

    // QKV projections (transpose weight just-in-time, single wt buffer)
    transpose_w<<<dim3(CD / 32, CD / 32), blk, 0, stream>>>(Wq, wt, CD, CD);
    gemm_mfma<0, 0, 0, 0><<<dim3(CD / 128, CT / 128), blk, 0, stream>>>(x, wt, bq, qb, CT, CD, CD, CD, CD);
    transpose_w<<<dim3(CD / 32, CD / 32), blk, 0, stream>>>(Wk, wt, CD, CD);
    gemm_mfma<0, 0, 0, 0><<<dim3(CD / 128, CT / 128), blk, 0, stream>>>(x, wt, bk, kb, CT, CD, CD, CD, CD);
    transpose_w<<<dim3(CD / 32, CD / 32), blk, 0, stream>>>(Wv, wt, CD, CD);
    gemm_mfma<0, 0, 0, 0><<<dim3(CD / 128, CT / 128), blk, 0, stream>>>(x, wt, bv, vb, CT, CD, CD, CD, CD);

    // attention (64-query tiles)
    attn_kernel<<<dim3(CS / 64, CH, CB), blk, 0, stream>>>(qb, kb, vb, ctx);

    // output proj + LN1
    transpose_w<<<dim3(CD / 32, CD / 32), blk, 0, stream>>>(Wo, wt, CD, CD);
    gemm_mfma<0, 0, 0, 0><<<dim3(CD / 128, CT / 128), blk, 0, stream>>>(ctx, wt, bo, tmp, CT, CD, CD, CD, CD);
    ln_kernel<<<CT, blk, 0, stream>>>(attn, tmp, x, nullptr, ln1_g, ln1_b);

    // FFN up (GELU, bf16 out)
    transpose_w<<<dim3(CFF / 32, CD / 32), blk, 0, stream>>>(Wi, wt, CD, CFF);
    gemm_mfma<0, 1, 1, 0><<<dim3(CFF / 128, CT / 128), blk, 0, stream>>>(attn, wt, bi, inter, CT, CFF, CD, CD, CFF);
    // FFN down (bf16 A, fp32 out)
    transpose_w<<<dim3(CD / 32, CFF / 32), blk, 0, stream>>>(Wd, wt, CFF, CD);
    gemm_mfma<1, 0, 0, 0><<<dim3(CD / 128, CT / 128), blk, 0, stream>>>(inter, wt, bd, tmp, CT, CD, CFF, CFF, CD);
    // PKM query proj (bf16 A, bf16 out)
    transpose_w<<<dim3((PH * KD) / 32, CFF / 32), blk, 0, stream>>>(Wpq, wt, CFF, PH * KD);
    gemm_mfma<1, 1, 0, 0><<<dim3((PH * KD) / 128, CT / 128), blk, 0, stream>>>(inter, wt, bpq, pq, CT, PH * KD, CFF, CFF, PH * KD);

    // PKM scores: 8 batched GEMMs (z = h*2+half), M=2048 N=128 K=256
    gemm_mfma<1, 0, 0, 1><<<dim3(1, CT / 128, PH * 2), blk, 0, stream>>>(pq, keysb, nullptr, sbuf, CT, NK, HALF, PH * KD, PH * 2 * NK);

    // top-k pipeline + gather
    topk1_kernel<<<(CT * PH * 2 + 255) / 256, blk, 0, stream>>>(sbuf, tv, ti);
    cart_topk_kernel<<<(CT * PH + 255) / 256, blk, 0, stream>>>(tv, ti, wgt, ind);
    pkm_gather_kernel<<<CT, blk, 0, stream>>>(wgt, ind, values, ctx);

    // final LN
    ln_kernel<<<CT, blk, 0, stream>>>((float*)d_out, tmp, ctx, attn, ln2_g, ln2_b);
}

// Round 3
// 580.426 us; speedup vs baseline: 6.6495x; 2.2981x over previous
//
#include <hip/hip_runtime.h>
#include <math.h>

// Problem constants
constexpr int CB = 4, CS = 512, CD = 768, CFF = 3072, CH = 12, CHD = 64;
constexpr int CT = CB * CS;            // 2048 tokens
constexpr int PH = 4, KD = 512, NK = 128, KNN = 32, HALF = 256;

typedef __attribute__((ext_vector_type(8))) short short8_t;   // 8 bf16 (4 VGPRs)
typedef __attribute__((ext_vector_type(4))) float f32x4;      // MFMA accumulator

__device__ __forceinline__ unsigned short f2bf(float f) {
    unsigned int u = __float_as_uint(f);
    unsigned int r = (u + 0x7FFF + ((u >> 16) & 1)) >> 16;    // RNE
    return (unsigned short)r;
}

// ------------------------------------------------------- weight transpose --
// W fp32 [K][N] -> WT bf16 [N][K]
__global__ __launch_bounds__(256) void transpose_w(const float* __restrict__ W,
    unsigned short* __restrict__ WT, int K, int N)
{
    __shared__ unsigned short ts[32][33];
    const int n0 = blockIdx.x * 32, k0 = blockIdx.y * 32;
    const int c = threadIdx.x & 31, rr = threadIdx.x >> 5;
#pragma unroll
    for (int i = 0; i < 4; i++) {
        int r = rr + i * 8;
        ts[c][r] = f2bf(W[(size_t)(k0 + r) * N + n0 + c]);   // ts[a][b]=W[k0+b][n0+a]
    }
    __syncthreads();
#pragma unroll
    for (int i = 0; i < 4; i++) {
        int rw = rr + i * 8;
        WT[(size_t)(n0 + rw) * K + k0 + c] = ts[rw][c];
    }
}

// ------------------------------------------------------------ fp32->bf16 --
__global__ __launch_bounds__(256) void cvt_bf16_kernel(const float* __restrict__ in,
    unsigned short* __restrict__ out, int n)
{
    for (int i = blockIdx.x * 256 + threadIdx.x; i < n; i += gridDim.x * 256)
        out[i] = f2bf(in[i]);
}

// ---------------------------------------------------------------- MFMA GEMM
// C[M,N] = A[M,K] @ B[K,N] + bias, B given transposed (BT bf16 [N][K]).
// A fp32 (converted during staging) or bf16. C fp32 or bf16. ACT==1: exact GELU.
// PKM mode: blockIdx.z selects (h,half): A+=z-offset, BT+=z*NK*HALF, C+=z*NK.
constexpr int LSTR = 56;   // 32 + 24 pad (rows stay 16B aligned, banks spread)

template<int A_BF16, int C_BF16, int ACT, int PKMM>
__global__ __launch_bounds__(256) void gemm_mfma(const void* __restrict__ Ag,
    const unsigned short* __restrict__ BT, const float* __restrict__ bias,
    void* __restrict__ Cg, int M, int N, int K, int lda, int ldc)
{
    __shared__ unsigned short As[128 * LSTR];
    __shared__ unsigned short Bs[128 * LSTR];
    const int tid = threadIdx.x;
    const int lane = tid & 63, w = tid >> 6;
    const int wr = w >> 1, wc = w & 1;
    const int l15 = lane & 15, l4 = lane >> 4;

    size_t aoff = 0, boff = 0, coff = 0;
    if (PKMM) {
        int z = blockIdx.z;
        aoff = (size_t)(z >> 1) * KD + (size_t)(z & 1) * HALF;
        boff = (size_t)z * NK * HALF;
        coff = (size_t)z * NK;
    }
    const int rowA0 = blockIdx.y * 128, rowB0 = blockIdx.x * 128;

    f32x4 acc[4][4];
#pragma unroll
    for (int i = 0; i < 4; i++)
#pragma unroll
        for (int j = 0; j < 4; j++) acc[i][j] = (f32x4){0.f, 0.f, 0.f, 0.f};

    const unsigned short* Abf = (const unsigned short*)Ag;
    const float* Af = (const float*)Ag;

    for (int k0 = 0; k0 < K; k0 += 32) {
        // ---- stage A tile: 128 rows x 32 k (bf16 in LDS)
#pragma unroll
        for (int it = 0; it < 2; ++it) {
            int e = it * 256 + tid;          // 0..511, 8 elems each
            int r = e >> 2, c8 = e & 3;
            if (A_BF16) {
                uint4 v = *(const uint4*)(Abf + aoff + (size_t)(rowA0 + r) * lda + k0 + c8 * 8);
                *(uint4*)&As[r * LSTR + c8 * 8] = v;
            } else {
                const float* src = Af + aoff + (size_t)(rowA0 + r) * lda + k0 + c8 * 8;
                float4 v0 = *(const float4*)src;
                float4 v1 = *(const float4*)(src + 4);
                unsigned short t[8] = {f2bf(v0.x), f2bf(v0.y), f2bf(v0.z), f2bf(v0.w),
                                       f2bf(v1.x), f2bf(v1.y), f2bf(v1.z), f2bf(v1.w)};
                *(uint4*)&As[r * LSTR + c8 * 8] = *(uint4*)t;
            }
        }
        // ---- stage BT tile: 128 rows(n) x 32 k
#pragma unroll
        for (int it = 0; it < 2; ++it) {
            int e = it * 256 + tid;
            int r = e >> 2, c8 = e & 3;
            uint4 v = *(const uint4*)(BT + boff + (size_t)(rowB0 + r) * K + k0 + c8 * 8);
            *(uint4*)&Bs[r * LSTR + c8 * 8] = v;
        }
        __syncthreads();

        short8_t af[4], bf[4];
#pragma unroll
        for (int i = 0; i < 4; i++)
            af[i] = *(const short8_t*)&As[(wr * 64 + i * 16 + l15) * LSTR + l4 * 8];
#pragma unroll
        for (int j = 0; j < 4; j++)
            bf[j] = *(const short8_t*)&Bs[(wc * 64 + j * 16 + l15) * LSTR + l4 * 8];
#pragma unroll
        for (int i = 0; i < 4; i++)
#pragma unroll
            for (int j = 0; j < 4; j++)
                acc[i][j] = __builtin_amdgcn_mfma_f32_16x16x32_bf16(af[i], bf[j], acc[i][j], 0, 0, 0);
        __syncthreads();
    }

    // ---- epilogue: bias (+GELU) + store; D: col=lane&15, row=(lane>>4)*4+reg
#pragma unroll
    for (int i = 0; i < 4; i++) {
#pragma unroll
        for (int j = 0; j < 4; j++) {
            const int row = rowA0 + wr * 64 + i * 16 + l4 * 4;
            const int col = rowB0 + wc * 64 + j * 16 + l15;
            const float bv = PKMM ? 0.f : bias[col];
#pragma unroll
            for (int jj = 0; jj < 4; jj++) {
                float v = acc[i][j][jj] + bv;
                if (ACT == 1) v = 0.5f * v * (1.0f + erff(v * 0.70710678118654752f));
                if (C_BF16)
                    ((unsigned short*)Cg)[coff + (size_t)(row + jj) * ldc + col] = f2bf(v);
                else
                    ((float*)Cg)[coff + (size_t)(row + jj) * ldc + col] = v;
            }
        }
    }
}

// ----------------------------------------------------------- attention ----
// 64-query tile per block; K/V tiles of 64 staged in LDS; online softmax.
constexpr int AP = 68;   // padded stride (16B aligned rows, spread banks)

__global__ __launch_bounds__(256) void attn_kernel(const float* __restrict__ q,
    const float* __restrict__ k, const float* __restrict__ v,
    float* __restrict__ ctx)
{
    __shared__ float Qs[64 * AP], Ks[64 * AP], Vs[64 * AP], Ss[64 * AP];
    __shared__ float mA[64], cfA[64], lA[64];
    __shared__ float red[4][64];
    const int tid = threadIdx.x, lane = tid & 63, g = tid >> 6;
    const int h = blockIdx.y, b = blockIdx.z;
    const int q0 = blockIdx.x * 64;
    const size_t base = (size_t)(b * CS) * CD + h * CHD;

#pragma unroll
    for (int i = 0; i < 16; i++) {
        int e = i * 256 + tid;
        int r = e >> 6, d = e & 63;
        Qs[r * AP + d] = q[base + (size_t)(q0 + r) * CD + d];
    }
    if (tid < 64) { mA[tid] = -1e30f; lA[tid] = 0.f; }
    float acc[16];
#pragma unroll
    for (int i = 0; i < 16; i++) acc[i] = 0.f;
    __syncthreads();

    for (int kt = 0; kt < 8; ++kt) {
#pragma unroll
        for (int i = 0; i < 16; i++) {
            int e = i * 256 + tid;
            int r = e >> 6, d = e & 63;
            Ks[r * AP + d] = k[base + (size_t)(kt * 64 + r) * CD + d];
            Vs[r * AP + d] = v[base + (size_t)(kt * 64 + r) * CD + d];
        }
        __syncthreads();

        // scores: wave g owns keys g*16..+15, lane = query row
        float s[16];
#pragma unroll
        for (int ki = 0; ki < 16; ki++) s[ki] = 0.f;
        for (int d4 = 0; d4 < 16; ++d4) {
            float4 qv = *(const float4*)&Qs[lane * AP + d4 * 4];
#pragma unroll
            for (int ki = 0; ki < 16; ki++) {
                float4 kv = *(const float4*)&Ks[(g * 16 + ki) * AP + d4 * 4];
                s[ki] += qv.x * kv.x + qv.y * kv.y + qv.z * kv.z + qv.w * kv.w;
            }
        }
        float lm = -1e30f;
#pragma unroll
        for (int ki = 0; ki < 16; ki++) { s[ki] *= 0.125f; lm = fmaxf(lm, s[ki]); }
        red[g][lane] = lm;
        __syncthreads();
        if (g == 0) {
            float mt = fmaxf(fmaxf(red[0][lane], red[1][lane]), fmaxf(red[2][lane], red[3][lane]));
            float mo = mA[lane];
            float mn = fmaxf(mo, mt);
            cfA[lane] = __expf(mo - mn);
            mA[lane] = mn;
        }
        __syncthreads();
        const float mn = mA[lane];
        float ls = 0.f;
#pragma unroll
        for (int ki = 0; ki < 16; ki++) {
            float e = __expf(s[ki] - mn);
            Ss[lane * AP + g * 16 + ki] = e;
            ls += e;
        }
        red[g][lane] = ls;
        __syncthreads();

        // PV: wave g owns dims g*16..+15, lane = query row
        const float cf = cfA[lane];
#pragma unroll
        for (int i = 0; i < 16; i++) acc[i] *= cf;
        for (int t4 = 0; t4 < 16; ++t4) {
            float4 pv = *(const float4*)&Ss[lane * AP + t4 * 4];
#pragma unroll
            for (int tt = 0; tt < 4; ++tt) {
                const float p = (tt == 0) ? pv.x : (tt == 1) ? pv.y : (tt == 2) ? pv.z : pv.w;
                const float* vr = &Vs[(t4 * 4 + tt) * AP + g * 16];
                float4 v0 = *(const float4*)(vr);
                float4 v1 = *(const float4*)(vr + 4);
                float4 v2 = *(const float4*)(vr + 8);
                float4 v3 = *(const float4*)(vr + 12);
                acc[0] += p * v0.x; acc[1] += p * v0.y; acc[2] += p * v0.z; acc[3] += p * v0.w;
                acc[4] += p * v1.x; acc[5] += p * v1.y; acc[6] += p * v1.z; acc[7] += p * v1.w;
                acc[8] += p * v2.x; acc[9] += p * v2.y; acc[10] += p * v2.z; acc[11] += p * v2.w;
                acc[12] += p * v3.x; acc[13] += p * v3.y; acc[14] += p * v3.z; acc[15] += p * v3.w;
            }
        }
        if (g == 0)
            lA[lane] = lA[lane] * cf + (red[0][lane] + red[1][lane] + red[2][lane] + red[3][lane]);
        __syncthreads();
    }
    const float linv = 1.0f / lA[lane];
#pragma unroll
    for (int i = 0; i < 16; i++)
        ctx[base + (size_t)(q0 + lane) * CD + g * 16 + i] = acc[i] * linv;
}

// ----------------------------------------------------------- layernorm ----
__global__ __launch_bounds__(256) void ln_kernel(float* __restrict__ out,
    const float* __restrict__ a, const float* __restrict__ b2,
    const float* __restrict__ c, const float* __restrict__ g,
    const float* __restrict__ bb)
{
    const int t = blockIdx.x, tid = threadIdx.x;
    __shared__ float buf[CD];
    __shared__ float red[256];
    float l = 0.f;
    for (int d = tid; d < CD; d += 256) {
        float v = a[(size_t)t * CD + d];
        if (b2) v += b2[(size_t)t * CD + d];
        if (c)  v += c[(size_t)t * CD + d];
        buf[d] = v; l += v;
    }
    red[tid] = l; __syncthreads();
    for (int o = 128; o > 0; o >>= 1) { if (tid < o) red[tid] += red[tid + o]; __syncthreads(); }
    const float mean = red[0] * (1.0f / CD); __syncthreads();
    float l2 = 0.f;
    for (int d = tid; d < CD; d += 256) { float dd = buf[d] - mean; l2 += dd * dd; }
    red[tid] = l2; __syncthreads();
    for (int o = 128; o > 0; o >>= 1) { if (tid < o) red[tid] += red[tid + o]; __syncthreads(); }
    const float inv = rsqrtf(red[0] * (1.0f / CD) + 1e-12f);
    for (int d = tid; d < CD; d += 256)
        out[(size_t)t * CD + d] = (buf[d] - mean) * inv * g[d] + bb[d];
}

// --------------------------------------------- fused PKM top-k (both stages)
// One 128-thread block per (t,h). Scores are contiguous: sc[(t*4+h)*256].
// Stage 1: bitonic-sort each 128-half desc (tie: lower idx). Stage 2: top-32
// of cartesian sums pruned to {(i,j): (i+1)(j+1)<=32} (119 cands, provably
// a superset of top-32 incl. tie semantics), bitonic-sorted. Softmax + ind.
__device__ const unsigned char CCNT[32] = {32,16,10,8,6,5,4,4,3,3,2,2,2,2,2,2,
                                           1,1,1,1,1,1,1,1,1,1,1,1,1,1,1,1};

__global__ __launch_bounds__(128) void pkm_topk_kernel(const float* __restrict__ sc,
    float* __restrict__ w, int* __restrict__ ind)
{
    const int gid = blockIdx.x;            // t*PH + h
    const int tid = threadIdx.x;
    __shared__ float sv[256];
    __shared__ int   si_[256];
    __shared__ float cv[128];
    __shared__ int   ci[128];

    const float* s = sc + (size_t)gid * 256;
    sv[tid] = s[tid];           si_[tid] = tid;
    sv[tid + 128] = s[tid + 128]; si_[tid + 128] = tid;
    __syncthreads();

    // ---- stage-1: sort both halves descending (128 pairs/stage, all threads)
    for (int k = 2; k <= 128; k <<= 1) {
        for (int j = k >> 1; j > 0; j >>= 1) {
            const int hh = tid >> 6, p = tid & 63;
            const int i = ((p & ~(j - 1)) << 1) | (p & (j - 1));
            const int l = i | j;
            const int bi_ = hh * 128 + i, bl = hh * 128 + l;
            float av = sv[bi_], bv2 = sv[bl];
            int   ai = si_[bi_], bx = si_[bl];
            const bool agtb = (av > bv2) || (av == bv2 && ai < bx);
            const bool desc = ((i & k) == 0);
            if (agtb != desc) { sv[bi_] = bv2; sv[bl] = av; si_[bi_] = bx; si_[bl] = ai; }
            __syncthreads();
        }
    }

    // ---- stage-2: pruned cartesian candidates
    {
        float val; int fi;
        if (tid < 119) {
            int tt = tid, ii = 0;
            while (tt >= (int)CCNT[ii]) { tt -= CCNT[ii]; ii++; }
            val = sv[ii] + sv[128 + tt];
            fi = ii * 32 + tt;
        } else { val = -3.0e38f; fi = 0x7FFFFFF; }
        cv[tid] = val; ci[tid] = fi;
    }
    __syncthreads();

    for (int k = 2; k <= 128; k <<= 1) {
        for (int j = k >> 1; j > 0; j >>= 1) {
            if (tid < 64) {
                const int p = tid;
                const int i = ((p & ~(j - 1)) << 1) | (p & (j - 1));
                const int l = i | j;
                float av = cv[i], bv2 = cv[l];
                int   ai = ci[i], bx = ci[l];
                const bool agtb = (av > bv2) || (av == bv2 && ai < bx);
                const bool desc = ((i & k) == 0);
                if (agtb != desc) { cv[i] = bv2; cv[l] = av; ci[i] = bx; ci[l] = ai; }
            }
            __syncthreads();
        }
    }

    // ---- softmax over top-32 + indices
    if (tid < 32) {
        const float mx = cv[0];
        float e = __expf(cv[tid] - mx);
        float s2 = e;
        for (int o = 16; o > 0; o >>= 1) s2 += __shfl_xor(s2, o);
        const int fi = ci[tid];
        const int ii = fi >> 5, jj = fi & 31;
        w[(size_t)gid * KNN + tid] = e / s2;
        ind[(size_t)gid * KNN + tid] = si_[ii] * NK + si_[128 + jj];
    }
}

// --------------------------------------------------------- PKM gather -----
__global__ __launch_bounds__(256) void pkm_gather_kernel(const float* __restrict__ w,
    const int* __restrict__ ind, const float* __restrict__ values,
    float* __restrict__ out)
{
    const int t = blockIdx.x, tid = threadIdx.x;
    __shared__ float ws[PH * KNN];
    __shared__ int   is[PH * KNN];
    if (tid < PH * KNN) {
        ws[tid] = w[(size_t)t * PH * KNN + tid];
        is[tid] = ind[(size_t)t * PH * KNN + tid];
    }
    __syncthreads();
    float acc0 = 0.f, acc1 = 0.f, acc2 = 0.f;
    for (int i = 0; i < PH * KNN; i++) {
        const float* vr = &values[(size_t)is[i] * CD];
        const float wi = ws[i];
        acc0 = fmaf(wi, vr[tid], acc0);
        acc1 = fmaf(wi, vr[tid + 256], acc1);
        acc2 = fmaf(wi, vr[tid + 512], acc2);
    }
    out[(size_t)t * CD + tid] = acc0;
    out[(size_t)t * CD + tid + 256] = acc1;
    out[(size_t)t * CD + tid + 512] = acc2;
}

// ------------------------------------------------------------- launch -----
extern "C" void kernel_launch(void* const* d_in, const int* in_sizes, int n_in,
                              void* d_out, int out_size, void* d_ws, size_t ws_size,
                              hipStream_t stream)
{
    const float* x      = (const float*)d_in[0];
    const float* Wq     = (const float*)d_in[1];
    const float* bq     = (const float*)d_in[2];
    const float* Wk     = (const float*)d_in[3];
    const float* bk     = (const float*)d_in[4];
    const float* Wv     = (const float*)d_in[5];
    const float* bv     = (const float*)d_in[6];
    const float* Wo     = (const float*)d_in[7];
    const float* bo     = (const float*)d_in[8];
    const float* ln1_g  = (const float*)d_in[9];
    const float* ln1_b  = (const float*)d_in[10];
    const float* Wi     = (const float*)d_in[11];
    const float* bi     = (const float*)d_in[12];
    const float* Wd     = (const float*)d_in[13];
    const float* bd     = (const float*)d_in[14];
    const float* ln2_g  = (const float*)d_in[15];
    const float* ln2_b  = (const float*)d_in[16];
    const float* Wpq    = (const float*)d_in[17];
    const float* bpq    = (const float*)d_in[18];
    const float* keys   = (const float*)d_in[19];
    const float* values = (const float*)d_in[20];

    float* ws = (float*)d_ws;
    // workspace layout (float units)
    float*          qb    = ws;                       // 2048*768
    float*          kb    = ws + 1572864;
    float*          vb    = ws + 3145728;
    unsigned short* pq    = (unsigned short*)ws;      // bf16 2048*2048 (qkv dead)
    float*          ctx   = ws + 4718592;             // later: pkm_out
    float*          tmp   = ws + 6291456;             // later: dense
    float*          attn  = ws + 7864320;
    unsigned short* inter = (unsigned short*)(ws + 9437184);   // bf16 2048*3072
    float*          sbuf  = ws + 12582912;            // 2048*1024
    float*          wgt   = ws + 15728640;
    int*            ind   = (int*)(ws + 15990784);
    unsigned short* wt    = (unsigned short*)(ws + 16252928);  // bf16 <=3072*2048
    unsigned short* keysb = (unsigned short*)(ws + 19398656);  // bf16 262144

    const dim3 blk(256);

    // keys -> bf16
    cvt_bf16_kernel<<<1024, blk, 0, stream>>>(keys, keysb, PH * 2 * NK * HALF);

    // QKV projections (transpose weight just-in-time, single wt buffer)
    transpose_w<<<dim3(CD / 32, CD / 32), blk, 0, stream>>>(Wq, wt, CD, CD);
    gemm_mfma<0, 0, 0, 0><<<dim3(CD / 128, CT / 128), blk, 0, stream>>>(x, wt, bq, qb, CT, CD, CD, CD, CD);
    transpose_w<<<dim3(CD / 32, CD / 32), blk, 0, stream>>>(Wk, wt, CD, CD);
    gemm_mfma<0, 0, 0, 0><<<dim3(CD / 128, CT / 128), blk, 0, stream>>>(x, wt, bk, kb, CT, CD, CD, CD, CD);
    transpose_w<<<dim3(CD / 32, CD / 32), blk, 0, stream>>>(Wv, wt, CD, CD);
    gemm_mfma<0, 0, 0, 0><<<dim3(CD / 128, CT / 128), blk, 0, stream>>>(x, wt, bv, vb, CT, CD, CD, CD, CD);

    // attention (64-query tiles)
    attn_kernel<<<dim3(CS / 64, CH, CB), blk, 0, stream>>>(qb, kb, vb, ctx);

    // output proj + LN1
    transpose_w<<<dim3(CD / 32, CD / 32), blk, 0, stream>>>(Wo, wt, CD, CD);
    gemm_mfma<0, 0, 0, 0><<<dim3(CD / 128, CT / 128), blk, 0, stream>>>(ctx, wt, bo, tmp, CT, CD, CD, CD, CD);
    ln_kernel<<<CT, blk, 0, stream>>>(attn, tmp, x, nullptr, ln1_g, ln1_b);

    // FFN up (GELU, bf16 out)
    transpose_w<<<dim3(CFF / 32, CD / 32), blk, 0, stream>>>(Wi, wt, CD, CFF);
    gemm_mfma<0, 1, 1, 0><<<dim3(CFF / 128, CT / 128), blk, 0, stream>>>(attn, wt, bi, inter, CT, CFF, CD, CD, CFF);
    // FFN down (bf16 A, fp32 out)
    transpose_w<<<dim3(CD / 32, CFF / 32), blk, 0, stream>>>(Wd, wt, CFF, CD);
    gemm_mfma<1, 0, 0, 0><<<dim3(CD / 128, CT / 128), blk, 0, stream>>>(inter, wt, bd, tmp, CT, CD, CFF, CFF, CD);
    // PKM query proj (bf16 A, bf16 out)
    transpose_w<<<dim3((PH * KD) / 32, CFF / 32), blk, 0, stream>>>(Wpq, wt, CFF, PH * KD);
    gemm_mfma<1, 1, 0, 0><<<dim3((PH * KD) / 128, CT / 128), blk, 0, stream>>>(inter, wt, bpq, pq, CT, PH * KD, CFF, CFF, PH * KD);

    // PKM scores: 8 batched GEMMs (z = h*2+half), M=2048 N=128 K=256
    gemm_mfma<1, 0, 0, 1><<<dim3(1, CT / 128, PH * 2), blk, 0, stream>>>(pq, keysb, nullptr, sbuf, CT, NK, HALF, PH * KD, PH * 2 * NK);

    // fused two-stage top-k + softmax (one block per (t,h))
    pkm_topk_kernel<<<CT * PH, dim3(128), 0, stream>>>(sbuf, wgt, ind);

    // gather
    pkm_gather_kernel<<<CT, blk, 0, stream>>>(wgt, ind, values, ctx);

    // final LN
    ln_kernel<<<CT, blk, 0, stream>>>((float*)d_out, tmp, ctx, attn, ln2_g, ln2_b);
}

// Round 4
// 334.873 us; speedup vs baseline: 11.5254x; 1.7333x over previous
//
#include <hip/hip_runtime.h>
#include <math.h>

// Problem constants
constexpr int CB = 4, CS = 512, CD = 768, CFF = 3072, CH = 12, CHD = 64;
constexpr int CT = CB * CS;            // 2048 tokens
constexpr int PH = 4, KD = 512, NK = 128, KNN = 32, HALF = 256;

typedef __attribute__((ext_vector_type(8))) short short8_t;   // 8 bf16 (4 VGPRs)
typedef __attribute__((ext_vector_type(4))) float f32x4;      // MFMA accumulator

__device__ __forceinline__ unsigned short f2bf(float f) {
    unsigned int u = __float_as_uint(f);
    return (unsigned short)((u + 0x7FFF + ((u >> 16) & 1)) >> 16);  // RNE
}
__device__ __forceinline__ float bf2f(unsigned short h) {
    return __uint_as_float(((unsigned)h) << 16);
}

// ------------------------------------------------------------ fp32->bf16 --
__global__ __launch_bounds__(256) void cvt_bf16x4(const float* __restrict__ in,
    unsigned short* __restrict__ out, int n4)
{
    for (int i = blockIdx.x * 256 + threadIdx.x; i < n4; i += gridDim.x * 256) {
        float4 v = ((const float4*)in)[i];
        ushort4 o = { f2bf(v.x), f2bf(v.y), f2bf(v.z), f2bf(v.w) };
        ((ushort4*)out)[i] = o;
    }
}

// ------------------------------------------------------- weight transpose --
// W fp32 [K][N] -> WT bf16 [N][K]
__global__ __launch_bounds__(256) void transpose_w(const float* __restrict__ W,
    unsigned short* __restrict__ WT, int K, int N)
{
    __shared__ unsigned short ts[32][33];
    const int n0 = blockIdx.x * 32, k0 = blockIdx.y * 32;
    const int c = threadIdx.x & 31, rr = threadIdx.x >> 5;
#pragma unroll
    for (int i = 0; i < 4; i++) {
        int r = rr + i * 8;
        ts[c][r] = f2bf(W[(size_t)(k0 + r) * N + n0 + c]);
    }
    __syncthreads();
#pragma unroll
    for (int i = 0; i < 4; i++) {
        int rw = rr + i * 8;
        WT[(size_t)(n0 + rw) * K + k0 + c] = ts[rw][c];
    }
}

// 4x 768x768 weights (Wq,Wk,Wv,Wo) -> wt + z*589824
__global__ __launch_bounds__(256) void transpose_qkvo(const float* __restrict__ W0,
    const float* __restrict__ W1, const float* __restrict__ W2,
    const float* __restrict__ W3, unsigned short* __restrict__ WT)
{
    __shared__ unsigned short ts[32][33];
    const int z = blockIdx.z;
    const float* W = (z == 0) ? W0 : (z == 1) ? W1 : (z == 2) ? W2 : W3;
    unsigned short* out = WT + (size_t)z * 589824;
    const int n0 = blockIdx.x * 32, k0 = blockIdx.y * 32;
    const int c = threadIdx.x & 31, rr = threadIdx.x >> 5;
#pragma unroll
    for (int i = 0; i < 4; i++) {
        int r = rr + i * 8;
        ts[c][r] = f2bf(W[(size_t)(k0 + r) * CD + n0 + c]);
    }
    __syncthreads();
#pragma unroll
    for (int i = 0; i < 4; i++) {
        int rw = rr + i * 8;
        out[(size_t)(n0 + rw) * CD + k0 + c] = ts[rw][c];
    }
}

// ---------------------------------------------------------------- MFMA GEMM
// C[M,N] = A[M,K] @ B[K,N] + bias, B given transposed (BT bf16 [N][K]).
// BMODE: 0 single bias b0; 1 qkv split (768/1536); 2 dn+pq split (768).
constexpr int LSTR = 56;   // 32 + 24 pad

template<int A_BF16, int C_BF16, int ACT, int PKMM, int BMODE>
__global__ __launch_bounds__(256) void gemm_mfma(const void* __restrict__ Ag,
    const unsigned short* __restrict__ BT, const float* __restrict__ b0,
    void* __restrict__ Cg, int M, int N, int K, int lda, int ldc,
    const float* __restrict__ b1, const float* __restrict__ b2)
{
    __shared__ unsigned short As[128 * LSTR];
    __shared__ unsigned short Bs[128 * LSTR];
    const int tid = threadIdx.x;
    const int lane = tid & 63, w = tid >> 6;
    const int wr = w >> 1, wc = w & 1;
    const int l15 = lane & 15, l4 = lane >> 4;

    size_t aoff = 0, boff = 0, coff = 0;
    if (PKMM) {
        int z = blockIdx.z;
        aoff = (size_t)(z >> 1) * KD + (size_t)(z & 1) * HALF;
        boff = (size_t)z * NK * HALF;
        coff = (size_t)z * NK;
    }
    const int rowA0 = blockIdx.y * 128, rowB0 = blockIdx.x * 128;

    f32x4 acc[4][4];
#pragma unroll
    for (int i = 0; i < 4; i++)
#pragma unroll
        for (int j = 0; j < 4; j++) acc[i][j] = (f32x4){0.f, 0.f, 0.f, 0.f};

    const unsigned short* Abf = (const unsigned short*)Ag;
    const float* Af = (const float*)Ag;

    for (int k0 = 0; k0 < K; k0 += 32) {
#pragma unroll
        for (int it = 0; it < 2; ++it) {
            int e = it * 256 + tid;
            int r = e >> 2, c8 = e & 3;
            if (A_BF16) {
                uint4 v = *(const uint4*)(Abf + aoff + (size_t)(rowA0 + r) * lda + k0 + c8 * 8);
                *(uint4*)&As[r * LSTR + c8 * 8] = v;
            } else {
                const float* src = Af + aoff + (size_t)(rowA0 + r) * lda + k0 + c8 * 8;
                float4 v0 = *(const float4*)src;
                float4 v1 = *(const float4*)(src + 4);
                unsigned short t[8] = {f2bf(v0.x), f2bf(v0.y), f2bf(v0.z), f2bf(v0.w),
                                       f2bf(v1.x), f2bf(v1.y), f2bf(v1.z), f2bf(v1.w)};
                *(uint4*)&As[r * LSTR + c8 * 8] = *(uint4*)t;
            }
        }
#pragma unroll
        for (int it = 0; it < 2; ++it) {
            int e = it * 256 + tid;
            int r = e >> 2, c8 = e & 3;
            uint4 v = *(const uint4*)(BT + boff + (size_t)(rowB0 + r) * K + k0 + c8 * 8);
            *(uint4*)&Bs[r * LSTR + c8 * 8] = v;
        }
        __syncthreads();

        short8_t af[4], bf[4];
#pragma unroll
        for (int i = 0; i < 4; i++)
            af[i] = *(const short8_t*)&As[(wr * 64 + i * 16 + l15) * LSTR + l4 * 8];
#pragma unroll
        for (int j = 0; j < 4; j++)
            bf[j] = *(const short8_t*)&Bs[(wc * 64 + j * 16 + l15) * LSTR + l4 * 8];
#pragma unroll
        for (int i = 0; i < 4; i++)
#pragma unroll
            for (int j = 0; j < 4; j++)
                acc[i][j] = __builtin_amdgcn_mfma_f32_16x16x32_bf16(af[i], bf[j], acc[i][j], 0, 0, 0);
        __syncthreads();
    }

#pragma unroll
    for (int i = 0; i < 4; i++) {
#pragma unroll
        for (int j = 0; j < 4; j++) {
            const int row = rowA0 + wr * 64 + i * 16 + l4 * 4;
            const int col = rowB0 + wc * 64 + j * 16 + l15;
            float bv;
            if (PKMM) bv = 0.f;
            else if (BMODE == 0) bv = b0[col];
            else if (BMODE == 1) bv = (col < 768) ? b0[col] : (col < 1536 ? b1[col - 768] : b2[col - 1536]);
            else bv = (col < 768) ? b0[col] : b1[col - 768];
#pragma unroll
            for (int jj = 0; jj < 4; jj++) {
                float v = acc[i][j][jj] + bv;
                if (ACT == 1) v = 0.5f * v * (1.0f + erff(v * 0.70710678118654752f));
                if (C_BF16)
                    ((unsigned short*)Cg)[coff + (size_t)(row + jj) * ldc + col] = f2bf(v);
                else
                    ((float*)Cg)[coff + (size_t)(row + jj) * ldc + col] = v;
            }
        }
    }
}

// ----------------------------------------------------- MFMA flash attention
// qkv bf16 [2048][2304]; Q at col h*64, K at 768+h*64, V at 1536+h*64.
// Block: 64 queries x full 512 keys; 4 waves, wave w owns q rows w*16..+15.
constexpr int AST = 72;   // bf16 elem stride

__global__ __launch_bounds__(256) void attn_mfma(const unsigned short* __restrict__ qkv,
    unsigned short* __restrict__ ctx)
{
    __shared__ unsigned short Qs[64 * AST], Ks[64 * AST], Vt[64 * AST], Ss[64 * AST];
    const int tid = threadIdx.x, lane = tid & 63, w = tid >> 6;
    const int l15 = lane & 15, l4 = lane >> 4;
    const int h = blockIdx.y, b = blockIdx.z, q0 = blockIdx.x * 64;
    const int tb0 = b * CS;

    // stage Q (64x64 bf16)
#pragma unroll
    for (int it = 0; it < 2; ++it) {
        int e = it * 256 + tid, r = e >> 3, c = e & 7;
        *(uint4*)&Qs[r * AST + c * 8] =
            *(const uint4*)&qkv[(size_t)(tb0 + q0 + r) * 2304 + h * 64 + c * 8];
    }
    f32x4 accO[4];
    float mreg[4], lreg[4];
#pragma unroll
    for (int j = 0; j < 4; j++) accO[j] = (f32x4){0.f, 0.f, 0.f, 0.f};
#pragma unroll
    for (int r = 0; r < 4; r++) { mreg[r] = -1e30f; lreg[r] = 0.f; }
    __syncthreads();
    const short8_t aq0 = *(const short8_t*)&Qs[(w * 16 + l15) * AST + l4 * 8];
    const short8_t aq1 = *(const short8_t*)&Qs[(w * 16 + l15) * AST + 32 + l4 * 8];

    for (int kt = 0; kt < 8; ++kt) {
        __syncthreads();   // previous tile fully consumed
        // stage K (linear) and V (transposed, chunk-rotated)
#pragma unroll
        for (int it = 0; it < 2; ++it) {
            int e = it * 256 + tid, r = e >> 3, c = e & 7;
            *(uint4*)&Ks[r * AST + c * 8] =
                *(const uint4*)&qkv[(size_t)(tb0 + kt * 64 + r) * 2304 + 768 + h * 64 + c * 8];
            uint4 vv = *(const uint4*)&qkv[(size_t)(tb0 + kt * 64 + r) * 2304 + 1536 + h * 64 + c * 8];
            const unsigned short* pv = (const unsigned short*)&vv;
            const int rc = (((r >> 3) + c) & 7) * 8 + (r & 7);
#pragma unroll
            for (int e2 = 0; e2 < 8; ++e2)
                Vt[(c * 8 + e2) * AST + rc] = pv[e2];
        }
        __syncthreads();

        // scores S = Q K^T
        f32x4 sc[4];
#pragma unroll
        for (int j = 0; j < 4; j++) sc[j] = (f32x4){0.f, 0.f, 0.f, 0.f};
#pragma unroll
        for (int j = 0; j < 4; j++) {
            short8_t bk0 = *(const short8_t*)&Ks[(j * 16 + l15) * AST + l4 * 8];
            short8_t bk1 = *(const short8_t*)&Ks[(j * 16 + l15) * AST + 32 + l4 * 8];
            sc[j] = __builtin_amdgcn_mfma_f32_16x16x32_bf16(aq0, bk0, sc[j], 0, 0, 0);
            sc[j] = __builtin_amdgcn_mfma_f32_16x16x32_bf16(aq1, bk1, sc[j], 0, 0, 0);
        }

        // online softmax (row q = w*16 + l4*4 + r; 16-lane l15-group holds the row)
        float cf[4];
#pragma unroll
        for (int r = 0; r < 4; r++) {
            float s0 = sc[0][r] * 0.125f, s1 = sc[1][r] * 0.125f;
            float s2 = sc[2][r] * 0.125f, s3 = sc[3][r] * 0.125f;
            float mt = fmaxf(fmaxf(s0, s1), fmaxf(s2, s3));
            mt = fmaxf(mt, __shfl_xor(mt, 1));
            mt = fmaxf(mt, __shfl_xor(mt, 2));
            mt = fmaxf(mt, __shfl_xor(mt, 4));
            mt = fmaxf(mt, __shfl_xor(mt, 8));
            float mo = mreg[r], mn = fmaxf(mo, mt);
            float c = __expf(mo - mn);
            mreg[r] = mn; cf[r] = c;
            float p0 = __expf(s0 - mn), p1 = __expf(s1 - mn);
            float p2 = __expf(s2 - mn), p3 = __expf(s3 - mn);
            float ps = p0 + p1 + p2 + p3;
            ps += __shfl_xor(ps, 1);
            ps += __shfl_xor(ps, 2);
            ps += __shfl_xor(ps, 4);
            ps += __shfl_xor(ps, 8);
            lreg[r] = lreg[r] * c + ps;
            const int qrow = (w * 16 + l4 * 4 + r) * AST;
            Ss[qrow + l15]      = f2bf(p0);
            Ss[qrow + 16 + l15] = f2bf(p1);
            Ss[qrow + 32 + l15] = f2bf(p2);
            Ss[qrow + 48 + l15] = f2bf(p3);
        }
#pragma unroll
        for (int j = 0; j < 4; j++) {
            accO[j][0] *= cf[0]; accO[j][1] *= cf[1];
            accO[j][2] *= cf[2]; accO[j][3] *= cf[3];
        }

        // PV: O += P V (wave-private Ss rows; no barrier needed)
        const short8_t ap0 = *(const short8_t*)&Ss[(w * 16 + l15) * AST + l4 * 8];
        const short8_t ap1 = *(const short8_t*)&Ss[(w * 16 + l15) * AST + 32 + l4 * 8];
#pragma unroll
        for (int j = 0; j < 4; j++) {
            const int d = j * 16 + l15, dc = d >> 3;
            short8_t bv0 = *(const short8_t*)&Vt[d * AST + (((l4    ) + dc) & 7) * 8];
            short8_t bv1 = *(const short8_t*)&Vt[d * AST + (((l4 + 4) + dc) & 7) * 8];
            accO[j] = __builtin_amdgcn_mfma_f32_16x16x32_bf16(ap0, bv0, accO[j], 0, 0, 0);
            accO[j] = __builtin_amdgcn_mfma_f32_16x16x32_bf16(ap1, bv1, accO[j], 0, 0, 0);
        }
    }

    float inv[4];
#pragma unroll
    for (int r = 0; r < 4; r++) inv[r] = 1.0f / lreg[r];
#pragma unroll
    for (int j = 0; j < 4; j++)
#pragma unroll
        for (int r = 0; r < 4; r++)
            ctx[(size_t)(tb0 + q0 + w * 16 + l4 * 4 + r) * CD + h * 64 + j * 16 + l15] =
                f2bf(accO[j][r] * inv[r]);
}

// ----------------------------------------------------------- layernorm ----
__global__ __launch_bounds__(256) void ln_kernel(float* __restrict__ out,
    unsigned short* __restrict__ outb,
    const float* __restrict__ a, int lda,
    const float* __restrict__ b2, const float* __restrict__ c,
    const float* __restrict__ g, const float* __restrict__ bb)
{
    const int t = blockIdx.x, tid = threadIdx.x;
    __shared__ float buf[CD];
    __shared__ float red[256];
    float l = 0.f;
    for (int d = tid; d < CD; d += 256) {
        float v = a[(size_t)t * lda + d];
        if (b2) v += b2[(size_t)t * CD + d];
        if (c)  v += c[(size_t)t * CD + d];
        buf[d] = v; l += v;
    }
    red[tid] = l; __syncthreads();
    for (int o = 128; o > 0; o >>= 1) { if (tid < o) red[tid] += red[tid + o]; __syncthreads(); }
    const float mean = red[0] * (1.0f / CD); __syncthreads();
    float l2 = 0.f;
    for (int d = tid; d < CD; d += 256) { float dd = buf[d] - mean; l2 += dd * dd; }
    red[tid] = l2; __syncthreads();
    for (int o = 128; o > 0; o >>= 1) { if (tid < o) red[tid] += red[tid + o]; __syncthreads(); }
    const float inv = rsqrtf(red[0] * (1.0f / CD) + 1e-12f);
    for (int d = tid; d < CD; d += 256) {
        float v = (buf[d] - mean) * inv * g[d] + bb[d];
        out[(size_t)t * CD + d] = v;
        if (outb) outb[(size_t)t * CD + d] = f2bf(v);
    }
}

// --------------------------------------------- fused PKM top-k (both stages)
__device__ const unsigned char CCNT[32] = {32,16,10,8,6,5,4,4,3,3,2,2,2,2,2,2,
                                           1,1,1,1,1,1,1,1,1,1,1,1,1,1,1,1};

__global__ __launch_bounds__(128) void pkm_topk_kernel(const float* __restrict__ sc,
    float* __restrict__ w, int* __restrict__ ind)
{
    const int gid = blockIdx.x;            // t*PH + h
    const int tid = threadIdx.x;
    __shared__ float sv[256];
    __shared__ int   si_[256];
    __shared__ float cv[128];
    __shared__ int   ci[128];

    const float* s = sc + (size_t)gid * 256;
    sv[tid] = s[tid];             si_[tid] = tid;
    sv[tid + 128] = s[tid + 128]; si_[tid + 128] = tid;
    __syncthreads();

    for (int k = 2; k <= 128; k <<= 1) {
        for (int j = k >> 1; j > 0; j >>= 1) {
            const int hh = tid >> 6, p = tid & 63;
            const int i = ((p & ~(j - 1)) << 1) | (p & (j - 1));
            const int l = i | j;
            const int bi_ = hh * 128 + i, bl = hh * 128 + l;
            float av = sv[bi_], bv2 = sv[bl];
            int   ai = si_[bi_], bx = si_[bl];
            const bool agtb = (av > bv2) || (av == bv2 && ai < bx);
            const bool desc = ((i & k) == 0);
            if (agtb != desc) { sv[bi_] = bv2; sv[bl] = av; si_[bi_] = bx; si_[bl] = ai; }
            __syncthreads();
        }
    }

    {
        float val; int fi;
        if (tid < 119) {
            int tt = tid, ii = 0;
            while (tt >= (int)CCNT[ii]) { tt -= CCNT[ii]; ii++; }
            val = sv[ii] + sv[128 + tt];
            fi = ii * 32 + tt;
        } else { val = -3.0e38f; fi = 0x7FFFFFF; }
        cv[tid] = val; ci[tid] = fi;
    }
    __syncthreads();

    for (int k = 2; k <= 128; k <<= 1) {
        for (int j = k >> 1; j > 0; j >>= 1) {
            if (tid < 64) {
                const int p = tid;
                const int i = ((p & ~(j - 1)) << 1) | (p & (j - 1));
                const int l = i | j;
                float av = cv[i], bv2 = cv[l];
                int   ai = ci[i], bx = ci[l];
                const bool agtb = (av > bv2) || (av == bv2 && ai < bx);
                const bool desc = ((i & k) == 0);
                if (agtb != desc) { cv[i] = bv2; cv[l] = av; ci[i] = bx; ci[l] = ai; }
            }
            __syncthreads();
        }
    }

    if (tid < 32) {
        const float mx = cv[0];
        float e = __expf(cv[tid] - mx);
        float s2 = e;
        for (int o = 16; o > 0; o >>= 1) s2 += __shfl_xor(s2, o);
        const int fi = ci[tid];
        const int ii = fi >> 5, jj = fi & 31;
        w[(size_t)gid * KNN + tid] = e / s2;
        ind[(size_t)gid * KNN + tid] = si_[ii] * NK + si_[128 + jj];
    }
}

// --------------------------------------------------------- PKM gather -----
// block per token, 384 threads; thread owns 2 dims; values bf16.
__global__ __launch_bounds__(384) void pkm_gather_kernel(const float* __restrict__ w,
    const int* __restrict__ ind, const unsigned short* __restrict__ valb,
    float* __restrict__ out)
{
    const int t = blockIdx.x, tid = threadIdx.x;
    __shared__ float ws[PH * KNN];
    __shared__ int   is[PH * KNN];
    if (tid < PH * KNN) {
        ws[tid] = w[(size_t)t * PH * KNN + tid];
        is[tid] = ind[(size_t)t * PH * KNN + tid];
    }
    __syncthreads();
    const int d0 = tid * 2;
    float a0 = 0.f, a1 = 0.f;
#pragma unroll 4
    for (int i = 0; i < PH * KNN; i++) {
        unsigned pv = *(const unsigned*)&valb[(size_t)is[i] * CD + d0];
        float wi = ws[i];
        a0 = fmaf(wi, bf2f((unsigned short)(pv & 0xffff)), a0);
        a1 = fmaf(wi, bf2f((unsigned short)(pv >> 16)), a1);
    }
    out[(size_t)t * CD + d0] = a0;
    out[(size_t)t * CD + d0 + 1] = a1;
}

// ------------------------------------------------------------- launch -----
extern "C" void kernel_launch(void* const* d_in, const int* in_sizes, int n_in,
                              void* d_out, int out_size, void* d_ws, size_t ws_size,
                              hipStream_t stream)
{
    const float* x      = (const float*)d_in[0];
    const float* Wq     = (const float*)d_in[1];
    const float* bq     = (const float*)d_in[2];
    const float* Wk     = (const float*)d_in[3];
    const float* bk     = (const float*)d_in[4];
    const float* Wv     = (const float*)d_in[5];
    const float* bv     = (const float*)d_in[6];
    const float* Wo     = (const float*)d_in[7];
    const float* bo     = (const float*)d_in[8];
    const float* ln1_g  = (const float*)d_in[9];
    const float* ln1_b  = (const float*)d_in[10];
    const float* Wi     = (const float*)d_in[11];
    const float* bi     = (const float*)d_in[12];
    const float* Wd     = (const float*)d_in[13];
    const float* bd     = (const float*)d_in[14];
    const float* ln2_g  = (const float*)d_in[15];
    const float* ln2_b  = (const float*)d_in[16];
    const float* Wpq    = (const float*)d_in[17];
    const float* bpq    = (const float*)d_in[18];
    const float* keys   = (const float*)d_in[19];
    const float* values = (const float*)d_in[20];

    char* W = (char*)d_ws;
    // region A: qkv bf16 (9.44MB) -> sbuf fp32 (8.39MB) -> pkm_out fp32 (6.29MB)
    unsigned short* qkvb  = (unsigned short*)(W + 0);
    float*          sbuf  = (float*)(W + 0);
    float*          pkmo  = (float*)(W + 0);
    // region B: attn fp32 (6.29MB), alive LN1..LN2
    float*          attnf = (float*)(W + 9437184);
    // region C: ctx bf16 (3.1MB) -> inter bf16 (12.58MB) -> wgt/ind (2MB)
    unsigned short* ctxb  = (unsigned short*)(W + 15728640);
    unsigned short* interb= (unsigned short*)(W + 15728640);
    float*          wgt   = (float*)(W + 15728640);
    int*            ind   = (int*)(W + 15728640 + 1048576);
    // region G (23.07MB): xb / wo_out (@0), attnb (@6.29MB), then tmp [2048][2816] fp32
    unsigned short* xb    = (unsigned short*)(W + 28311552);
    float*          woout = (float*)(W + 28311552);
    float*          tmp   = (float*)(W + 28311552);
    unsigned short* attnb = (unsigned short*)(W + 28311552 + 6291456);
    // keysb bf16 (0.5MB)
    unsigned short* keysb = (unsigned short*)(W + 51380224);
    // wt bf16 (26.74MB) -> valb bf16 (25.17MB)
    unsigned short* wt    = (unsigned short*)(W + 51904512);
    unsigned short* valb  = (unsigned short*)(W + 51904512);

    const dim3 blk(256);
    const size_t WOFF = 589824;   // 768*768

    // input conversions
    cvt_bf16x4<<<2048, blk, 0, stream>>>(x, xb, CT * CD / 4);
    cvt_bf16x4<<<256, blk, 0, stream>>>(keys, keysb, (PH * 2 * NK * HALF) / 4);

    // weight transposes (all upfront, distinct wt sub-regions)
    transpose_qkvo<<<dim3(24, 24, 4), blk, 0, stream>>>(Wq, Wk, Wv, Wo, wt);
    transpose_w<<<dim3(96, 24), blk, 0, stream>>>(Wi,  wt + 4 * WOFF, CD, CFF);
    transpose_w<<<dim3(24, 96), blk, 0, stream>>>(Wd,  wt + 4 * WOFF + 2359296, CFF, CD);
    transpose_w<<<dim3(64, 96), blk, 0, stream>>>(Wpq, wt + 4 * WOFF + 2 * 2359296, CFF, PH * KD);

    // merged QKV projection: [2048][2304] bf16
    gemm_mfma<1, 1, 0, 0, 1><<<dim3(18, 16), blk, 0, stream>>>(
        xb, wt, bq, qkvb, CT, 2304, CD, CD, 2304, bk, bv);

    // flash attention (MFMA)
    attn_mfma<<<dim3(8, 12, 4), blk, 0, stream>>>(qkvb, ctxb);

    // output projection + LN1 (dual fp32 + bf16 out)
    gemm_mfma<1, 0, 0, 0, 0><<<dim3(6, 16), blk, 0, stream>>>(
        ctxb, wt + 3 * WOFF, bo, woout, CT, CD, CD, CD, CD, nullptr, nullptr);
    ln_kernel<<<CT, blk, 0, stream>>>(attnf, attnb, woout, CD, x, nullptr, ln1_g, ln1_b);

    // FFN up (GELU, bf16 out)
    gemm_mfma<1, 1, 1, 0, 0><<<dim3(24, 16), blk, 0, stream>>>(
        attnb, wt + 4 * WOFF, bi, interb, CT, CFF, CD, CD, CFF, nullptr, nullptr);

    // merged FFN down + PKM query proj: [2048][2816] fp32 (dense cols 0..767, pq 768..2815)
    gemm_mfma<1, 0, 0, 0, 2><<<dim3(22, 16), blk, 0, stream>>>(
        interb, wt + 4 * WOFF + 2359296, bd, tmp, CT, 2816, CFF, CFF, 2816, bpq, nullptr);

    // values -> bf16 (into dead wt region)
    cvt_bf16x4<<<2048, blk, 0, stream>>>(values, valb, (NK * NK * CD) / 4);

    // PKM scores: 8 batched GEMMs (z = h*2+half), A = pq columns of tmp
    gemm_mfma<0, 0, 0, 1, 0><<<dim3(1, 16, 8), blk, 0, stream>>>(
        tmp + 768, keysb, nullptr, sbuf, CT, NK, HALF, 2816, PH * 2 * NK, nullptr, nullptr);

    // fused two-stage top-k + softmax
    pkm_topk_kernel<<<CT * PH, dim3(128), 0, stream>>>(sbuf, wgt, ind);

    // gather (bf16 values)
    pkm_gather_kernel<<<CT, dim3(384), 0, stream>>>(wgt, ind, valb, pkmo);

    // final LN over dense(lda 2816) + pkm + attn
    ln_kernel<<<CT, blk, 0, stream>>>((float*)d_out, nullptr, tmp, 2816, pkmo, attnf, ln2_g, ln2_b);
}

// Round 5
// 312.569 us; speedup vs baseline: 12.3479x; 1.0714x over previous
//
#include <hip/hip_runtime.h>
#include <math.h>

// Problem constants
constexpr int CB = 4, CS = 512, CD = 768, CFF = 3072, CH = 12, CHD = 64;
constexpr int CT = CB * CS;            // 2048 tokens
constexpr int PH = 4, KD = 512, NK = 128, KNN = 32, HALF = 256;

typedef __attribute__((ext_vector_type(8))) short short8_t;   // 8 bf16 (4 VGPRs)
typedef __attribute__((ext_vector_type(4))) float f32x4;      // MFMA accumulator

__device__ __forceinline__ unsigned short f2bf(float f) {
    unsigned int u = __float_as_uint(f);
    return (unsigned short)((u + 0x7FFF + ((u >> 16) & 1)) >> 16);  // RNE
}
__device__ __forceinline__ float bf2f(unsigned short h) {
    return __uint_as_float(((unsigned)h) << 16);
}

// async global->LDS, 16B per lane; LDS dest = wave-uniform base + lane*16
__device__ __forceinline__ void ld_lds16(const unsigned short* g, unsigned short* l) {
    __builtin_amdgcn_global_load_lds(
        (const __attribute__((address_space(1))) void*)g,
        (__attribute__((address_space(3))) void*)l, 16, 0, 0);
}

// ------------------------------------------------------------ fp32->bf16 --
__global__ __launch_bounds__(256) void cvt_bf16x4(const float* __restrict__ in,
    unsigned short* __restrict__ out, int n4)
{
    for (int i = blockIdx.x * 256 + threadIdx.x; i < n4; i += gridDim.x * 256) {
        float4 v = ((const float4*)in)[i];
        ushort4 o = { f2bf(v.x), f2bf(v.y), f2bf(v.z), f2bf(v.w) };
        ((ushort4*)out)[i] = o;
    }
}

// ------------------------------------------------------- weight transpose --
// W fp32 [K][N] -> WT bf16 [N][K]
__global__ __launch_bounds__(256) void transpose_w(const float* __restrict__ W,
    unsigned short* __restrict__ WT, int K, int N)
{
    __shared__ unsigned short ts[32][33];
    const int n0 = blockIdx.x * 32, k0 = blockIdx.y * 32;
    const int c = threadIdx.x & 31, rr = threadIdx.x >> 5;
#pragma unroll
    for (int i = 0; i < 4; i++) {
        int r = rr + i * 8;
        ts[c][r] = f2bf(W[(size_t)(k0 + r) * N + n0 + c]);
    }
    __syncthreads();
#pragma unroll
    for (int i = 0; i < 4; i++) {
        int rw = rr + i * 8;
        WT[(size_t)(n0 + rw) * K + k0 + c] = ts[rw][c];
    }
}

// 4x 768x768 weights (Wq,Wk,Wv,Wo) -> wt + z*589824
__global__ __launch_bounds__(256) void transpose_qkvo(const float* __restrict__ W0,
    const float* __restrict__ W1, const float* __restrict__ W2,
    const float* __restrict__ W3, unsigned short* __restrict__ WT)
{
    __shared__ unsigned short ts[32][33];
    const int z = blockIdx.z;
    const float* W = (z == 0) ? W0 : (z == 1) ? W1 : (z == 2) ? W2 : W3;
    unsigned short* out = WT + (size_t)z * 589824;
    const int n0 = blockIdx.x * 32, k0 = blockIdx.y * 32;
    const int c = threadIdx.x & 31, rr = threadIdx.x >> 5;
#pragma unroll
    for (int i = 0; i < 4; i++) {
        int r = rr + i * 8;
        ts[c][r] = f2bf(W[(size_t)(k0 + r) * CD + n0 + c]);
    }
    __syncthreads();
#pragma unroll
    for (int i = 0; i < 4; i++) {
        int rw = rr + i * 8;
        out[(size_t)(n0 + rw) * CD + k0 + c] = ts[rw][c];
    }
}

// ----------------------------------------------------- MFMA GEMM (m97-style)
// C[M,N] = A[M,K] @ B[K,N] + bias; A bf16 [M][lda], BT bf16 [N][K].
// Direct-to-LDS staging (global_load_lds x16), linear LDS [rows][32] with
// both-sides chunk-XOR swizzle (chunk ^= row&3) to spread read banks.
// TM: 64 or 128 (N tile fixed 128). CMODE: 0 fp32 C, 1 bf16 C, 2 split
// (col<768 -> fp32 Cg ldc, else bf16 Cg2 ldc2). ACT==1: exact GELU.
// PKMM: blockIdx.z batches (h,half) for PKM scores.
template<int TM, int CMODE, int ACT, int PKMM, int BMODE>
__global__ __launch_bounds__(256) void gemm_lds(
    const unsigned short* __restrict__ A, const unsigned short* __restrict__ BT,
    const float* __restrict__ b0, const float* __restrict__ b1,
    const float* __restrict__ b2,
    void* __restrict__ Cg, void* __restrict__ Cg2,
    int M, int N, int K, int lda, int ldc, int ldc2)
{
    __shared__ unsigned short As[TM * 32];
    __shared__ unsigned short Bs[128 * 32];
    const int tid = threadIdx.x, lane = tid & 63, w = tid >> 6;
    const int l15 = lane & 15, l4 = lane >> 4;
    const int wr = w >> 1, wc = w & 1;
    constexpr int NI = TM / 32;            // A fragments per wave

    size_t aoff = 0, boff = 0, coff = 0;
    if (PKMM) {
        int z = blockIdx.z;
        aoff = (size_t)(z >> 1) * KD + (size_t)(z & 1) * HALF;
        boff = (size_t)z * NK * HALF;
        coff = (size_t)z * NK;
    }
    const int rowA0 = blockIdx.y * TM, rowB0 = blockIdx.x * 128;

    // staging lane pattern: lane -> (row sr, chunk sc); fetch global chunk scg
    const int sr = lane >> 2, sc = lane & 3;
    const int scg = sc ^ (sr & 3);

    f32x4 acc[NI][4];
#pragma unroll
    for (int i = 0; i < NI; i++)
#pragma unroll
        for (int j = 0; j < 4; j++) acc[i][j] = (f32x4){0.f, 0.f, 0.f, 0.f};

    const int rdc = (l4 ^ (l15 & 3)) * 8;   // swizzled read chunk offset (elems)

    for (int k0 = 0; k0 < K; k0 += 32) {
        // ---- stage A
        if (TM == 128) {
#pragma unroll
            for (int i = 0; i < 2; i++) {
                const int r0 = w * 32 + i * 16;
                ld_lds16(&A[aoff + (size_t)(rowA0 + r0 + sr) * lda + k0 + scg * 8],
                         &As[r0 * 32]);
            }
        } else {
            const int r0 = w * 16;
            ld_lds16(&A[aoff + (size_t)(rowA0 + r0 + sr) * lda + k0 + scg * 8],
                     &As[r0 * 32]);
        }
        // ---- stage B
#pragma unroll
        for (int i = 0; i < 2; i++) {
            const int r0 = w * 32 + i * 16;
            ld_lds16(&BT[boff + (size_t)(rowB0 + r0 + sr) * K + k0 + scg * 8],
                     &Bs[r0 * 32]);
        }
        __syncthreads();   // drains vmcnt (compiler emits full waitcnt)

        short8_t af[NI], bf[4];
#pragma unroll
        for (int i = 0; i < NI; i++)
            af[i] = *(const short8_t*)&As[(wr * (TM / 2) + i * 16 + l15) * 32 + rdc];
#pragma unroll
        for (int j = 0; j < 4; j++)
            bf[j] = *(const short8_t*)&Bs[(wc * 64 + j * 16 + l15) * 32 + rdc];
#pragma unroll
        for (int i = 0; i < NI; i++)
#pragma unroll
            for (int j = 0; j < 4; j++)
                acc[i][j] = __builtin_amdgcn_mfma_f32_16x16x32_bf16(af[i], bf[j], acc[i][j], 0, 0, 0);
        __syncthreads();
    }

    // ---- epilogue; D: col=lane&15, row=(lane>>4)*4+reg
#pragma unroll
    for (int i = 0; i < NI; i++) {
#pragma unroll
        for (int j = 0; j < 4; j++) {
            const int row = rowA0 + wr * (TM / 2) + i * 16 + l4 * 4;
            const int col = rowB0 + wc * 64 + j * 16 + l15;
            float bv;
            if (PKMM) bv = 0.f;
            else if (BMODE == 0) bv = b0[col];
            else if (BMODE == 1) bv = (col < 768) ? b0[col] : (col < 1536 ? b1[col - 768] : b2[col - 1536]);
            else bv = (col < 768) ? b0[col] : b1[col - 768];
#pragma unroll
            for (int jj = 0; jj < 4; jj++) {
                float v = acc[i][j][jj] + bv;
                if (ACT == 1) v = 0.5f * v * (1.0f + erff(v * 0.70710678118654752f));
                if (CMODE == 0)
                    ((float*)Cg)[coff + (size_t)(row + jj) * ldc + col] = v;
                else if (CMODE == 1)
                    ((unsigned short*)Cg)[coff + (size_t)(row + jj) * ldc + col] = f2bf(v);
                else {
                    if (col < 768)
                        ((float*)Cg)[(size_t)(row + jj) * ldc + col] = v;
                    else
                        ((unsigned short*)Cg2)[(size_t)(row + jj) * ldc2 + (col - 768)] = f2bf(v);
                }
            }
        }
    }
}

// ----------------------------------------------------- MFMA flash attention
constexpr int AST = 72;   // bf16 elem stride

__global__ __launch_bounds__(256) void attn_mfma(const unsigned short* __restrict__ qkv,
    unsigned short* __restrict__ ctx)
{
    __shared__ unsigned short Qs[64 * AST], Ks[64 * AST], Vt[64 * AST], Ss[64 * AST];
    const int tid = threadIdx.x, lane = tid & 63, w = tid >> 6;
    const int l15 = lane & 15, l4 = lane >> 4;
    const int h = blockIdx.y, b = blockIdx.z, q0 = blockIdx.x * 64;
    const int tb0 = b * CS;

#pragma unroll
    for (int it = 0; it < 2; ++it) {
        int e = it * 256 + tid, r = e >> 3, c = e & 7;
        *(uint4*)&Qs[r * AST + c * 8] =
            *(const uint4*)&qkv[(size_t)(tb0 + q0 + r) * 2304 + h * 64 + c * 8];
    }
    f32x4 accO[4];
    float mreg[4], lreg[4];
#pragma unroll
    for (int j = 0; j < 4; j++) accO[j] = (f32x4){0.f, 0.f, 0.f, 0.f};
#pragma unroll
    for (int r = 0; r < 4; r++) { mreg[r] = -1e30f; lreg[r] = 0.f; }
    __syncthreads();
    const short8_t aq0 = *(const short8_t*)&Qs[(w * 16 + l15) * AST + l4 * 8];
    const short8_t aq1 = *(const short8_t*)&Qs[(w * 16 + l15) * AST + 32 + l4 * 8];

    for (int kt = 0; kt < 8; ++kt) {
        __syncthreads();
#pragma unroll
        for (int it = 0; it < 2; ++it) {
            int e = it * 256 + tid, r = e >> 3, c = e & 7;
            *(uint4*)&Ks[r * AST + c * 8] =
                *(const uint4*)&qkv[(size_t)(tb0 + kt * 64 + r) * 2304 + 768 + h * 64 + c * 8];
            uint4 vv = *(const uint4*)&qkv[(size_t)(tb0 + kt * 64 + r) * 2304 + 1536 + h * 64 + c * 8];
            const unsigned short* pv = (const unsigned short*)&vv;
            const int rc = (((r >> 3) + c) & 7) * 8 + (r & 7);
#pragma unroll
            for (int e2 = 0; e2 < 8; ++e2)
                Vt[(c * 8 + e2) * AST + rc] = pv[e2];
        }
        __syncthreads();

        f32x4 sc[4];
#pragma unroll
        for (int j = 0; j < 4; j++) sc[j] = (f32x4){0.f, 0.f, 0.f, 0.f};
#pragma unroll
        for (int j = 0; j < 4; j++) {
            short8_t bk0 = *(const short8_t*)&Ks[(j * 16 + l15) * AST + l4 * 8];
            short8_t bk1 = *(const short8_t*)&Ks[(j * 16 + l15) * AST + 32 + l4 * 8];
            sc[j] = __builtin_amdgcn_mfma_f32_16x16x32_bf16(aq0, bk0, sc[j], 0, 0, 0);
            sc[j] = __builtin_amdgcn_mfma_f32_16x16x32_bf16(aq1, bk1, sc[j], 0, 0, 0);
        }

        float cf[4];
#pragma unroll
        for (int r = 0; r < 4; r++) {
            float s0 = sc[0][r] * 0.125f, s1 = sc[1][r] * 0.125f;
            float s2 = sc[2][r] * 0.125f, s3 = sc[3][r] * 0.125f;
            float mt = fmaxf(fmaxf(s0, s1), fmaxf(s2, s3));
            mt = fmaxf(mt, __shfl_xor(mt, 1));
            mt = fmaxf(mt, __shfl_xor(mt, 2));
            mt = fmaxf(mt, __shfl_xor(mt, 4));
            mt = fmaxf(mt, __shfl_xor(mt, 8));
            float mo = mreg[r], mn = fmaxf(mo, mt);
            float c = __expf(mo - mn);
            mreg[r] = mn; cf[r] = c;
            float p0 = __expf(s0 - mn), p1 = __expf(s1 - mn);
            float p2 = __expf(s2 - mn), p3 = __expf(s3 - mn);
            float ps = p0 + p1 + p2 + p3;
            ps += __shfl_xor(ps, 1);
            ps += __shfl_xor(ps, 2);
            ps += __shfl_xor(ps, 4);
            ps += __shfl_xor(ps, 8);
            lreg[r] = lreg[r] * c + ps;
            const int qrow = (w * 16 + l4 * 4 + r) * AST;
            Ss[qrow + l15]      = f2bf(p0);
            Ss[qrow + 16 + l15] = f2bf(p1);
            Ss[qrow + 32 + l15] = f2bf(p2);
            Ss[qrow + 48 + l15] = f2bf(p3);
        }
#pragma unroll
        for (int j = 0; j < 4; j++) {
            accO[j][0] *= cf[0]; accO[j][1] *= cf[1];
            accO[j][2] *= cf[2]; accO[j][3] *= cf[3];
        }

        const short8_t ap0 = *(const short8_t*)&Ss[(w * 16 + l15) * AST + l4 * 8];
        const short8_t ap1 = *(const short8_t*)&Ss[(w * 16 + l15) * AST + 32 + l4 * 8];
#pragma unroll
        for (int j = 0; j < 4; j++) {
            const int d = j * 16 + l15, dc = d >> 3;
            short8_t bv0 = *(const short8_t*)&Vt[d * AST + (((l4    ) + dc) & 7) * 8];
            short8_t bv1 = *(const short8_t*)&Vt[d * AST + (((l4 + 4) + dc) & 7) * 8];
            accO[j] = __builtin_amdgcn_mfma_f32_16x16x32_bf16(ap0, bv0, accO[j], 0, 0, 0);
            accO[j] = __builtin_amdgcn_mfma_f32_16x16x32_bf16(ap1, bv1, accO[j], 0, 0, 0);
        }
    }

    float inv[4];
#pragma unroll
    for (int r = 0; r < 4; r++) inv[r] = 1.0f / lreg[r];
#pragma unroll
    for (int j = 0; j < 4; j++)
#pragma unroll
        for (int r = 0; r < 4; r++)
            ctx[(size_t)(tb0 + q0 + w * 16 + l4 * 4 + r) * CD + h * 64 + j * 16 + l15] =
                f2bf(accO[j][r] * inv[r]);
}

// ----------------------------------------------------------- layernorm ----
__global__ __launch_bounds__(256) void ln_kernel(float* __restrict__ out,
    unsigned short* __restrict__ outb,
    const float* __restrict__ a, int lda,
    const float* __restrict__ b2, const float* __restrict__ c,
    const float* __restrict__ g, const float* __restrict__ bb)
{
    const int t = blockIdx.x, tid = threadIdx.x;
    __shared__ float buf[CD];
    __shared__ float red[256];
    float l = 0.f;
    for (int d = tid; d < CD; d += 256) {
        float v = a[(size_t)t * lda + d];
        if (b2) v += b2[(size_t)t * CD + d];
        if (c)  v += c[(size_t)t * CD + d];
        buf[d] = v; l += v;
    }
    red[tid] = l; __syncthreads();
    for (int o = 128; o > 0; o >>= 1) { if (tid < o) red[tid] += red[tid + o]; __syncthreads(); }
    const float mean = red[0] * (1.0f / CD); __syncthreads();
    float l2 = 0.f;
    for (int d = tid; d < CD; d += 256) { float dd = buf[d] - mean; l2 += dd * dd; }
    red[tid] = l2; __syncthreads();
    for (int o = 128; o > 0; o >>= 1) { if (tid < o) red[tid] += red[tid + o]; __syncthreads(); }
    const float inv = rsqrtf(red[0] * (1.0f / CD) + 1e-12f);
    for (int d = tid; d < CD; d += 256) {
        float v = (buf[d] - mean) * inv * g[d] + bb[d];
        out[(size_t)t * CD + d] = v;
        if (outb) outb[(size_t)t * CD + d] = f2bf(v);
    }
}

// --------------------------------------------- fused PKM top-k (both stages)
__device__ const unsigned char CCNT[32] = {32,16,10,8,6,5,4,4,3,3,2,2,2,2,2,2,
                                           1,1,1,1,1,1,1,1,1,1,1,1,1,1,1,1};

__global__ __launch_bounds__(128) void pkm_topk_kernel(const float* __restrict__ sc,
    float* __restrict__ w, int* __restrict__ ind)
{
    const int gid = blockIdx.x;            // t*PH + h
    const int tid = threadIdx.x;
    __shared__ float sv[256];
    __shared__ int   si_[256];
    __shared__ float cv[128];
    __shared__ int   ci[128];

    const float* s = sc + (size_t)gid * 256;
    sv[tid] = s[tid];             si_[tid] = tid;
    sv[tid + 128] = s[tid + 128]; si_[tid + 128] = tid;
    __syncthreads();

    for (int k = 2; k <= 128; k <<= 1) {
        for (int j = k >> 1; j > 0; j >>= 1) {
            const int hh = tid >> 6, p = tid & 63;
            const int i = ((p & ~(j - 1)) << 1) | (p & (j - 1));
            const int l = i | j;
            const int bi_ = hh * 128 + i, bl = hh * 128 + l;
            float av = sv[bi_], bv2 = sv[bl];
            int   ai = si_[bi_], bx = si_[bl];
            const bool agtb = (av > bv2) || (av == bv2 && ai < bx);
            const bool desc = ((i & k) == 0);
            if (agtb != desc) { sv[bi_] = bv2; sv[bl] = av; si_[bi_] = bx; si_[bl] = ai; }
            __syncthreads();
        }
    }

    {
        float val; int fi;
        if (tid < 119) {
            int tt = tid, ii = 0;
            while (tt >= (int)CCNT[ii]) { tt -= CCNT[ii]; ii++; }
            val = sv[ii] + sv[128 + tt];
            fi = ii * 32 + tt;
        } else { val = -3.0e38f; fi = 0x7FFFFFF; }
        cv[tid] = val; ci[tid] = fi;
    }
    __syncthreads();

    for (int k = 2; k <= 128; k <<= 1) {
        for (int j = k >> 1; j > 0; j >>= 1) {
            if (tid < 64) {
                const int p = tid;
                const int i = ((p & ~(j - 1)) << 1) | (p & (j - 1));
                const int l = i | j;
                float av = cv[i], bv2 = cv[l];
                int   ai = ci[i], bx = ci[l];
                const bool agtb = (av > bv2) || (av == bv2 && ai < bx);
                const bool desc = ((i & k) == 0);
                if (agtb != desc) { cv[i] = bv2; cv[l] = av; ci[i] = bx; ci[l] = ai; }
            }
            __syncthreads();
        }
    }

    if (tid < 32) {
        const float mx = cv[0];
        float e = __expf(cv[tid] - mx);
        float s2 = e;
        for (int o = 16; o > 0; o >>= 1) s2 += __shfl_xor(s2, o);
        const int fi = ci[tid];
        const int ii = fi >> 5, jj = fi & 31;
        w[(size_t)gid * KNN + tid] = e / s2;
        ind[(size_t)gid * KNN + tid] = si_[ii] * NK + si_[128 + jj];
    }
}

// --------------------------------------------------------- PKM gather -----
__global__ __launch_bounds__(384) void pkm_gather_kernel(const float* __restrict__ w,
    const int* __restrict__ ind, const unsigned short* __restrict__ valb,
    float* __restrict__ out)
{
    const int t = blockIdx.x, tid = threadIdx.x;
    __shared__ float ws[PH * KNN];
    __shared__ int   is[PH * KNN];
    if (tid < PH * KNN) {
        ws[tid] = w[(size_t)t * PH * KNN + tid];
        is[tid] = ind[(size_t)t * PH * KNN + tid];
    }
    __syncthreads();
    const int d0 = tid * 2;
    float a0 = 0.f, a1 = 0.f;
#pragma unroll 4
    for (int i = 0; i < PH * KNN; i++) {
        unsigned pv = *(const unsigned*)&valb[(size_t)is[i] * CD + d0];
        float wi = ws[i];
        a0 = fmaf(wi, bf2f((unsigned short)(pv & 0xffff)), a0);
        a1 = fmaf(wi, bf2f((unsigned short)(pv >> 16)), a1);
    }
    out[(size_t)t * CD + d0] = a0;
    out[(size_t)t * CD + d0 + 1] = a1;
}

// ------------------------------------------------------------- launch -----
extern "C" void kernel_launch(void* const* d_in, const int* in_sizes, int n_in,
                              void* d_out, int out_size, void* d_ws, size_t ws_size,
                              hipStream_t stream)
{
    const float* x      = (const float*)d_in[0];
    const float* Wq     = (const float*)d_in[1];
    const float* bq     = (const float*)d_in[2];
    const float* Wk     = (const float*)d_in[3];
    const float* bk     = (const float*)d_in[4];
    const float* Wv     = (const float*)d_in[5];
    const float* bv     = (const float*)d_in[6];
    const float* Wo     = (const float*)d_in[7];
    const float* bo     = (const float*)d_in[8];
    const float* ln1_g  = (const float*)d_in[9];
    const float* ln1_b  = (const float*)d_in[10];
    const float* Wi     = (const float*)d_in[11];
    const float* bi     = (const float*)d_in[12];
    const float* Wd     = (const float*)d_in[13];
    const float* bd     = (const float*)d_in[14];
    const float* ln2_g  = (const float*)d_in[15];
    const float* ln2_b  = (const float*)d_in[16];
    const float* Wpq    = (const float*)d_in[17];
    const float* bpq    = (const float*)d_in[18];
    const float* keys   = (const float*)d_in[19];
    const float* values = (const float*)d_in[20];

    char* W = (char*)d_ws;
    // region A: qkvb bf16 (9.44MB) -> sbuf fp32 (8.39MB) -> pkmo fp32 (6.29MB)
    unsigned short* qkvb  = (unsigned short*)(W + 0);
    float*          sbuf  = (float*)(W + 0);
    float*          pkmo  = (float*)(W + 0);
    // region B: attnf fp32 (6.29MB), alive LN1..LN2
    float*          attnf = (float*)(W + 9437184);
    // region C: ctxb bf16 (3.1MB) -> interb bf16 (12.58MB) -> wgt/ind
    unsigned short* ctxb  = (unsigned short*)(W + 15728640);
    unsigned short* interb= (unsigned short*)(W + 15728640);
    float*          wgt   = (float*)(W + 15728640);
    int*            ind   = (int*)(W + 16777216);
    // region D: xb/woout/dense (@28.3MB), attnb (@34.6MB), pqb (@37.7MB)
    unsigned short* xb    = (unsigned short*)(W + 28311552);
    float*          woout = (float*)(W + 28311552);
    float*          dense = (float*)(W + 28311552);
    unsigned short* attnb = (unsigned short*)(W + 34603008);
    unsigned short* pqb   = (unsigned short*)(W + 37748736);
    // keysb bf16 (0.5MB)
    unsigned short* keysb = (unsigned short*)(W + 46137344);
    // wt bf16 (26.74MB) -> valb bf16 (25.17MB) after last weight GEMM
    unsigned short* wt    = (unsigned short*)(W + 46661632);
    unsigned short* valb  = (unsigned short*)(W + 46661632);

    const dim3 blk(256);
    const size_t WOFF = 589824;   // 768*768

    // input conversions
    cvt_bf16x4<<<2048, blk, 0, stream>>>(x, xb, CT * CD / 4);
    cvt_bf16x4<<<256, blk, 0, stream>>>(keys, keysb, (PH * 2 * NK * HALF) / 4);

    // weight transposes
    transpose_qkvo<<<dim3(24, 24, 4), blk, 0, stream>>>(Wq, Wk, Wv, Wo, wt);
    transpose_w<<<dim3(96, 24), blk, 0, stream>>>(Wi,  wt + 4 * WOFF, CD, CFF);
    transpose_w<<<dim3(24, 96), blk, 0, stream>>>(Wd,  wt + 4 * WOFF + 2359296, CFF, CD);
    transpose_w<<<dim3(64, 96), blk, 0, stream>>>(Wpq, wt + 4 * WOFF + 2 * 2359296, CFF, PH * KD);

    // merged QKV projection: [2048][2304] bf16  (TM=64 -> 576 blocks)
    gemm_lds<64, 1, 0, 0, 1><<<dim3(18, 32), blk, 0, stream>>>(
        xb, wt, bq, bk, bv, qkvb, nullptr, CT, 2304, CD, CD, 2304, 0);

    // flash attention (MFMA)
    attn_mfma<<<dim3(8, 12, 4), blk, 0, stream>>>(qkvb, ctxb);

    // output projection + LN1
    gemm_lds<64, 0, 0, 0, 0><<<dim3(6, 32), blk, 0, stream>>>(
        ctxb, wt + 3 * WOFF, bo, nullptr, nullptr, woout, nullptr, CT, CD, CD, CD, CD, 0);
    ln_kernel<<<CT, blk, 0, stream>>>(attnf, attnb, woout, CD, x, nullptr, ln1_g, ln1_b);

    // FFN up (GELU, bf16 out)  (TM=128 -> 384 blocks)
    gemm_lds<128, 1, 1, 0, 0><<<dim3(24, 16), blk, 0, stream>>>(
        attnb, wt + 4 * WOFF, bi, nullptr, nullptr, interb, nullptr, CT, CFF, CD, CD, CFF, 0);

    // merged FFN down + PKM query proj: dense fp32 [2048][768] + pq bf16 [2048][2048]
    gemm_lds<128, 2, 0, 0, 2><<<dim3(22, 16), blk, 0, stream>>>(
        interb, wt + 4 * WOFF + 2359296, bd, bpq, nullptr, dense, pqb, CT, 2816, CFF, CFF, CD, 2048);

    // values -> bf16 (into dead wt region)
    cvt_bf16x4<<<2048, blk, 0, stream>>>(values, valb, (NK * NK * CD) / 4);

    // PKM scores: 8 batched GEMMs (z = h*2+half), A = pqb bf16
    gemm_lds<64, 0, 0, 1, 0><<<dim3(1, 32, 8), blk, 0, stream>>>(
        pqb, keysb, nullptr, nullptr, nullptr, sbuf, nullptr, CT, NK, HALF, 2048, PH * 2 * NK, 0);

    // fused two-stage top-k + softmax
    pkm_topk_kernel<<<CT * PH, dim3(128), 0, stream>>>(sbuf, wgt, ind);

    // gather (bf16 values)
    pkm_gather_kernel<<<CT, dim3(384), 0, stream>>>(wgt, ind, valb, pkmo);

    // final LN over dense + pkm + attn
    ln_kernel<<<CT, blk, 0, stream>>>((float*)d_out, nullptr, dense, CD, pkmo, attnf, ln2_g, ln2_b);
}

// Round 6
// 293.367 us; speedup vs baseline: 13.1561x; 1.0655x over previous
//
#include <hip/hip_runtime.h>
#include <math.h>

// Problem constants
constexpr int CB = 4, CS = 512, CD = 768, CFF = 3072, CH = 12, CHD = 64;
constexpr int CT = CB * CS;            // 2048 tokens
constexpr int PH = 4, KD = 512, NK = 128, KNN = 32, HALF = 256;

typedef __attribute__((ext_vector_type(8))) short short8_t;   // 8 bf16 (4 VGPRs)
typedef __attribute__((ext_vector_type(4))) float f32x4;      // MFMA accumulator

__device__ __forceinline__ unsigned short f2bf(float f) {
    unsigned int u = __float_as_uint(f);
    return (unsigned short)((u + 0x7FFF + ((u >> 16) & 1)) >> 16);  // RNE
}
__device__ __forceinline__ float bf2f(unsigned short h) {
    return __uint_as_float(((unsigned)h) << 16);
}

// async global->LDS, 16B per lane; LDS dest = wave-uniform base + lane*16
__device__ __forceinline__ void ld_lds16(const unsigned short* g, unsigned short* l) {
    __builtin_amdgcn_global_load_lds(
        (const __attribute__((address_space(1))) void*)g,
        (__attribute__((address_space(3))) void*)l, 16, 0, 0);
}

// ------------------------------------------------------------ fp32->bf16 --
__global__ __launch_bounds__(256) void cvt_bf16x4(const float* __restrict__ in,
    unsigned short* __restrict__ out, int n4)
{
    for (int i = blockIdx.x * 256 + threadIdx.x; i < n4; i += gridDim.x * 256) {
        float4 v = ((const float4*)in)[i];
        ushort4 o = { f2bf(v.x), f2bf(v.y), f2bf(v.z), f2bf(v.w) };
        ((ushort4*)out)[i] = o;
    }
}

// ------------------------------------------- merged weight transpose ------
// All 7 weights fp32 [K][N] -> bf16 [N][K] in one launch (13056 tiles).
// Layout in wt: Wq,Wk,Wv,Wo (4x 768x768), Wi (768x3072), Wd (3072x768),
// Wpq (3072x2048).
__global__ __launch_bounds__(256) void transpose_all(
    const float* __restrict__ Wq, const float* __restrict__ Wk,
    const float* __restrict__ Wv, const float* __restrict__ Wo,
    const float* __restrict__ Wi, const float* __restrict__ Wd,
    const float* __restrict__ Wpq, unsigned short* __restrict__ wt)
{
    __shared__ unsigned short ts[32][33];
    int b = blockIdx.x;
    const float* W; unsigned short* WT; int K, N, tile;
    if (b < 2304) {
        int z = b / 576; tile = b - z * 576;
        W = (z == 0) ? Wq : (z == 1) ? Wk : (z == 2) ? Wv : Wo;
        WT = wt + (size_t)z * 589824; K = 768; N = 768;
    } else if (b < 4608) {
        tile = b - 2304; W = Wi; WT = wt + 4 * 589824; K = 768; N = 3072;
    } else if (b < 6912) {
        tile = b - 4608; W = Wd; WT = wt + 4 * 589824 + 2359296; K = 3072; N = 768;
    } else {
        tile = b - 6912; W = Wpq; WT = wt + 4 * 589824 + 2 * 2359296; K = 3072; N = 2048;
    }
    const int nx = N >> 5;
    const int n0 = (tile % nx) * 32, k0 = (tile / nx) * 32;
    const int c = threadIdx.x & 31, rr = threadIdx.x >> 5;
#pragma unroll
    for (int i = 0; i < 4; i++) {
        int r = rr + i * 8;
        ts[c][r] = f2bf(W[(size_t)(k0 + r) * N + n0 + c]);
    }
    __syncthreads();
#pragma unroll
    for (int i = 0; i < 4; i++) {
        int rw = rr + i * 8;
        WT[(size_t)(n0 + rw) * K + k0 + c] = ts[rw][c];
    }
}

// ------------------------------------- MFMA GEMM (2-phase pipelined) ------
// C[M,N] = A[M,K] @ B[K,N] + bias; A bf16 [M][lda], BT bf16 [N][K].
// Double-buffered LDS; STAGE(t+1) issued before compute(t); counted
// s_waitcnt vmcnt(LPW) so next-tile loads stay in flight across the raw
// s_barrier (T3 minimum recipe). Both-sides XOR swizzle f(row)=(row>>1)&3
// -> 2-way max bank aliasing (free).
template<int TM, int CMODE, int ACT, int PKMM, int BMODE>
__global__ __launch_bounds__(256) void gemm_lds(
    const unsigned short* __restrict__ A, const unsigned short* __restrict__ BT,
    const float* __restrict__ b0, const float* __restrict__ b1,
    const float* __restrict__ b2,
    void* __restrict__ Cg, void* __restrict__ Cg2,
    int M, int N, int K, int lda, int ldc, int ldc2)
{
    __shared__ unsigned short As[2][TM * 32];
    __shared__ unsigned short Bs[2][128 * 32];
    const int tid = threadIdx.x, lane = tid & 63, w = tid >> 6;
    const int l15 = lane & 15, l4 = lane >> 4;
    const int wr = w >> 1, wc = w & 1;
    constexpr int NI = TM / 32;            // A fragments per wave
    constexpr int LPW = (TM == 128) ? 4 : 3;   // staging loads per wave

    size_t aoff = 0, boff = 0, coff = 0;
    if (PKMM) {
        int z = blockIdx.z;
        aoff = (size_t)(z >> 1) * KD + (size_t)(z & 1) * HALF;
        boff = (size_t)z * NK * HALF;
        coff = (size_t)z * NK;
    }
    const int rowA0 = blockIdx.y * TM, rowB0 = blockIdx.x * 128;

    // staging lane pattern: lane -> (row sr, chunk sc); global chunk scg
    const int sr = lane >> 2, sc = lane & 3;
    const int scg = sc ^ ((sr >> 1) & 3);
    const int rdc = (l4 ^ ((l15 >> 1) & 3)) * 8;   // read chunk offset (elems)

    f32x4 acc[NI][4];
#pragma unroll
    for (int i = 0; i < NI; i++)
#pragma unroll
        for (int j = 0; j < 4; j++) acc[i][j] = (f32x4){0.f, 0.f, 0.f, 0.f};

    auto STAGE = [&](int t, int buf) {
        const int k0 = t * 32;
        if (TM == 128) {
#pragma unroll
            for (int i = 0; i < 2; i++) {
                const int r0 = w * 32 + i * 16;
                ld_lds16(&A[aoff + (size_t)(rowA0 + r0 + sr) * lda + k0 + scg * 8],
                         &As[buf][r0 * 32]);
            }
        } else {
            const int r0 = w * 16;
            ld_lds16(&A[aoff + (size_t)(rowA0 + r0 + sr) * lda + k0 + scg * 8],
                     &As[buf][r0 * 32]);
        }
#pragma unroll
        for (int i = 0; i < 2; i++) {
            const int r0 = w * 32 + i * 16;
            ld_lds16(&BT[boff + (size_t)(rowB0 + r0 + sr) * K + k0 + scg * 8],
                     &Bs[buf][r0 * 32]);
        }
    };

    const int NT = K / 32;
    STAGE(0, 0);
    for (int t = 0; t < NT; ++t) {
        const int cur = t & 1;
        if (t + 1 < NT) {
            STAGE(t + 1, cur ^ 1);
            if (LPW == 4) asm volatile("s_waitcnt vmcnt(4)" ::: "memory");
            else          asm volatile("s_waitcnt vmcnt(3)" ::: "memory");
        } else {
            asm volatile("s_waitcnt vmcnt(0)" ::: "memory");
        }
        __builtin_amdgcn_sched_barrier(0);
        __builtin_amdgcn_s_barrier();
        __builtin_amdgcn_sched_barrier(0);

        short8_t af[NI], bf[4];
#pragma unroll
        for (int i = 0; i < NI; i++)
            af[i] = *(const short8_t*)&As[cur][(wr * (TM / 2) + i * 16 + l15) * 32 + rdc];
#pragma unroll
        for (int j = 0; j < 4; j++)
            bf[j] = *(const short8_t*)&Bs[cur][(wc * 64 + j * 16 + l15) * 32 + rdc];
#pragma unroll
        for (int i = 0; i < NI; i++)
#pragma unroll
            for (int j = 0; j < 4; j++)
                acc[i][j] = __builtin_amdgcn_mfma_f32_16x16x32_bf16(af[i], bf[j], acc[i][j], 0, 0, 0);
        __builtin_amdgcn_sched_barrier(0);
        __builtin_amdgcn_s_barrier();
        __builtin_amdgcn_sched_barrier(0);
    }

    // ---- epilogue; D: col=lane&15, row=(lane>>4)*4+reg
#pragma unroll
    for (int i = 0; i < NI; i++) {
#pragma unroll
        for (int j = 0; j < 4; j++) {
            const int row = rowA0 + wr * (TM / 2) + i * 16 + l4 * 4;
            const int col = rowB0 + wc * 64 + j * 16 + l15;
            float bv;
            if (PKMM) bv = 0.f;
            else if (BMODE == 0) bv = b0[col];
            else if (BMODE == 1) bv = (col < 768) ? b0[col] : (col < 1536 ? b1[col - 768] : b2[col - 1536]);
            else bv = (col < 768) ? b0[col] : b1[col - 768];
#pragma unroll
            for (int jj = 0; jj < 4; jj++) {
                float v = acc[i][j][jj] + bv;
                if (ACT == 1) v = 0.5f * v * (1.0f + erff(v * 0.70710678118654752f));
                if (CMODE == 0)
                    ((float*)Cg)[coff + (size_t)(row + jj) * ldc + col] = v;
                else if (CMODE == 1)
                    ((unsigned short*)Cg)[coff + (size_t)(row + jj) * ldc + col] = f2bf(v);
                else {
                    if (col < 768)
                        ((float*)Cg)[(size_t)(row + jj) * ldc + col] = v;
                    else
                        ((unsigned short*)Cg2)[(size_t)(row + jj) * ldc2 + (col - 768)] = f2bf(v);
                }
            }
        }
    }
}

// ----------------------------------------------------- MFMA flash attention
constexpr int AST = 72;   // bf16 elem stride

__global__ __launch_bounds__(256) void attn_mfma(const unsigned short* __restrict__ qkv,
    unsigned short* __restrict__ ctx)
{
    __shared__ unsigned short Qs[64 * AST], Ks[64 * AST], Vt[64 * AST], Ss[64 * AST];
    const int tid = threadIdx.x, lane = tid & 63, w = tid >> 6;
    const int l15 = lane & 15, l4 = lane >> 4;
    const int h = blockIdx.y, b = blockIdx.z, q0 = blockIdx.x * 64;
    const int tb0 = b * CS;

#pragma unroll
    for (int it = 0; it < 2; ++it) {
        int e = it * 256 + tid, r = e >> 3, c = e & 7;
        *(uint4*)&Qs[r * AST + c * 8] =
            *(const uint4*)&qkv[(size_t)(tb0 + q0 + r) * 2304 + h * 64 + c * 8];
    }
    f32x4 accO[4];
    float mreg[4], lreg[4];
#pragma unroll
    for (int j = 0; j < 4; j++) accO[j] = (f32x4){0.f, 0.f, 0.f, 0.f};
#pragma unroll
    for (int r = 0; r < 4; r++) { mreg[r] = -1e30f; lreg[r] = 0.f; }
    __syncthreads();
    const short8_t aq0 = *(const short8_t*)&Qs[(w * 16 + l15) * AST + l4 * 8];
    const short8_t aq1 = *(const short8_t*)&Qs[(w * 16 + l15) * AST + 32 + l4 * 8];

    for (int kt = 0; kt < 8; ++kt) {
        __syncthreads();
#pragma unroll
        for (int it = 0; it < 2; ++it) {
            int e = it * 256 + tid, r = e >> 3, c = e & 7;
            *(uint4*)&Ks[r * AST + c * 8] =
                *(const uint4*)&qkv[(size_t)(tb0 + kt * 64 + r) * 2304 + 768 + h * 64 + c * 8];
            uint4 vv = *(const uint4*)&qkv[(size_t)(tb0 + kt * 64 + r) * 2304 + 1536 + h * 64 + c * 8];
            const unsigned short* pv = (const unsigned short*)&vv;
            const int rc = (((r >> 3) + c) & 7) * 8 + (r & 7);
#pragma unroll
            for (int e2 = 0; e2 < 8; ++e2)
                Vt[(c * 8 + e2) * AST + rc] = pv[e2];
        }
        __syncthreads();

        f32x4 sc[4];
#pragma unroll
        for (int j = 0; j < 4; j++) sc[j] = (f32x4){0.f, 0.f, 0.f, 0.f};
#pragma unroll
        for (int j = 0; j < 4; j++) {
            short8_t bk0 = *(const short8_t*)&Ks[(j * 16 + l15) * AST + l4 * 8];
            short8_t bk1 = *(const short8_t*)&Ks[(j * 16 + l15) * AST + 32 + l4 * 8];
            sc[j] = __builtin_amdgcn_mfma_f32_16x16x32_bf16(aq0, bk0, sc[j], 0, 0, 0);
            sc[j] = __builtin_amdgcn_mfma_f32_16x16x32_bf16(aq1, bk1, sc[j], 0, 0, 0);
        }

        float cf[4];
#pragma unroll
        for (int r = 0; r < 4; r++) {
            float s0 = sc[0][r] * 0.125f, s1 = sc[1][r] * 0.125f;
            float s2 = sc[2][r] * 0.125f, s3 = sc[3][r] * 0.125f;
            float mt = fmaxf(fmaxf(s0, s1), fmaxf(s2, s3));
            mt = fmaxf(mt, __shfl_xor(mt, 1));
            mt = fmaxf(mt, __shfl_xor(mt, 2));
            mt = fmaxf(mt, __shfl_xor(mt, 4));
            mt = fmaxf(mt, __shfl_xor(mt, 8));
            float mo = mreg[r], mn = fmaxf(mo, mt);
            float c = __expf(mo - mn);
            mreg[r] = mn; cf[r] = c;
            float p0 = __expf(s0 - mn), p1 = __expf(s1 - mn);
            float p2 = __expf(s2 - mn), p3 = __expf(s3 - mn);
            float ps = p0 + p1 + p2 + p3;
            ps += __shfl_xor(ps, 1);
            ps += __shfl_xor(ps, 2);
            ps += __shfl_xor(ps, 4);
            ps += __shfl_xor(ps, 8);
            lreg[r] = lreg[r] * c + ps;
            const int qrow = (w * 16 + l4 * 4 + r) * AST;
            Ss[qrow + l15]      = f2bf(p0);
            Ss[qrow + 16 + l15] = f2bf(p1);
            Ss[qrow + 32 + l15] = f2bf(p2);
            Ss[qrow + 48 + l15] = f2bf(p3);
        }
#pragma unroll
        for (int j = 0; j < 4; j++) {
            accO[j][0] *= cf[0]; accO[j][1] *= cf[1];
            accO[j][2] *= cf[2]; accO[j][3] *= cf[3];
        }

        const short8_t ap0 = *(const short8_t*)&Ss[(w * 16 + l15) * AST + l4 * 8];
        const short8_t ap1 = *(const short8_t*)&Ss[(w * 16 + l15) * AST + 32 + l4 * 8];
#pragma unroll
        for (int j = 0; j < 4; j++) {
            const int d = j * 16 + l15, dc = d >> 3;
            short8_t bv0 = *(const short8_t*)&Vt[d * AST + (((l4    ) + dc) & 7) * 8];
            short8_t bv1 = *(const short8_t*)&Vt[d * AST + (((l4 + 4) + dc) & 7) * 8];
            accO[j] = __builtin_amdgcn_mfma_f32_16x16x32_bf16(ap0, bv0, accO[j], 0, 0, 0);
            accO[j] = __builtin_amdgcn_mfma_f32_16x16x32_bf16(ap1, bv1, accO[j], 0, 0, 0);
        }
    }

    float inv[4];
#pragma unroll
    for (int r = 0; r < 4; r++) inv[r] = 1.0f / lreg[r];
#pragma unroll
    for (int j = 0; j < 4; j++)
#pragma unroll
        for (int r = 0; r < 4; r++)
            ctx[(size_t)(tb0 + q0 + w * 16 + l4 * 4 + r) * CD + h * 64 + j * 16 + l15] =
                f2bf(accO[j][r] * inv[r]);
}

// ----------------------------------------------------------- layernorm ----
__global__ __launch_bounds__(256) void ln_kernel(float* __restrict__ out,
    unsigned short* __restrict__ outb,
    const float* __restrict__ a, int lda,
    const float* __restrict__ b2, const float* __restrict__ c,
    const float* __restrict__ g, const float* __restrict__ bb)
{
    const int t = blockIdx.x, tid = threadIdx.x;
    __shared__ float buf[CD];
    __shared__ float red[256];
    float l = 0.f;
    for (int d = tid; d < CD; d += 256) {
        float v = a[(size_t)t * lda + d];
        if (b2) v += b2[(size_t)t * CD + d];
        if (c)  v += c[(size_t)t * CD + d];
        buf[d] = v; l += v;
    }
    red[tid] = l; __syncthreads();
    for (int o = 128; o > 0; o >>= 1) { if (tid < o) red[tid] += red[tid + o]; __syncthreads(); }
    const float mean = red[0] * (1.0f / CD); __syncthreads();
    float l2 = 0.f;
    for (int d = tid; d < CD; d += 256) { float dd = buf[d] - mean; l2 += dd * dd; }
    red[tid] = l2; __syncthreads();
    for (int o = 128; o > 0; o >>= 1) { if (tid < o) red[tid] += red[tid + o]; __syncthreads(); }
    const float inv = rsqrtf(red[0] * (1.0f / CD) + 1e-12f);
    for (int d = tid; d < CD; d += 256) {
        float v = (buf[d] - mean) * inv * g[d] + bb[d];
        out[(size_t)t * CD + d] = v;
        if (outb) outb[(size_t)t * CD + d] = f2bf(v);
    }
}

// --------------------------------------------- fused PKM top-k (both stages)
__device__ const unsigned char CCNT[32] = {32,16,10,8,6,5,4,4,3,3,2,2,2,2,2,2,
                                           1,1,1,1,1,1,1,1,1,1,1,1,1,1,1,1};

__global__ __launch_bounds__(128) void pkm_topk_kernel(const float* __restrict__ sc,
    float* __restrict__ w, int* __restrict__ ind)
{
    const int gid = blockIdx.x;            // t*PH + h
    const int tid = threadIdx.x;
    __shared__ float sv[256];
    __shared__ int   si_[256];
    __shared__ float cv[128];
    __shared__ int   ci[128];

    const float* s = sc + (size_t)gid * 256;
    sv[tid] = s[tid];             si_[tid] = tid;
    sv[tid + 128] = s[tid + 128]; si_[tid + 128] = tid;
    __syncthreads();

    for (int k = 2; k <= 128; k <<= 1) {
        for (int j = k >> 1; j > 0; j >>= 1) {
            const int hh = tid >> 6, p = tid & 63;
            const int i = ((p & ~(j - 1)) << 1) | (p & (j - 1));
            const int l = i | j;
            const int bi_ = hh * 128 + i, bl = hh * 128 + l;
            float av = sv[bi_], bv2 = sv[bl];
            int   ai = si_[bi_], bx = si_[bl];
            const bool agtb = (av > bv2) || (av == bv2 && ai < bx);
            const bool desc = ((i & k) == 0);
            if (agtb != desc) { sv[bi_] = bv2; sv[bl] = av; si_[bi_] = bx; si_[bl] = ai; }
            __syncthreads();
        }
    }

    {
        float val; int fi;
        if (tid < 119) {
            int tt = tid, ii = 0;
            while (tt >= (int)CCNT[ii]) { tt -= CCNT[ii]; ii++; }
            val = sv[ii] + sv[128 + tt];
            fi = ii * 32 + tt;
        } else { val = -3.0e38f; fi = 0x7FFFFFF; }
        cv[tid] = val; ci[tid] = fi;
    }
    __syncthreads();

    for (int k = 2; k <= 128; k <<= 1) {
        for (int j = k >> 1; j > 0; j >>= 1) {
            if (tid < 64) {
                const int p = tid;
                const int i = ((p & ~(j - 1)) << 1) | (p & (j - 1));
                const int l = i | j;
                float av = cv[i], bv2 = cv[l];
                int   ai = ci[i], bx = ci[l];
                const bool agtb = (av > bv2) || (av == bv2 && ai < bx);
                const bool desc = ((i & k) == 0);
                if (agtb != desc) { cv[i] = bv2; cv[l] = av; ci[i] = bx; ci[l] = ai; }
            }
            __syncthreads();
        }
    }

    if (tid < 32) {
        const float mx = cv[0];
        float e = __expf(cv[tid] - mx);
        float s2 = e;
        for (int o = 16; o > 0; o >>= 1) s2 += __shfl_xor(s2, o);
        const int fi = ci[tid];
        const int ii = fi >> 5, jj = fi & 31;
        w[(size_t)gid * KNN + tid] = e / s2;
        ind[(size_t)gid * KNN + tid] = si_[ii] * NK + si_[128 + jj];
    }
}

// --------------------------------------------------------- PKM gather -----
__global__ __launch_bounds__(384) void pkm_gather_kernel(const float* __restrict__ w,
    const int* __restrict__ ind, const unsigned short* __restrict__ valb,
    float* __restrict__ out)
{
    const int t = blockIdx.x, tid = threadIdx.x;
    __shared__ float ws[PH * KNN];
    __shared__ int   is[PH * KNN];
    if (tid < PH * KNN) {
        ws[tid] = w[(size_t)t * PH * KNN + tid];
        is[tid] = ind[(size_t)t * PH * KNN + tid];
    }
    __syncthreads();
    const int d0 = tid * 2;
    float a0 = 0.f, a1 = 0.f;
#pragma unroll 4
    for (int i = 0; i < PH * KNN; i++) {
        unsigned pv = *(const unsigned*)&valb[(size_t)is[i] * CD + d0];
        float wi = ws[i];
        a0 = fmaf(wi, bf2f((unsigned short)(pv & 0xffff)), a0);
        a1 = fmaf(wi, bf2f((unsigned short)(pv >> 16)), a1);
    }
    out[(size_t)t * CD + d0] = a0;
    out[(size_t)t * CD + d0 + 1] = a1;
}

// ------------------------------------------------------------- launch -----
extern "C" void kernel_launch(void* const* d_in, const int* in_sizes, int n_in,
                              void* d_out, int out_size, void* d_ws, size_t ws_size,
                              hipStream_t stream)
{
    const float* x      = (const float*)d_in[0];
    const float* Wq     = (const float*)d_in[1];
    const float* bq     = (const float*)d_in[2];
    const float* Wk     = (const float*)d_in[3];
    const float* bk     = (const float*)d_in[4];
    const float* Wv     = (const float*)d_in[5];
    const float* bv     = (const float*)d_in[6];
    const float* Wo     = (const float*)d_in[7];
    const float* bo     = (const float*)d_in[8];
    const float* ln1_g  = (const float*)d_in[9];
    const float* ln1_b  = (const float*)d_in[10];
    const float* Wi     = (const float*)d_in[11];
    const float* bi     = (const float*)d_in[12];
    const float* Wd     = (const float*)d_in[13];
    const float* bd     = (const float*)d_in[14];
    const float* ln2_g  = (const float*)d_in[15];
    const float* ln2_b  = (const float*)d_in[16];
    const float* Wpq    = (const float*)d_in[17];
    const float* bpq    = (const float*)d_in[18];
    const float* keys   = (const float*)d_in[19];
    const float* values = (const float*)d_in[20];

    char* W = (char*)d_ws;
    // region A: qkvb bf16 (9.44MB) -> sbuf fp32 (8.39MB) -> pkmo fp32 (6.29MB)
    unsigned short* qkvb  = (unsigned short*)(W + 0);
    float*          sbuf  = (float*)(W + 0);
    float*          pkmo  = (float*)(W + 0);
    // region B: attnf fp32 (6.29MB), alive LN1..LN2
    float*          attnf = (float*)(W + 9437184);
    // region C: ctxb bf16 (3.1MB) -> interb bf16 (12.58MB) -> wgt/ind
    unsigned short* ctxb  = (unsigned short*)(W + 15728640);
    unsigned short* interb= (unsigned short*)(W + 15728640);
    float*          wgt   = (float*)(W + 15728640);
    int*            ind   = (int*)(W + 16777216);
    // region D: xb/woout/dense (@28.3MB), attnb (@34.6MB), pqb (@37.7MB)
    unsigned short* xb    = (unsigned short*)(W + 28311552);
    float*          woout = (float*)(W + 28311552);
    float*          dense = (float*)(W + 28311552);
    unsigned short* attnb = (unsigned short*)(W + 34603008);
    unsigned short* pqb   = (unsigned short*)(W + 37748736);
    // keysb bf16 (0.5MB)
    unsigned short* keysb = (unsigned short*)(W + 46137344);
    // wt bf16 (26.74MB) -> valb bf16 (25.17MB) after last weight GEMM
    unsigned short* wt    = (unsigned short*)(W + 46661632);
    unsigned short* valb  = (unsigned short*)(W + 46661632);

    const dim3 blk(256);
    const size_t WOFF = 589824;   // 768*768

    // input conversions
    cvt_bf16x4<<<2048, blk, 0, stream>>>(x, xb, CT * CD / 4);
    cvt_bf16x4<<<256, blk, 0, stream>>>(keys, keysb, (PH * 2 * NK * HALF) / 4);

    // merged weight transpose (all 7 weights, one launch)
    transpose_all<<<13056, blk, 0, stream>>>(Wq, Wk, Wv, Wo, Wi, Wd, Wpq, wt);

    // merged QKV projection: [2048][2304] bf16  (TM=64 -> 576 blocks)
    gemm_lds<64, 1, 0, 0, 1><<<dim3(18, 32), blk, 0, stream>>>(
        xb, wt, bq, bk, bv, qkvb, nullptr, CT, 2304, CD, CD, 2304, 0);

    // flash attention (MFMA)
    attn_mfma<<<dim3(8, 12, 4), blk, 0, stream>>>(qkvb, ctxb);

    // output projection + LN1
    gemm_lds<64, 0, 0, 0, 0><<<dim3(6, 32), blk, 0, stream>>>(
        ctxb, wt + 3 * WOFF, bo, nullptr, nullptr, woout, nullptr, CT, CD, CD, CD, CD, 0);
    ln_kernel<<<CT, blk, 0, stream>>>(attnf, attnb, woout, CD, x, nullptr, ln1_g, ln1_b);

    // FFN up (GELU, bf16 out)  (TM=128 -> 384 blocks)
    gemm_lds<128, 1, 1, 0, 0><<<dim3(24, 16), blk, 0, stream>>>(
        attnb, wt + 4 * WOFF, bi, nullptr, nullptr, interb, nullptr, CT, CFF, CD, CD, CFF, 0);

    // merged FFN down + PKM query proj: dense fp32 [2048][768] + pq bf16 [2048][2048]
    gemm_lds<128, 2, 0, 0, 2><<<dim3(22, 16), blk, 0, stream>>>(
        interb, wt + 4 * WOFF + 2359296, bd, bpq, nullptr, dense, pqb, CT, 2816, CFF, CFF, CD, 2048);

    // values -> bf16 (into dead wt region)
    cvt_bf16x4<<<2048, blk, 0, stream>>>(values, valb, (NK * NK * CD) / 4);

    // PKM scores: 8 batched GEMMs (z = h*2+half), A = pqb bf16
    gemm_lds<64, 0, 0, 1, 0><<<dim3(1, 32, 8), blk, 0, stream>>>(
        pqb, keysb, nullptr, nullptr, nullptr, sbuf, nullptr, CT, NK, HALF, 2048, PH * 2 * NK, 0);

    // fused two-stage top-k + softmax
    pkm_topk_kernel<<<CT * PH, dim3(128), 0, stream>>>(sbuf, wgt, ind);

    // gather (bf16 values)
    pkm_gather_kernel<<<CT, dim3(384), 0, stream>>>(wgt, ind, valb, pkmo);

    // final LN over dense + pkm + attn
    ln_kernel<<<CT, blk, 0, stream>>>((float*)d_out, nullptr, dense, CD, pkmo, attnf, ln2_g, ln2_b);
}

// Round 7
// 271.936 us; speedup vs baseline: 14.1929x; 1.0788x over previous
//
#include <hip/hip_runtime.h>
#include <math.h>

// Problem constants
constexpr int CB = 4, CS = 512, CD = 768, CFF = 3072, CH = 12, CHD = 64;
constexpr int CT = CB * CS;            // 2048 tokens
constexpr int PH = 4, KD = 512, NK = 128, KNN = 32, HALF = 256;

typedef __attribute__((ext_vector_type(8))) short short8_t;   // 8 bf16 (4 VGPRs)
typedef __attribute__((ext_vector_type(4))) float f32x4;      // MFMA accumulator

__device__ __forceinline__ unsigned short f2bf(float f) {
    unsigned int u = __float_as_uint(f);
    return (unsigned short)((u + 0x7FFF + ((u >> 16) & 1)) >> 16);  // RNE
}
__device__ __forceinline__ float bf2f(unsigned short h) {
    return __uint_as_float(((unsigned)h) << 16);
}

// async global->LDS, 16B per lane; LDS dest = wave-uniform base + lane*16
__device__ __forceinline__ void ld_lds16(const unsigned short* g, unsigned short* l) {
    __builtin_amdgcn_global_load_lds(
        (const __attribute__((address_space(1))) void*)g,
        (__attribute__((address_space(3))) void*)l, 16, 0, 0);
}

// ------------------------------------------------------------ fp32->bf16 --
__global__ __launch_bounds__(256) void cvt_bf16x4(const float* __restrict__ in,
    unsigned short* __restrict__ out, int n4)
{
    for (int i = blockIdx.x * 256 + threadIdx.x; i < n4; i += gridDim.x * 256) {
        float4 v = ((const float4*)in)[i];
        ushort4 o = { f2bf(v.x), f2bf(v.y), f2bf(v.z), f2bf(v.w) };
        ((ushort4*)out)[i] = o;
    }
}

// ------------------------------------------- merged weight transpose ------
__global__ __launch_bounds__(256) void transpose_all(
    const float* __restrict__ Wq, const float* __restrict__ Wk,
    const float* __restrict__ Wv, const float* __restrict__ Wo,
    const float* __restrict__ Wi, const float* __restrict__ Wd,
    const float* __restrict__ Wpq, unsigned short* __restrict__ wt)
{
    __shared__ unsigned short ts[32][33];
    int b = blockIdx.x;
    const float* W; unsigned short* WT; int K, N, tile;
    if (b < 2304) {
        int z = b / 576; tile = b - z * 576;
        W = (z == 0) ? Wq : (z == 1) ? Wk : (z == 2) ? Wv : Wo;
        WT = wt + (size_t)z * 589824; K = 768; N = 768;
    } else if (b < 4608) {
        tile = b - 2304; W = Wi; WT = wt + 4 * 589824; K = 768; N = 3072;
    } else if (b < 6912) {
        tile = b - 4608; W = Wd; WT = wt + 4 * 589824 + 2359296; K = 3072; N = 768;
    } else {
        tile = b - 6912; W = Wpq; WT = wt + 4 * 589824 + 2 * 2359296; K = 3072; N = 2048;
    }
    const int nx = N >> 5;
    const int n0 = (tile % nx) * 32, k0 = (tile / nx) * 32;
    const int c = threadIdx.x & 31, rr = threadIdx.x >> 5;
#pragma unroll
    for (int i = 0; i < 4; i++) {
        int r = rr + i * 8;
        ts[c][r] = f2bf(W[(size_t)(k0 + r) * N + n0 + c]);
    }
    __syncthreads();
#pragma unroll
    for (int i = 0; i < 4; i++) {
        int rw = rr + i * 8;
        WT[(size_t)(n0 + rw) * K + k0 + c] = ts[rw][c];
    }
}

// --------------------------- MFMA GEMM (BK=64, 2-phase pipelined) ---------
// C[M,N] = A[M,K] @ B[K,N] + bias; A bf16 [M][lda], BT bf16 [N][K].
// Double-buffered LDS, BK=64; STAGE(t+1) issued before compute(t); counted
// s_waitcnt vmcnt(LPW) keeps next-tile loads in flight across the raw
// s_barrier. Both-sides XOR swizzle: stage chunk = sc^ (row&7), read chunk
// = (l4+4h)^(row&7) -> 2-way bank aliasing (free).
template<int TM, int CMODE, int ACT, int PKMM, int BMODE>
__global__ __launch_bounds__(256) void gemm_lds(
    const unsigned short* __restrict__ A, const unsigned short* __restrict__ BT,
    const float* __restrict__ b0, const float* __restrict__ b1,
    const float* __restrict__ b2,
    void* __restrict__ Cg, void* __restrict__ Cg2,
    int M, int N, int K, int lda, int ldc, int ldc2)
{
    __shared__ unsigned short As[2][TM * 64];
    __shared__ unsigned short Bs[2][128 * 64];
    const int tid = threadIdx.x, lane = tid & 63, w = tid >> 6;
    const int l15 = lane & 15, l4 = lane >> 4;
    const int wr = w >> 1, wc = w & 1;
    constexpr int NI = TM / 32;            // A fragments per wave (per k-half)

    size_t aoff = 0, boff = 0, coff = 0;
    if (PKMM) {
        int z = blockIdx.z;
        aoff = (size_t)(z >> 1) * KD + (size_t)(z & 1) * HALF;
        boff = (size_t)z * NK * HALF;
        coff = (size_t)z * NK;
    }
    const int rowA0 = blockIdx.y * TM, rowB0 = blockIdx.x * 128;

    // staging: wave writes 1KB per call = 8 rows x 8 chunks (16B each)
    const int sr = lane >> 3, sc = lane & 7;
    const int scg = sc ^ sr;               // global chunk for swizzled store
    const int cx = l15 & 7;                // read-side row&7

    f32x4 acc[NI][4];
#pragma unroll
    for (int i = 0; i < NI; i++)
#pragma unroll
        for (int j = 0; j < 4; j++) acc[i][j] = (f32x4){0.f, 0.f, 0.f, 0.f};

    auto STAGE = [&](int t, int buf) {
        const int k0 = t * 64;
        if (TM == 128) {
#pragma unroll
            for (int i = 0; i < 4; i++) {
                const int r0 = w * 32 + i * 8;
                ld_lds16(&A[aoff + (size_t)(rowA0 + r0 + sr) * lda + k0 + scg * 8],
                         &As[buf][r0 * 64]);
            }
        } else {
#pragma unroll
            for (int i = 0; i < 2; i++) {
                const int r0 = w * 16 + i * 8;
                ld_lds16(&A[aoff + (size_t)(rowA0 + r0 + sr) * lda + k0 + scg * 8],
                         &As[buf][r0 * 64]);
            }
        }
#pragma unroll
        for (int i = 0; i < 4; i++) {
            const int r0 = w * 32 + i * 8;
            ld_lds16(&BT[boff + (size_t)(rowB0 + r0 + sr) * K + k0 + scg * 8],
                     &Bs[buf][r0 * 64]);
        }
    };

    const int NT = K / 64;
    STAGE(0, 0);
    for (int t = 0; t < NT; ++t) {
        const int cur = t & 1;
        if (t + 1 < NT) {
            STAGE(t + 1, cur ^ 1);
            if constexpr (TM == 128) asm volatile("s_waitcnt vmcnt(8)" ::: "memory");
            else                     asm volatile("s_waitcnt vmcnt(6)" ::: "memory");
        } else {
            asm volatile("s_waitcnt vmcnt(0)" ::: "memory");
        }
        __builtin_amdgcn_sched_barrier(0);
        __builtin_amdgcn_s_barrier();
        __builtin_amdgcn_sched_barrier(0);

        short8_t af[2][NI], bf[2][4];
#pragma unroll
        for (int h = 0; h < 2; h++) {
            const int co = ((l4 + 4 * h) ^ cx) * 8;
#pragma unroll
            for (int i = 0; i < NI; i++)
                af[h][i] = *(const short8_t*)&As[cur][(wr * (TM / 2) + i * 16 + l15) * 64 + co];
#pragma unroll
            for (int j = 0; j < 4; j++)
                bf[h][j] = *(const short8_t*)&Bs[cur][(wc * 64 + j * 16 + l15) * 64 + co];
        }
#pragma unroll
        for (int h = 0; h < 2; h++)
#pragma unroll
            for (int i = 0; i < NI; i++)
#pragma unroll
                for (int j = 0; j < 4; j++)
                    acc[i][j] = __builtin_amdgcn_mfma_f32_16x16x32_bf16(af[h][i], bf[h][j], acc[i][j], 0, 0, 0);
        __builtin_amdgcn_sched_barrier(0);
        __builtin_amdgcn_s_barrier();
        __builtin_amdgcn_sched_barrier(0);
    }

    // ---- epilogue; D: col=lane&15, row=(lane>>4)*4+reg
#pragma unroll
    for (int i = 0; i < NI; i++) {
#pragma unroll
        for (int j = 0; j < 4; j++) {
            const int row = rowA0 + wr * (TM / 2) + i * 16 + l4 * 4;
            const int col = rowB0 + wc * 64 + j * 16 + l15;
            float bv;
            if (PKMM) bv = 0.f;
            else if (BMODE == 0) bv = b0[col];
            else if (BMODE == 1) bv = (col < 768) ? b0[col] : (col < 1536 ? b1[col - 768] : b2[col - 1536]);
            else bv = (col < 768) ? b0[col] : b1[col - 768];
#pragma unroll
            for (int jj = 0; jj < 4; jj++) {
                float v = acc[i][j][jj] + bv;
                if (ACT == 1) v = 0.5f * v * (1.0f + erff(v * 0.70710678118654752f));
                if (CMODE == 0)
                    ((float*)Cg)[coff + (size_t)(row + jj) * ldc + col] = v;
                else if (CMODE == 1)
                    ((unsigned short*)Cg)[coff + (size_t)(row + jj) * ldc + col] = f2bf(v);
                else {
                    if (col < 768)
                        ((float*)Cg)[(size_t)(row + jj) * ldc + col] = v;
                    else
                        ((unsigned short*)Cg2)[(size_t)(row + jj) * ldc2 + (col - 768)] = f2bf(v);
                }
            }
        }
    }
}

// ----------------------------------------------------- MFMA flash attention
constexpr int AST = 72;   // bf16 elem stride

__global__ __launch_bounds__(256) void attn_mfma(const unsigned short* __restrict__ qkv,
    unsigned short* __restrict__ ctx)
{
    __shared__ unsigned short Qs[64 * AST], Ks[64 * AST], Vt[64 * AST], Ss[64 * AST];
    const int tid = threadIdx.x, lane = tid & 63, w = tid >> 6;
    const int l15 = lane & 15, l4 = lane >> 4;
    const int h = blockIdx.y, b = blockIdx.z, q0 = blockIdx.x * 64;
    const int tb0 = b * CS;

#pragma unroll
    for (int it = 0; it < 2; ++it) {
        int e = it * 256 + tid, r = e >> 3, c = e & 7;
        *(uint4*)&Qs[r * AST + c * 8] =
            *(const uint4*)&qkv[(size_t)(tb0 + q0 + r) * 2304 + h * 64 + c * 8];
    }
    f32x4 accO[4];
    float mreg[4], lreg[4];
#pragma unroll
    for (int j = 0; j < 4; j++) accO[j] = (f32x4){0.f, 0.f, 0.f, 0.f};
#pragma unroll
    for (int r = 0; r < 4; r++) { mreg[r] = -1e30f; lreg[r] = 0.f; }
    __syncthreads();
    const short8_t aq0 = *(const short8_t*)&Qs[(w * 16 + l15) * AST + l4 * 8];
    const short8_t aq1 = *(const short8_t*)&Qs[(w * 16 + l15) * AST + 32 + l4 * 8];

    for (int kt = 0; kt < 8; ++kt) {
        __syncthreads();
#pragma unroll
        for (int it = 0; it < 2; ++it) {
            int e = it * 256 + tid, r = e >> 3, c = e & 7;
            *(uint4*)&Ks[r * AST + c * 8] =
                *(const uint4*)&qkv[(size_t)(tb0 + kt * 64 + r) * 2304 + 768 + h * 64 + c * 8];
            uint4 vv = *(const uint4*)&qkv[(size_t)(tb0 + kt * 64 + r) * 2304 + 1536 + h * 64 + c * 8];
            const unsigned short* pv = (const unsigned short*)&vv;
            const int rc = (((r >> 3) + c) & 7) * 8 + (r & 7);
#pragma unroll
            for (int e2 = 0; e2 < 8; ++e2)
                Vt[(c * 8 + e2) * AST + rc] = pv[e2];
        }
        __syncthreads();

        f32x4 sc[4];
#pragma unroll
        for (int j = 0; j < 4; j++) sc[j] = (f32x4){0.f, 0.f, 0.f, 0.f};
#pragma unroll
        for (int j = 0; j < 4; j++) {
            short8_t bk0 = *(const short8_t*)&Ks[(j * 16 + l15) * AST + l4 * 8];
            short8_t bk1 = *(const short8_t*)&Ks[(j * 16 + l15) * AST + 32 + l4 * 8];
            sc[j] = __builtin_amdgcn_mfma_f32_16x16x32_bf16(aq0, bk0, sc[j], 0, 0, 0);
            sc[j] = __builtin_amdgcn_mfma_f32_16x16x32_bf16(aq1, bk1, sc[j], 0, 0, 0);
        }

        float cf[4];
#pragma unroll
        for (int r = 0; r < 4; r++) {
            float s0 = sc[0][r] * 0.125f, s1 = sc[1][r] * 0.125f;
            float s2 = sc[2][r] * 0.125f, s3 = sc[3][r] * 0.125f;
            float mt = fmaxf(fmaxf(s0, s1), fmaxf(s2, s3));
            mt = fmaxf(mt, __shfl_xor(mt, 1));
            mt = fmaxf(mt, __shfl_xor(mt, 2));
            mt = fmaxf(mt, __shfl_xor(mt, 4));
            mt = fmaxf(mt, __shfl_xor(mt, 8));
            float mo = mreg[r], mn = fmaxf(mo, mt);
            float c = __expf(mo - mn);
            mreg[r] = mn; cf[r] = c;
            float p0 = __expf(s0 - mn), p1 = __expf(s1 - mn);
            float p2 = __expf(s2 - mn), p3 = __expf(s3 - mn);
            float ps = p0 + p1 + p2 + p3;
            ps += __shfl_xor(ps, 1);
            ps += __shfl_xor(ps, 2);
            ps += __shfl_xor(ps, 4);
            ps += __shfl_xor(ps, 8);
            lreg[r] = lreg[r] * c + ps;
            const int qrow = (w * 16 + l4 * 4 + r) * AST;
            Ss[qrow + l15]      = f2bf(p0);
            Ss[qrow + 16 + l15] = f2bf(p1);
            Ss[qrow + 32 + l15] = f2bf(p2);
            Ss[qrow + 48 + l15] = f2bf(p3);
        }
#pragma unroll
        for (int j = 0; j < 4; j++) {
            accO[j][0] *= cf[0]; accO[j][1] *= cf[1];
            accO[j][2] *= cf[2]; accO[j][3] *= cf[3];
        }

        const short8_t ap0 = *(const short8_t*)&Ss[(w * 16 + l15) * AST + l4 * 8];
        const short8_t ap1 = *(const short8_t*)&Ss[(w * 16 + l15) * AST + 32 + l4 * 8];
#pragma unroll
        for (int j = 0; j < 4; j++) {
            const int d = j * 16 + l15, dc = d >> 3;
            short8_t bv0 = *(const short8_t*)&Vt[d * AST + (((l4    ) + dc) & 7) * 8];
            short8_t bv1 = *(const short8_t*)&Vt[d * AST + (((l4 + 4) + dc) & 7) * 8];
            accO[j] = __builtin_amdgcn_mfma_f32_16x16x32_bf16(ap0, bv0, accO[j], 0, 0, 0);
            accO[j] = __builtin_amdgcn_mfma_f32_16x16x32_bf16(ap1, bv1, accO[j], 0, 0, 0);
        }
    }

    float inv[4];
#pragma unroll
    for (int r = 0; r < 4; r++) inv[r] = 1.0f / lreg[r];
#pragma unroll
    for (int j = 0; j < 4; j++)
#pragma unroll
        for (int r = 0; r < 4; r++)
            ctx[(size_t)(tb0 + q0 + w * 16 + l4 * 4 + r) * CD + h * 64 + j * 16 + l15] =
                f2bf(accO[j][r] * inv[r]);
}

// ----------------------------------------------------------- layernorm ----
__global__ __launch_bounds__(256) void ln_kernel(float* __restrict__ out,
    unsigned short* __restrict__ outb,
    const float* __restrict__ a, int lda,
    const float* __restrict__ b2, const float* __restrict__ c,
    const float* __restrict__ g, const float* __restrict__ bb)
{
    const int t = blockIdx.x, tid = threadIdx.x;
    __shared__ float buf[CD];
    __shared__ float red[256];
    float l = 0.f;
    for (int d = tid; d < CD; d += 256) {
        float v = a[(size_t)t * lda + d];
        if (b2) v += b2[(size_t)t * CD + d];
        if (c)  v += c[(size_t)t * CD + d];
        buf[d] = v; l += v;
    }
    red[tid] = l; __syncthreads();
    for (int o = 128; o > 0; o >>= 1) { if (tid < o) red[tid] += red[tid + o]; __syncthreads(); }
    const float mean = red[0] * (1.0f / CD); __syncthreads();
    float l2 = 0.f;
    for (int d = tid; d < CD; d += 256) { float dd = buf[d] - mean; l2 += dd * dd; }
    red[tid] = l2; __syncthreads();
    for (int o = 128; o > 0; o >>= 1) { if (tid < o) red[tid] += red[tid + o]; __syncthreads(); }
    const float inv = rsqrtf(red[0] * (1.0f / CD) + 1e-12f);
    for (int d = tid; d < CD; d += 256) {
        float v = (buf[d] - mean) * inv * g[d] + bb[d];
        out[(size_t)t * CD + d] = v;
        if (outb) outb[(size_t)t * CD + d] = f2bf(v);
    }
}

// --------------------------------------------- fused PKM top-k (both stages)
__device__ const unsigned char CCNT[32] = {32,16,10,8,6,5,4,4,3,3,2,2,2,2,2,2,
                                           1,1,1,1,1,1,1,1,1,1,1,1,1,1,1,1};

__global__ __launch_bounds__(128) void pkm_topk_kernel(const float* __restrict__ sc,
    float* __restrict__ w, int* __restrict__ ind)
{
    const int gid = blockIdx.x;            // t*PH + h
    const int tid = threadIdx.x;
    __shared__ float sv[256];
    __shared__ int   si_[256];
    __shared__ float cv[128];
    __shared__ int   ci[128];

    const float* s = sc + (size_t)gid * 256;
    sv[tid] = s[tid];             si_[tid] = tid;
    sv[tid + 128] = s[tid + 128]; si_[tid + 128] = tid;
    __syncthreads();

    for (int k = 2; k <= 128; k <<= 1) {
        for (int j = k >> 1; j > 0; j >>= 1) {
            const int hh = tid >> 6, p = tid & 63;
            const int i = ((p & ~(j - 1)) << 1) | (p & (j - 1));
            const int l = i | j;
            const int bi_ = hh * 128 + i, bl = hh * 128 + l;
            float av = sv[bi_], bv2 = sv[bl];
            int   ai = si_[bi_], bx = si_[bl];
            const bool agtb = (av > bv2) || (av == bv2 && ai < bx);
            const bool desc = ((i & k) == 0);
            if (agtb != desc) { sv[bi_] = bv2; sv[bl] = av; si_[bi_] = bx; si_[bl] = ai; }
            __syncthreads();
        }
    }

    {
        float val; int fi;
        if (tid < 119) {
            int tt = tid, ii = 0;
            while (tt >= (int)CCNT[ii]) { tt -= CCNT[ii]; ii++; }
            val = sv[ii] + sv[128 + tt];
            fi = ii * 32 + tt;
        } else { val = -3.0e38f; fi = 0x7FFFFFF; }
        cv[tid] = val; ci[tid] = fi;
    }
    __syncthreads();

    for (int k = 2; k <= 128; k <<= 1) {
        for (int j = k >> 1; j > 0; j >>= 1) {
            if (tid < 64) {
                const int p = tid;
                const int i = ((p & ~(j - 1)) << 1) | (p & (j - 1));
                const int l = i | j;
                float av = cv[i], bv2 = cv[l];
                int   ai = ci[i], bx = ci[l];
                const bool agtb = (av > bv2) || (av == bv2 && ai < bx);
                const bool desc = ((i & k) == 0);
                if (agtb != desc) { cv[i] = bv2; cv[l] = av; ci[i] = bx; ci[l] = ai; }
            }
            __syncthreads();
        }
    }

    if (tid < 32) {
        const float mx = cv[0];
        float e = __expf(cv[tid] - mx);
        float s2 = e;
        for (int o = 16; o > 0; o >>= 1) s2 += __shfl_xor(s2, o);
        const int fi = ci[tid];
        const int ii = fi >> 5, jj = fi & 31;
        w[(size_t)gid * KNN + tid] = e / s2;
        ind[(size_t)gid * KNN + tid] = si_[ii] * NK + si_[128 + jj];
    }
}

// --------------------------------------------------------- PKM gather -----
__global__ __launch_bounds__(384) void pkm_gather_kernel(const float* __restrict__ w,
    const int* __restrict__ ind, const unsigned short* __restrict__ valb,
    float* __restrict__ out)
{
    const int t = blockIdx.x, tid = threadIdx.x;
    __shared__ float ws[PH * KNN];
    __shared__ int   is[PH * KNN];
    if (tid < PH * KNN) {
        ws[tid] = w[(size_t)t * PH * KNN + tid];
        is[tid] = ind[(size_t)t * PH * KNN + tid];
    }
    __syncthreads();
    const int d0 = tid * 2;
    float a0 = 0.f, a1 = 0.f;
#pragma unroll 4
    for (int i = 0; i < PH * KNN; i++) {
        unsigned pv = *(const unsigned*)&valb[(size_t)is[i] * CD + d0];
        float wi = ws[i];
        a0 = fmaf(wi, bf2f((unsigned short)(pv & 0xffff)), a0);
        a1 = fmaf(wi, bf2f((unsigned short)(pv >> 16)), a1);
    }
    out[(size_t)t * CD + d0] = a0;
    out[(size_t)t * CD + d0 + 1] = a1;
}

// ------------------------------------------------------------- launch -----
extern "C" void kernel_launch(void* const* d_in, const int* in_sizes, int n_in,
                              void* d_out, int out_size, void* d_ws, size_t ws_size,
                              hipStream_t stream)
{
    const float* x      = (const float*)d_in[0];
    const float* Wq     = (const float*)d_in[1];
    const float* bq     = (const float*)d_in[2];
    const float* Wk     = (const float*)d_in[3];
    const float* bk     = (const float*)d_in[4];
    const float* Wv     = (const float*)d_in[5];
    const float* bv     = (const float*)d_in[6];
    const float* Wo     = (const float*)d_in[7];
    const float* bo     = (const float*)d_in[8];
    const float* ln1_g  = (const float*)d_in[9];
    const float* ln1_b  = (const float*)d_in[10];
    const float* Wi     = (const float*)d_in[11];
    const float* bi     = (const float*)d_in[12];
    const float* Wd     = (const float*)d_in[13];
    const float* bd     = (const float*)d_in[14];
    const float* ln2_g  = (const float*)d_in[15];
    const float* ln2_b  = (const float*)d_in[16];
    const float* Wpq    = (const float*)d_in[17];
    const float* bpq    = (const float*)d_in[18];
    const float* keys   = (const float*)d_in[19];
    const float* values = (const float*)d_in[20];

    char* W = (char*)d_ws;
    // region A: qkvb bf16 (9.44MB) -> sbuf fp32 (8.39MB) -> pkmo fp32 (6.29MB)
    unsigned short* qkvb  = (unsigned short*)(W + 0);
    float*          sbuf  = (float*)(W + 0);
    float*          pkmo  = (float*)(W + 0);
    // region B: attnf fp32 (6.29MB), alive LN1..LN2
    float*          attnf = (float*)(W + 9437184);
    // region C: ctxb bf16 (3.1MB) -> interb bf16 (12.58MB) -> wgt/ind
    unsigned short* ctxb  = (unsigned short*)(W + 15728640);
    unsigned short* interb= (unsigned short*)(W + 15728640);
    float*          wgt   = (float*)(W + 15728640);
    int*            ind   = (int*)(W + 16777216);
    // region D: xb/woout/dense (@28.3MB), attnb (@34.6MB), pqb (@37.7MB)
    unsigned short* xb    = (unsigned short*)(W + 28311552);
    float*          woout = (float*)(W + 28311552);
    float*          dense = (float*)(W + 28311552);
    unsigned short* attnb = (unsigned short*)(W + 34603008);
    unsigned short* pqb   = (unsigned short*)(W + 37748736);
    // keysb bf16 (0.5MB)
    unsigned short* keysb = (unsigned short*)(W + 46137344);
    // wt bf16 (26.74MB) -> valb bf16 (25.17MB) after last weight GEMM
    unsigned short* wt    = (unsigned short*)(W + 46661632);
    unsigned short* valb  = (unsigned short*)(W + 46661632);

    const dim3 blk(256);
    const size_t WOFF = 589824;   // 768*768

    // input conversions
    cvt_bf16x4<<<2048, blk, 0, stream>>>(x, xb, CT * CD / 4);
    cvt_bf16x4<<<256, blk, 0, stream>>>(keys, keysb, (PH * 2 * NK * HALF) / 4);

    // merged weight transpose (all 7 weights, one launch)
    transpose_all<<<13056, blk, 0, stream>>>(Wq, Wk, Wv, Wo, Wi, Wd, Wpq, wt);

    // merged QKV projection: [2048][2304] bf16  (TM=64 -> 576 blocks)
    gemm_lds<64, 1, 0, 0, 1><<<dim3(18, 32), blk, 0, stream>>>(
        xb, wt, bq, bk, bv, qkvb, nullptr, CT, 2304, CD, CD, 2304, 0);

    // flash attention (MFMA)
    attn_mfma<<<dim3(8, 12, 4), blk, 0, stream>>>(qkvb, ctxb);

    // output projection + LN1
    gemm_lds<64, 0, 0, 0, 0><<<dim3(6, 32), blk, 0, stream>>>(
        ctxb, wt + 3 * WOFF, bo, nullptr, nullptr, woout, nullptr, CT, CD, CD, CD, CD, 0);
    ln_kernel<<<CT, blk, 0, stream>>>(attnf, attnb, woout, CD, x, nullptr, ln1_g, ln1_b);

    // FFN up (GELU, bf16 out)  (TM=128 -> 384 blocks)
    gemm_lds<128, 1, 1, 0, 0><<<dim3(24, 16), blk, 0, stream>>>(
        attnb, wt + 4 * WOFF, bi, nullptr, nullptr, interb, nullptr, CT, CFF, CD, CD, CFF, 0);

    // merged FFN down + PKM query proj: dense fp32 [2048][768] + pq bf16 [2048][2048]
    gemm_lds<128, 2, 0, 0, 2><<<dim3(22, 16), blk, 0, stream>>>(
        interb, wt + 4 * WOFF + 2359296, bd, bpq, nullptr, dense, pqb, CT, 2816, CFF, CFF, CD, 2048);

    // values -> bf16 (into dead wt region)
    cvt_bf16x4<<<2048, blk, 0, stream>>>(values, valb, (NK * NK * CD) / 4);

    // PKM scores: 8 batched GEMMs (z = h*2+half), A = pqb bf16
    gemm_lds<64, 0, 0, 1, 0><<<dim3(1, 32, 8), blk, 0, stream>>>(
        pqb, keysb, nullptr, nullptr, nullptr, sbuf, nullptr, CT, NK, HALF, 2048, PH * 2 * NK, 0);

    // fused two-stage top-k + softmax
    pkm_topk_kernel<<<CT * PH, dim3(128), 0, stream>>>(sbuf, wgt, ind);

    // gather (bf16 values)
    pkm_gather_kernel<<<CT, dim3(384), 0, stream>>>(wgt, ind, valb, pkmo);

    // final LN over dense + pkm + attn
    ln_kernel<<<CT, blk, 0, stream>>>((float*)d_out, nullptr, dense, CD, pkmo, attnf, ln2_g, ln2_b);
}

// Round 8
// 258.145 us; speedup vs baseline: 14.9511x; 1.0534x over previous
//
#include <hip/hip_runtime.h>
#include <math.h>

// Problem constants
constexpr int CB = 4, CS = 512, CD = 768, CFF = 3072, CH = 12, CHD = 64;
constexpr int CT = CB * CS;            // 2048 tokens
constexpr int PH = 4, KD = 512, NK = 128, KNN = 32, HALF = 256;

typedef __attribute__((ext_vector_type(8))) short short8_t;   // 8 bf16 (4 VGPRs)
typedef __attribute__((ext_vector_type(4))) float f32x4;      // MFMA accumulator

__device__ __forceinline__ unsigned short f2bf(float f) {
    unsigned int u = __float_as_uint(f);
    return (unsigned short)((u + 0x7FFF + ((u >> 16) & 1)) >> 16);  // RNE
}
__device__ __forceinline__ float bf2f(unsigned short h) {
    return __uint_as_float(((unsigned)h) << 16);
}

// async global->LDS, 16B per lane; LDS dest = wave-uniform base + lane*16
__device__ __forceinline__ void ld_lds16(const unsigned short* g, unsigned short* l) {
    __builtin_amdgcn_global_load_lds(
        (const __attribute__((address_space(1))) void*)g,
        (__attribute__((address_space(3))) void*)l, 16, 0, 0);
}

// ------------------------------------------------------------ fp32->bf16 --
__global__ __launch_bounds__(256) void cvt_bf16x4(const float* __restrict__ in,
    unsigned short* __restrict__ out, int n4)
{
    for (int i = blockIdx.x * 256 + threadIdx.x; i < n4; i += gridDim.x * 256) {
        float4 v = ((const float4*)in)[i];
        ushort4 o = { f2bf(v.x), f2bf(v.y), f2bf(v.z), f2bf(v.w) };
        ((ushort4*)out)[i] = o;
    }
}

// ------------------------------------------- merged weight transpose ------
__global__ __launch_bounds__(256) void transpose_all(
    const float* __restrict__ Wq, const float* __restrict__ Wk,
    const float* __restrict__ Wv, const float* __restrict__ Wo,
    const float* __restrict__ Wi, const float* __restrict__ Wd,
    const float* __restrict__ Wpq, unsigned short* __restrict__ wt)
{
    __shared__ unsigned short ts[32][33];
    int b = blockIdx.x;
    const float* W; unsigned short* WT; int K, N, tile;
    if (b < 2304) {
        int z = b / 576; tile = b - z * 576;
        W = (z == 0) ? Wq : (z == 1) ? Wk : (z == 2) ? Wv : Wo;
        WT = wt + (size_t)z * 589824; K = 768; N = 768;
    } else if (b < 4608) {
        tile = b - 2304; W = Wi; WT = wt + 4 * 589824; K = 768; N = 3072;
    } else if (b < 6912) {
        tile = b - 4608; W = Wd; WT = wt + 4 * 589824 + 2359296; K = 3072; N = 768;
    } else {
        tile = b - 6912; W = Wpq; WT = wt + 4 * 589824 + 2 * 2359296; K = 3072; N = 2048;
    }
    const int nx = N >> 5;
    const int n0 = (tile % nx) * 32, k0 = (tile / nx) * 32;
    const int c = threadIdx.x & 31, rr = threadIdx.x >> 5;
#pragma unroll
    for (int i = 0; i < 4; i++) {
        int r = rr + i * 8;
        ts[c][r] = f2bf(W[(size_t)(k0 + r) * N + n0 + c]);
    }
    __syncthreads();
#pragma unroll
    for (int i = 0; i < 4; i++) {
        int rw = rr + i * 8;
        WT[(size_t)(n0 + rw) * K + k0 + c] = ts[rw][c];
    }
}

// --------------------------- MFMA GEMM (BK=64, 2-phase pipelined) ---------
// C[M,N] = A[M,K] @ B[K,N] + bias; A bf16 [M][lda], BT bf16 [N][K].
// Double-buffered LDS, BK=64; STAGE(t+1) issued before compute(t); counted
// s_waitcnt keeps next-tile loads in flight across the raw s_barrier.
// Both-sides XOR swizzle (chunk ^= row&7) -> 2-way bank aliasing (free).
// XCD-aware bijective block swizzle when grid%8==0 (T1).
template<int TM, int CMODE, int ACT, int PKMM, int BMODE>
__global__ __launch_bounds__(256) void gemm_lds(
    const unsigned short* __restrict__ A, const unsigned short* __restrict__ BT,
    const float* __restrict__ b0, const float* __restrict__ b1,
    const float* __restrict__ b2,
    void* __restrict__ Cg, void* __restrict__ Cg2,
    int M, int N, int K, int lda, int ldc, int ldc2)
{
    __shared__ unsigned short As[2][TM * 64];
    __shared__ unsigned short Bs[2][128 * 64];
    const int tid = threadIdx.x, lane = tid & 63, w = tid >> 6;
    const int l15 = lane & 15, l4 = lane >> 4;
    const int wr = w >> 1, wc = w & 1;
    constexpr int NI = TM / 32;            // A fragments per wave (per k-half)

    // XCD-aware swizzle of flat block id (bijective; grid%8==0 in all uses)
    int bx = blockIdx.x, by = blockIdx.y;
    {
        const int nx = gridDim.x, nwg = nx * gridDim.y;
        if ((nwg & 7) == 0) {
            int flat = by * nx + bx;
            const int cpx = nwg >> 3;
            flat = (flat & 7) * cpx + (flat >> 3);
            bx = flat % nx; by = flat / nx;
        }
    }

    size_t aoff = 0, boff = 0, coff = 0;
    if (PKMM) {
        int z = blockIdx.z;
        aoff = (size_t)(z >> 1) * KD + (size_t)(z & 1) * HALF;
        boff = (size_t)z * NK * HALF;
        coff = (size_t)z * NK;
    }
    const int rowA0 = by * TM, rowB0 = bx * 128;

    // staging: wave writes 1KB per call = 8 rows x 8 chunks (16B each)
    const int sr = lane >> 3, sc = lane & 7;
    const int scg = sc ^ sr;               // global chunk for swizzled store
    const int cx = l15 & 7;                // read-side row&7

    f32x4 acc[NI][4];
#pragma unroll
    for (int i = 0; i < NI; i++)
#pragma unroll
        for (int j = 0; j < 4; j++) acc[i][j] = (f32x4){0.f, 0.f, 0.f, 0.f};

    auto STAGE = [&](int t, int buf) {
        const int k0 = t * 64;
        if (TM == 128) {
#pragma unroll
            for (int i = 0; i < 4; i++) {
                const int r0 = w * 32 + i * 8;
                ld_lds16(&A[aoff + (size_t)(rowA0 + r0 + sr) * lda + k0 + scg * 8],
                         &As[buf][r0 * 64]);
            }
        } else {
#pragma unroll
            for (int i = 0; i < 2; i++) {
                const int r0 = w * 16 + i * 8;
                ld_lds16(&A[aoff + (size_t)(rowA0 + r0 + sr) * lda + k0 + scg * 8],
                         &As[buf][r0 * 64]);
            }
        }
#pragma unroll
        for (int i = 0; i < 4; i++) {
            const int r0 = w * 32 + i * 8;
            ld_lds16(&BT[boff + (size_t)(rowB0 + r0 + sr) * K + k0 + scg * 8],
                     &Bs[buf][r0 * 64]);
        }
    };

    const int NT = K / 64;
    STAGE(0, 0);
    for (int t = 0; t < NT; ++t) {
        const int cur = t & 1;
        if (t + 1 < NT) {
            STAGE(t + 1, cur ^ 1);
            if constexpr (TM == 128) asm volatile("s_waitcnt vmcnt(8)" ::: "memory");
            else                     asm volatile("s_waitcnt vmcnt(6)" ::: "memory");
        } else {
            asm volatile("s_waitcnt vmcnt(0)" ::: "memory");
        }
        __builtin_amdgcn_sched_barrier(0);
        __builtin_amdgcn_s_barrier();
        __builtin_amdgcn_sched_barrier(0);

        short8_t af[2][NI], bf[2][4];
#pragma unroll
        for (int h = 0; h < 2; h++) {
            const int co = ((l4 + 4 * h) ^ cx) * 8;
#pragma unroll
            for (int i = 0; i < NI; i++)
                af[h][i] = *(const short8_t*)&As[cur][(wr * (TM / 2) + i * 16 + l15) * 64 + co];
#pragma unroll
            for (int j = 0; j < 4; j++)
                bf[h][j] = *(const short8_t*)&Bs[cur][(wc * 64 + j * 16 + l15) * 64 + co];
        }
#pragma unroll
        for (int h = 0; h < 2; h++)
#pragma unroll
            for (int i = 0; i < NI; i++)
#pragma unroll
                for (int j = 0; j < 4; j++)
                    acc[i][j] = __builtin_amdgcn_mfma_f32_16x16x32_bf16(af[h][i], bf[h][j], acc[i][j], 0, 0, 0);
        __builtin_amdgcn_sched_barrier(0);
        __builtin_amdgcn_s_barrier();
        __builtin_amdgcn_sched_barrier(0);
    }

    // ---- epilogue; D: col=lane&15, row=(lane>>4)*4+reg
#pragma unroll
    for (int i = 0; i < NI; i++) {
#pragma unroll
        for (int j = 0; j < 4; j++) {
            const int row = rowA0 + wr * (TM / 2) + i * 16 + l4 * 4;
            const int col = rowB0 + wc * 64 + j * 16 + l15;
            float bv;
            if (PKMM) bv = 0.f;
            else if (BMODE == 0) bv = b0[col];
            else if (BMODE == 1) bv = (col < 768) ? b0[col] : (col < 1536 ? b1[col - 768] : b2[col - 1536]);
            else bv = (col < 768) ? b0[col] : b1[col - 768];
#pragma unroll
            for (int jj = 0; jj < 4; jj++) {
                float v = acc[i][j][jj] + bv;
                if (ACT == 1) v = 0.5f * v * (1.0f + erff(v * 0.70710678118654752f));
                if (CMODE == 0)
                    ((float*)Cg)[coff + (size_t)(row + jj) * ldc + col] = v;
                else if (CMODE == 1)
                    ((unsigned short*)Cg)[coff + (size_t)(row + jj) * ldc + col] = f2bf(v);
                else {
                    if (col < 768)
                        ((float*)Cg)[(size_t)(row + jj) * ldc + col] = v;
                    else
                        ((unsigned short*)Cg2)[(size_t)(row + jj) * ldc2 + (col - 768)] = f2bf(v);
                }
            }
        }
    }
}

// ----------------------------------------------------- MFMA flash attention
constexpr int AST = 72;   // bf16 elem stride

__global__ __launch_bounds__(256) void attn_mfma(const unsigned short* __restrict__ qkv,
    unsigned short* __restrict__ ctx)
{
    __shared__ unsigned short Qs[64 * AST], Ks[64 * AST], Vt[64 * AST], Ss[64 * AST];
    const int tid = threadIdx.x, lane = tid & 63, w = tid >> 6;
    const int l15 = lane & 15, l4 = lane >> 4;
    const int h = blockIdx.y, b = blockIdx.z, q0 = blockIdx.x * 64;
    const int tb0 = b * CS;

#pragma unroll
    for (int it = 0; it < 2; ++it) {
        int e = it * 256 + tid, r = e >> 3, c = e & 7;
        *(uint4*)&Qs[r * AST + c * 8] =
            *(const uint4*)&qkv[(size_t)(tb0 + q0 + r) * 2304 + h * 64 + c * 8];
    }
    f32x4 accO[4];
    float mreg[4], lreg[4];
#pragma unroll
    for (int j = 0; j < 4; j++) accO[j] = (f32x4){0.f, 0.f, 0.f, 0.f};
#pragma unroll
    for (int r = 0; r < 4; r++) { mreg[r] = -1e30f; lreg[r] = 0.f; }
    __syncthreads();
    const short8_t aq0 = *(const short8_t*)&Qs[(w * 16 + l15) * AST + l4 * 8];
    const short8_t aq1 = *(const short8_t*)&Qs[(w * 16 + l15) * AST + 32 + l4 * 8];

    for (int kt = 0; kt < 8; ++kt) {
        __syncthreads();
#pragma unroll
        for (int it = 0; it < 2; ++it) {
            int e = it * 256 + tid, r = e >> 3, c = e & 7;
            *(uint4*)&Ks[r * AST + c * 8] =
                *(const uint4*)&qkv[(size_t)(tb0 + kt * 64 + r) * 2304 + 768 + h * 64 + c * 8];
            uint4 vv = *(const uint4*)&qkv[(size_t)(tb0 + kt * 64 + r) * 2304 + 1536 + h * 64 + c * 8];
            const unsigned short* pv = (const unsigned short*)&vv;
            const int rc = (((r >> 3) + c) & 7) * 8 + (r & 7);
#pragma unroll
            for (int e2 = 0; e2 < 8; ++e2)
                Vt[(c * 8 + e2) * AST + rc] = pv[e2];
        }
        __syncthreads();

        f32x4 sc[4];
#pragma unroll
        for (int j = 0; j < 4; j++) sc[j] = (f32x4){0.f, 0.f, 0.f, 0.f};
#pragma unroll
        for (int j = 0; j < 4; j++) {
            short8_t bk0 = *(const short8_t*)&Ks[(j * 16 + l15) * AST + l4 * 8];
            short8_t bk1 = *(const short8_t*)&Ks[(j * 16 + l15) * AST + 32 + l4 * 8];
            sc[j] = __builtin_amdgcn_mfma_f32_16x16x32_bf16(aq0, bk0, sc[j], 0, 0, 0);
            sc[j] = __builtin_amdgcn_mfma_f32_16x16x32_bf16(aq1, bk1, sc[j], 0, 0, 0);
        }

        float cf[4];
#pragma unroll
        for (int r = 0; r < 4; r++) {
            float s0 = sc[0][r] * 0.125f, s1 = sc[1][r] * 0.125f;
            float s2 = sc[2][r] * 0.125f, s3 = sc[3][r] * 0.125f;
            float mt = fmaxf(fmaxf(s0, s1), fmaxf(s2, s3));
            mt = fmaxf(mt, __shfl_xor(mt, 1));
            mt = fmaxf(mt, __shfl_xor(mt, 2));
            mt = fmaxf(mt, __shfl_xor(mt, 4));
            mt = fmaxf(mt, __shfl_xor(mt, 8));
            float mo = mreg[r], mn = fmaxf(mo, mt);
            float c = __expf(mo - mn);
            mreg[r] = mn; cf[r] = c;
            float p0 = __expf(s0 - mn), p1 = __expf(s1 - mn);
            float p2 = __expf(s2 - mn), p3 = __expf(s3 - mn);
            float ps = p0 + p1 + p2 + p3;
            ps += __shfl_xor(ps, 1);
            ps += __shfl_xor(ps, 2);
            ps += __shfl_xor(ps, 4);
            ps += __shfl_xor(ps, 8);
            lreg[r] = lreg[r] * c + ps;
            const int qrow = (w * 16 + l4 * 4 + r) * AST;
            Ss[qrow + l15]      = f2bf(p0);
            Ss[qrow + 16 + l15] = f2bf(p1);
            Ss[qrow + 32 + l15] = f2bf(p2);
            Ss[qrow + 48 + l15] = f2bf(p3);
        }
#pragma unroll
        for (int j = 0; j < 4; j++) {
            accO[j][0] *= cf[0]; accO[j][1] *= cf[1];
            accO[j][2] *= cf[2]; accO[j][3] *= cf[3];
        }

        const short8_t ap0 = *(const short8_t*)&Ss[(w * 16 + l15) * AST + l4 * 8];
        const short8_t ap1 = *(const short8_t*)&Ss[(w * 16 + l15) * AST + 32 + l4 * 8];
#pragma unroll
        for (int j = 0; j < 4; j++) {
            const int d = j * 16 + l15, dc = d >> 3;
            short8_t bv0 = *(const short8_t*)&Vt[d * AST + (((l4    ) + dc) & 7) * 8];
            short8_t bv1 = *(const short8_t*)&Vt[d * AST + (((l4 + 4) + dc) & 7) * 8];
            accO[j] = __builtin_amdgcn_mfma_f32_16x16x32_bf16(ap0, bv0, accO[j], 0, 0, 0);
            accO[j] = __builtin_amdgcn_mfma_f32_16x16x32_bf16(ap1, bv1, accO[j], 0, 0, 0);
        }
    }

    float inv[4];
#pragma unroll
    for (int r = 0; r < 4; r++) inv[r] = 1.0f / lreg[r];
#pragma unroll
    for (int j = 0; j < 4; j++)
#pragma unroll
        for (int r = 0; r < 4; r++)
            ctx[(size_t)(tb0 + q0 + w * 16 + l4 * 4 + r) * CD + h * 64 + j * 16 + l15] =
                f2bf(accO[j][r] * inv[r]);
}

// ----------------------------------------------------------- layernorm ----
__global__ __launch_bounds__(256) void ln_kernel(float* __restrict__ out,
    unsigned short* __restrict__ outb,
    const float* __restrict__ a, int lda,
    const float* __restrict__ b2, const float* __restrict__ c,
    const float* __restrict__ g, const float* __restrict__ bb)
{
    const int t = blockIdx.x, tid = threadIdx.x;
    __shared__ float buf[CD];
    __shared__ float red[256];
    float l = 0.f;
    for (int d = tid; d < CD; d += 256) {
        float v = a[(size_t)t * lda + d];
        if (b2) v += b2[(size_t)t * CD + d];
        if (c)  v += c[(size_t)t * CD + d];
        buf[d] = v; l += v;
    }
    red[tid] = l; __syncthreads();
    for (int o = 128; o > 0; o >>= 1) { if (tid < o) red[tid] += red[tid + o]; __syncthreads(); }
    const float mean = red[0] * (1.0f / CD); __syncthreads();
    float l2 = 0.f;
    for (int d = tid; d < CD; d += 256) { float dd = buf[d] - mean; l2 += dd * dd; }
    red[tid] = l2; __syncthreads();
    for (int o = 128; o > 0; o >>= 1) { if (tid < o) red[tid] += red[tid + o]; __syncthreads(); }
    const float inv = rsqrtf(red[0] * (1.0f / CD) + 1e-12f);
    for (int d = tid; d < CD; d += 256) {
        float v = (buf[d] - mean) * inv * g[d] + bb[d];
        out[(size_t)t * CD + d] = v;
        if (outb) outb[(size_t)t * CD + d] = f2bf(v);
    }
}

// --------------------------------------------- fused PKM top-k (both stages)
__device__ const unsigned char CCNT[32] = {32,16,10,8,6,5,4,4,3,3,2,2,2,2,2,2,
                                           1,1,1,1,1,1,1,1,1,1,1,1,1,1,1,1};

__global__ __launch_bounds__(128) void pkm_topk_kernel(const float* __restrict__ sc,
    float* __restrict__ w, int* __restrict__ ind)
{
    const int gid = blockIdx.x;            // t*PH + h
    const int tid = threadIdx.x;
    __shared__ float sv[256];
    __shared__ int   si_[256];
    __shared__ float cv[128];
    __shared__ int   ci[128];

    const float* s = sc + (size_t)gid * 256;
    sv[tid] = s[tid];             si_[tid] = tid;
    sv[tid + 128] = s[tid + 128]; si_[tid + 128] = tid;
    __syncthreads();

    for (int k = 2; k <= 128; k <<= 1) {
        for (int j = k >> 1; j > 0; j >>= 1) {
            const int hh = tid >> 6, p = tid & 63;
            const int i = ((p & ~(j - 1)) << 1) | (p & (j - 1));
            const int l = i | j;
            const int bi_ = hh * 128 + i, bl = hh * 128 + l;
            float av = sv[bi_], bv2 = sv[bl];
            int   ai = si_[bi_], bx = si_[bl];
            const bool agtb = (av > bv2) || (av == bv2 && ai < bx);
            const bool desc = ((i & k) == 0);
            if (agtb != desc) { sv[bi_] = bv2; sv[bl] = av; si_[bi_] = bx; si_[bl] = ai; }
            __syncthreads();
        }
    }

    {
        float val; int fi;
        if (tid < 119) {
            int tt = tid, ii = 0;
            while (tt >= (int)CCNT[ii]) { tt -= CCNT[ii]; ii++; }
            val = sv[ii] + sv[128 + tt];
            fi = ii * 32 + tt;
        } else { val = -3.0e38f; fi = 0x7FFFFFF; }
        cv[tid] = val; ci[tid] = fi;
    }
    __syncthreads();

    for (int k = 2; k <= 128; k <<= 1) {
        for (int j = k >> 1; j > 0; j >>= 1) {
            if (tid < 64) {
                const int p = tid;
                const int i = ((p & ~(j - 1)) << 1) | (p & (j - 1));
                const int l = i | j;
                float av = cv[i], bv2 = cv[l];
                int   ai = ci[i], bx = ci[l];
                const bool agtb = (av > bv2) || (av == bv2 && ai < bx);
                const bool desc = ((i & k) == 0);
                if (agtb != desc) { cv[i] = bv2; cv[l] = av; ci[i] = bx; ci[l] = ai; }
            }
            __syncthreads();
        }
    }

    if (tid < 32) {
        const float mx = cv[0];
        float e = __expf(cv[tid] - mx);
        float s2 = e;
        for (int o = 16; o > 0; o >>= 1) s2 += __shfl_xor(s2, o);
        const int fi = ci[tid];
        const int ii = fi >> 5, jj = fi & 31;
        w[(size_t)gid * KNN + tid] = e / s2;
        ind[(size_t)gid * KNN + tid] = si_[ii] * NK + si_[128 + jj];
    }
}

// --------------------------------------------------------- PKM gather -----
__global__ __launch_bounds__(384) void pkm_gather_kernel(const float* __restrict__ w,
    const int* __restrict__ ind, const unsigned short* __restrict__ valb,
    float* __restrict__ out)
{
    const int t = blockIdx.x, tid = threadIdx.x;
    __shared__ float ws[PH * KNN];
    __shared__ int   is[PH * KNN];
    if (tid < PH * KNN) {
        ws[tid] = w[(size_t)t * PH * KNN + tid];
        is[tid] = ind[(size_t)t * PH * KNN + tid];
    }
    __syncthreads();
    const int d0 = tid * 2;
    float a0 = 0.f, a1 = 0.f;
#pragma unroll 4
    for (int i = 0; i < PH * KNN; i++) {
        unsigned pv = *(const unsigned*)&valb[(size_t)is[i] * CD + d0];
        float wi = ws[i];
        a0 = fmaf(wi, bf2f((unsigned short)(pv & 0xffff)), a0);
        a1 = fmaf(wi, bf2f((unsigned short)(pv >> 16)), a1);
    }
    out[(size_t)t * CD + d0] = a0;
    out[(size_t)t * CD + d0 + 1] = a1;
}

// ------------------------------------------------------------- launch -----
extern "C" void kernel_launch(void* const* d_in, const int* in_sizes, int n_in,
                              void* d_out, int out_size, void* d_ws, size_t ws_size,
                              hipStream_t stream)
{
    const float* x      = (const float*)d_in[0];
    const float* Wq     = (const float*)d_in[1];
    const float* bq     = (const float*)d_in[2];
    const float* Wk     = (const float*)d_in[3];
    const float* bk     = (const float*)d_in[4];
    const float* Wv     = (const float*)d_in[5];
    const float* bv     = (const float*)d_in[6];
    const float* Wo     = (const float*)d_in[7];
    const float* bo     = (const float*)d_in[8];
    const float* ln1_g  = (const float*)d_in[9];
    const float* ln1_b  = (const float*)d_in[10];
    const float* Wi     = (const float*)d_in[11];
    const float* bi     = (const float*)d_in[12];
    const float* Wd     = (const float*)d_in[13];
    const float* bd     = (const float*)d_in[14];
    const float* ln2_g  = (const float*)d_in[15];
    const float* ln2_b  = (const float*)d_in[16];
    const float* Wpq    = (const float*)d_in[17];
    const float* bpq    = (const float*)d_in[18];
    const float* keys   = (const float*)d_in[19];
    const float* values = (const float*)d_in[20];

    char* W = (char*)d_ws;
    // region A: qkvb bf16 (9.44MB) -> sbuf fp32 (8.39MB) -> pkmo fp32 (6.29MB)
    unsigned short* qkvb  = (unsigned short*)(W + 0);
    float*          sbuf  = (float*)(W + 0);
    float*          pkmo  = (float*)(W + 0);
    // region B: attnf fp32 (6.29MB), alive LN1..LN2
    float*          attnf = (float*)(W + 9437184);
    // region C: ctxb bf16 (3.1MB) -> interb bf16 (12.58MB) -> wgt/ind
    unsigned short* ctxb  = (unsigned short*)(W + 15728640);
    unsigned short* interb= (unsigned short*)(W + 15728640);
    float*          wgt   = (float*)(W + 15728640);
    int*            ind   = (int*)(W + 16777216);
    // region D: xb/woout/dense (@28.3MB), attnb (@34.6MB), pqb (@37.7MB)
    unsigned short* xb    = (unsigned short*)(W + 28311552);
    float*          woout = (float*)(W + 28311552);
    float*          dense = (float*)(W + 28311552);
    unsigned short* attnb = (unsigned short*)(W + 34603008);
    unsigned short* pqb   = (unsigned short*)(W + 37748736);
    // keysb bf16 (0.5MB)
    unsigned short* keysb = (unsigned short*)(W + 46137344);
    // wt bf16 (26.74MB) -> valb bf16 (25.17MB) after last weight GEMM
    unsigned short* wt    = (unsigned short*)(W + 46661632);
    unsigned short* valb  = (unsigned short*)(W + 46661632);

    const dim3 blk(256);
    const size_t WOFF = 589824;   // 768*768

    // input conversions
    cvt_bf16x4<<<2048, blk, 0, stream>>>(x, xb, CT * CD / 4);
    cvt_bf16x4<<<256, blk, 0, stream>>>(keys, keysb, (PH * 2 * NK * HALF) / 4);

    // merged weight transpose (all 7 weights, one launch)
    transpose_all<<<13056, blk, 0, stream>>>(Wq, Wk, Wv, Wo, Wi, Wd, Wpq, wt);

    // merged QKV projection: [2048][2304] bf16  (TM=64 -> 576 blocks)
    gemm_lds<64, 1, 0, 0, 1><<<dim3(18, 32), blk, 0, stream>>>(
        xb, wt, bq, bk, bv, qkvb, nullptr, CT, 2304, CD, CD, 2304, 0);

    // flash attention (MFMA)
    attn_mfma<<<dim3(8, 12, 4), blk, 0, stream>>>(qkvb, ctxb);

    // output projection + LN1
    gemm_lds<64, 0, 0, 0, 0><<<dim3(6, 32), blk, 0, stream>>>(
        ctxb, wt + 3 * WOFF, bo, nullptr, nullptr, woout, nullptr, CT, CD, CD, CD, CD, 0);
    ln_kernel<<<CT, blk, 0, stream>>>(attnf, attnb, woout, CD, x, nullptr, ln1_g, ln1_b);

    // FFN up (GELU, bf16 out)  (TM=64 -> 768 blocks, 3/CU)
    gemm_lds<64, 1, 1, 0, 0><<<dim3(24, 32), blk, 0, stream>>>(
        attnb, wt + 4 * WOFF, bi, nullptr, nullptr, interb, nullptr, CT, CFF, CD, CD, CFF, 0);

    // merged FFN down + PKM query proj (TM=64 -> 704 blocks, 2.75/CU)
    gemm_lds<64, 2, 0, 0, 2><<<dim3(22, 32), blk, 0, stream>>>(
        interb, wt + 4 * WOFF + 2359296, bd, bpq, nullptr, dense, pqb, CT, 2816, CFF, CFF, CD, 2048);

    // values -> bf16 (into dead wt region)
    cvt_bf16x4<<<2048, blk, 0, stream>>>(values, valb, (NK * NK * CD) / 4);

    // PKM scores: 8 batched GEMMs (z = h*2+half), A = pqb bf16
    gemm_lds<64, 0, 0, 1, 0><<<dim3(1, 32, 8), blk, 0, stream>>>(
        pqb, keysb, nullptr, nullptr, nullptr, sbuf, nullptr, CT, NK, HALF, 2048, PH * 2 * NK, 0);

    // fused two-stage top-k + softmax
    pkm_topk_kernel<<<CT * PH, dim3(128), 0, stream>>>(sbuf, wgt, ind);

    // gather (bf16 values)
    pkm_gather_kernel<<<CT, dim3(384), 0, stream>>>(wgt, ind, valb, pkmo);

    // final LN over dense + pkm + attn
    ln_kernel<<<CT, blk, 0, stream>>>((float*)d_out, nullptr, dense, CD, pkmo, attnf, ln2_g, ln2_b);
}

// Round 9
// 247.772 us; speedup vs baseline: 15.5771x; 1.0419x over previous
//
#include <hip/hip_runtime.h>
#include <math.h>

// Problem constants
constexpr int CB = 4, CS = 512, CD = 768, CFF = 3072, CH = 12, CHD = 64;
constexpr int CT = CB * CS;            // 2048 tokens
constexpr int PH = 4, KD = 512, NK = 128, KNN = 32, HALF = 256;

typedef __attribute__((ext_vector_type(8))) short short8_t;   // 8 bf16 (4 VGPRs)
typedef __attribute__((ext_vector_type(4))) float f32x4;      // MFMA accumulator

__device__ __forceinline__ unsigned short f2bf(float f) {
    unsigned int u = __float_as_uint(f);
    return (unsigned short)((u + 0x7FFF + ((u >> 16) & 1)) >> 16);  // RNE
}
__device__ __forceinline__ float bf2f(unsigned short h) {
    return __uint_as_float(((unsigned)h) << 16);
}

// async global->LDS, 16B per lane; LDS dest = wave-uniform base + lane*16
__device__ __forceinline__ void ld_lds16(const unsigned short* g, unsigned short* l) {
    __builtin_amdgcn_global_load_lds(
        (const __attribute__((address_space(1))) void*)g,
        (__attribute__((address_space(3))) void*)l, 16, 0, 0);
}

// ------------------------------------------------------------ fp32->bf16 --
__global__ __launch_bounds__(256) void cvt_bf16x4(const float* __restrict__ in,
    unsigned short* __restrict__ out, int n4)
{
    for (int i = blockIdx.x * 256 + threadIdx.x; i < n4; i += gridDim.x * 256) {
        float4 v = ((const float4*)in)[i];
        ushort4 o = { f2bf(v.x), f2bf(v.y), f2bf(v.z), f2bf(v.w) };
        ((ushort4*)out)[i] = o;
    }
}

// ------------------------- fused prep: weight transposes + x/keys cvt -----
// blocks [0,6528): transpose 64k x 32n tiles; [6528,8064): x cvt;
// [8064,8320): keys cvt.
__global__ __launch_bounds__(256) void prep_kernel(
    const float* __restrict__ Wq, const float* __restrict__ Wk,
    const float* __restrict__ Wv, const float* __restrict__ Wo,
    const float* __restrict__ Wi, const float* __restrict__ Wd,
    const float* __restrict__ Wpq, unsigned short* __restrict__ wt,
    const float* __restrict__ x, unsigned short* __restrict__ xb,
    const float* __restrict__ keys, unsigned short* __restrict__ keysb)
{
    const int b = blockIdx.x, tid = threadIdx.x;
    if (b < 6528) {
        __shared__ unsigned short ts[32][72];   // [n][k], 16B-aligned rows
        const float* W; unsigned short* WT; int K, N, tile;
        if (b < 1152) {
            int z = b / 288; tile = b - z * 288;
            W = (z == 0) ? Wq : (z == 1) ? Wk : (z == 2) ? Wv : Wo;
            WT = wt + (size_t)z * 589824; K = 768; N = 768;
        } else if (b < 2304) {
            tile = b - 1152; W = Wi; WT = wt + 4 * 589824; K = 768; N = 3072;
        } else if (b < 3456) {
            tile = b - 2304; W = Wd; WT = wt + 4 * 589824 + 2359296; K = 3072; N = 768;
        } else {
            tile = b - 3456; W = Wpq; WT = wt + 4 * 589824 + 2 * 2359296; K = 3072; N = 2048;
        }
        const int nx = N >> 5;                 // n-tiles
        const int n0 = (tile % nx) * 32, k0 = (tile / nx) * 64;
        const int c = tid & 31, rr = tid >> 5;
#pragma unroll
        for (int i = 0; i < 8; i++) {
            int r = rr + i * 8;                // 64 k-rows
            ts[c][r] = f2bf(W[(size_t)(k0 + r) * N + n0 + c]);
        }
        __syncthreads();
        const int nn = tid >> 3, kc = tid & 7; // 32 n-rows x 8 k-chunks
        uint4 v = *(const uint4*)&ts[nn][kc * 8];
        *(uint4*)&WT[(size_t)(n0 + nn) * K + k0 + kc * 8] = v;
    } else if (b < 8064) {
        const int i = (b - 6528) * 256 + tid;  // x: 393216 float4
        float4 v = ((const float4*)x)[i];
        ushort4 o = { f2bf(v.x), f2bf(v.y), f2bf(v.z), f2bf(v.w) };
        ((ushort4*)xb)[i] = o;
    } else {
        const int i = (b - 8064) * 256 + tid;  // keys: 65536 float4
        float4 v = ((const float4*)keys)[i];
        ushort4 o = { f2bf(v.x), f2bf(v.y), f2bf(v.z), f2bf(v.w) };
        ((ushort4*)keysb)[i] = o;
    }
}

// --------------------------- MFMA GEMM (BK=64, 2-phase pipelined) ---------
// C[M,N] = A[M,K] @ B[K,N] + bias; A bf16 [M][lda], BT bf16 [N][K].
// Double-buffered LDS, BK=64; STAGE(t+1) issued before compute(t); counted
// s_waitcnt keeps next-tile loads in flight across the raw s_barrier.
// Both-sides XOR swizzle (chunk ^= row&7) -> 2-way bank aliasing (free).
// XCD-aware bijective block swizzle when grid%8==0 (T1). TM in {32,64,128}.
template<int TM, int CMODE, int ACT, int PKMM, int BMODE>
__global__ __launch_bounds__(256) void gemm_lds(
    const unsigned short* __restrict__ A, const unsigned short* __restrict__ BT,
    const float* __restrict__ b0, const float* __restrict__ b1,
    const float* __restrict__ b2,
    void* __restrict__ Cg, void* __restrict__ Cg2,
    int M, int N, int K, int lda, int ldc, int ldc2)
{
    __shared__ unsigned short As[2][TM * 64];
    __shared__ unsigned short Bs[2][128 * 64];
    const int tid = threadIdx.x, lane = tid & 63, w = tid >> 6;
    const int l15 = lane & 15, l4 = lane >> 4;
    const int wr = w >> 1, wc = w & 1;
    constexpr int NI = (TM + 31) / 32 > 1 ? TM / 32 : 1;   // A frags per wave

    // XCD-aware swizzle of flat block id (bijective; grid%8==0 in all uses)
    int bx = blockIdx.x, by = blockIdx.y;
    {
        const int nx = gridDim.x, nwg = nx * gridDim.y;
        if ((nwg & 7) == 0) {
            int flat = by * nx + bx;
            const int cpx = nwg >> 3;
            flat = (flat & 7) * cpx + (flat >> 3);
            bx = flat % nx; by = flat / nx;
        }
    }

    size_t aoff = 0, boff = 0, coff = 0;
    if (PKMM) {
        int z = blockIdx.z;
        aoff = (size_t)(z >> 1) * KD + (size_t)(z & 1) * HALF;
        boff = (size_t)z * NK * HALF;
        coff = (size_t)z * NK;
    }
    const int rowA0 = by * TM, rowB0 = bx * 128;

    // staging: wave writes 1KB per call = 8 rows x 8 chunks (16B each)
    const int sr = lane >> 3, sc = lane & 7;
    const int scg = sc ^ sr;               // global chunk for swizzled store
    const int cx = l15 & 7;                // read-side row&7

    f32x4 acc[NI][4];
#pragma unroll
    for (int i = 0; i < NI; i++)
#pragma unroll
        for (int j = 0; j < 4; j++) acc[i][j] = (f32x4){0.f, 0.f, 0.f, 0.f};

    auto STAGE = [&](int t, int buf) {
        const int k0 = t * 64;
        if (TM == 128) {
#pragma unroll
            for (int i = 0; i < 4; i++) {
                const int r0 = w * 32 + i * 8;
                ld_lds16(&A[aoff + (size_t)(rowA0 + r0 + sr) * lda + k0 + scg * 8],
                         &As[buf][r0 * 64]);
            }
        } else if (TM == 64) {
#pragma unroll
            for (int i = 0; i < 2; i++) {
                const int r0 = w * 16 + i * 8;
                ld_lds16(&A[aoff + (size_t)(rowA0 + r0 + sr) * lda + k0 + scg * 8],
                         &As[buf][r0 * 64]);
            }
        } else {
            const int r0 = w * 8;
            ld_lds16(&A[aoff + (size_t)(rowA0 + r0 + sr) * lda + k0 + scg * 8],
                     &As[buf][r0 * 64]);
        }
#pragma unroll
        for (int i = 0; i < 4; i++) {
            const int r0 = w * 32 + i * 8;
            ld_lds16(&BT[boff + (size_t)(rowB0 + r0 + sr) * K + k0 + scg * 8],
                     &Bs[buf][r0 * 64]);
        }
    };

    const int NT = K / 64;
    STAGE(0, 0);
    for (int t = 0; t < NT; ++t) {
        const int cur = t & 1;
        if (t + 1 < NT) {
            STAGE(t + 1, cur ^ 1);
            if constexpr (TM == 128)     asm volatile("s_waitcnt vmcnt(8)" ::: "memory");
            else if constexpr (TM == 64) asm volatile("s_waitcnt vmcnt(6)" ::: "memory");
            else                         asm volatile("s_waitcnt vmcnt(5)" ::: "memory");
        } else {
            asm volatile("s_waitcnt vmcnt(0)" ::: "memory");
        }
        __builtin_amdgcn_sched_barrier(0);
        __builtin_amdgcn_s_barrier();
        __builtin_amdgcn_sched_barrier(0);

        short8_t af[2][NI], bf[2][4];
#pragma unroll
        for (int h = 0; h < 2; h++) {
            const int co = ((l4 + 4 * h) ^ cx) * 8;
#pragma unroll
            for (int i = 0; i < NI; i++)
                af[h][i] = *(const short8_t*)&As[cur][(wr * (TM / 2) + i * 16 + l15) * 64 + co];
#pragma unroll
            for (int j = 0; j < 4; j++)
                bf[h][j] = *(const short8_t*)&Bs[cur][(wc * 64 + j * 16 + l15) * 64 + co];
        }
#pragma unroll
        for (int h = 0; h < 2; h++)
#pragma unroll
            for (int i = 0; i < NI; i++)
#pragma unroll
                for (int j = 0; j < 4; j++)
                    acc[i][j] = __builtin_amdgcn_mfma_f32_16x16x32_bf16(af[h][i], bf[h][j], acc[i][j], 0, 0, 0);
        __builtin_amdgcn_sched_barrier(0);
        __builtin_amdgcn_s_barrier();
        __builtin_amdgcn_sched_barrier(0);
    }

    // ---- epilogue; D: col=lane&15, row=(lane>>4)*4+reg
#pragma unroll
    for (int i = 0; i < NI; i++) {
#pragma unroll
        for (int j = 0; j < 4; j++) {
            const int row = rowA0 + wr * (TM / 2) + i * 16 + l4 * 4;
            const int col = rowB0 + wc * 64 + j * 16 + l15;
            float bv;
            if (PKMM) bv = 0.f;
            else if (BMODE == 0) bv = b0[col];
            else if (BMODE == 1) bv = (col < 768) ? b0[col] : (col < 1536 ? b1[col - 768] : b2[col - 1536]);
            else bv = (col < 768) ? b0[col] : b1[col - 768];
#pragma unroll
            for (int jj = 0; jj < 4; jj++) {
                float v = acc[i][j][jj] + bv;
                if (ACT == 1) v = 0.5f * v * (1.0f + erff(v * 0.70710678118654752f));
                if (CMODE == 0)
                    ((float*)Cg)[coff + (size_t)(row + jj) * ldc + col] = v;
                else if (CMODE == 1)
                    ((unsigned short*)Cg)[coff + (size_t)(row + jj) * ldc + col] = f2bf(v);
                else {
                    if (col < 768)
                        ((float*)Cg)[(size_t)(row + jj) * ldc + col] = v;
                    else
                        ((unsigned short*)Cg2)[(size_t)(row + jj) * ldc2 + (col - 768)] = f2bf(v);
                }
            }
        }
    }
}

// ----------------------------------------------------- MFMA flash attention
constexpr int AST = 72;   // bf16 elem stride

__global__ __launch_bounds__(256) void attn_mfma(const unsigned short* __restrict__ qkv,
    unsigned short* __restrict__ ctx)
{
    __shared__ unsigned short Qs[64 * AST], Ks[64 * AST], Vt[64 * AST], Ss[64 * AST];
    const int tid = threadIdx.x, lane = tid & 63, w = tid >> 6;
    const int l15 = lane & 15, l4 = lane >> 4;
    const int h = blockIdx.y, b = blockIdx.z, q0 = blockIdx.x * 64;
    const int tb0 = b * CS;

#pragma unroll
    for (int it = 0; it < 2; ++it) {
        int e = it * 256 + tid, r = e >> 3, c = e & 7;
        *(uint4*)&Qs[r * AST + c * 8] =
            *(const uint4*)&qkv[(size_t)(tb0 + q0 + r) * 2304 + h * 64 + c * 8];
    }
    f32x4 accO[4];
    float mreg[4], lreg[4];
#pragma unroll
    for (int j = 0; j < 4; j++) accO[j] = (f32x4){0.f, 0.f, 0.f, 0.f};
#pragma unroll
    for (int r = 0; r < 4; r++) { mreg[r] = -1e30f; lreg[r] = 0.f; }
    __syncthreads();
    const short8_t aq0 = *(const short8_t*)&Qs[(w * 16 + l15) * AST + l4 * 8];
    const short8_t aq1 = *(const short8_t*)&Qs[(w * 16 + l15) * AST + 32 + l4 * 8];

    for (int kt = 0; kt < 8; ++kt) {
        __syncthreads();
#pragma unroll
        for (int it = 0; it < 2; ++it) {
            int e = it * 256 + tid, r = e >> 3, c = e & 7;
            *(uint4*)&Ks[r * AST + c * 8] =
                *(const uint4*)&qkv[(size_t)(tb0 + kt * 64 + r) * 2304 + 768 + h * 64 + c * 8];
            uint4 vv = *(const uint4*)&qkv[(size_t)(tb0 + kt * 64 + r) * 2304 + 1536 + h * 64 + c * 8];
            const unsigned short* pv = (const unsigned short*)&vv;
            const int rc = (((r >> 3) + c) & 7) * 8 + (r & 7);
#pragma unroll
            for (int e2 = 0; e2 < 8; ++e2)
                Vt[(c * 8 + e2) * AST + rc] = pv[e2];
        }
        __syncthreads();

        f32x4 sc[4];
#pragma unroll
        for (int j = 0; j < 4; j++) sc[j] = (f32x4){0.f, 0.f, 0.f, 0.f};
#pragma unroll
        for (int j = 0; j < 4; j++) {
            short8_t bk0 = *(const short8_t*)&Ks[(j * 16 + l15) * AST + l4 * 8];
            short8_t bk1 = *(const short8_t*)&Ks[(j * 16 + l15) * AST + 32 + l4 * 8];
            sc[j] = __builtin_amdgcn_mfma_f32_16x16x32_bf16(aq0, bk0, sc[j], 0, 0, 0);
            sc[j] = __builtin_amdgcn_mfma_f32_16x16x32_bf16(aq1, bk1, sc[j], 0, 0, 0);
        }

        float cf[4];
#pragma unroll
        for (int r = 0; r < 4; r++) {
            float s0 = sc[0][r] * 0.125f, s1 = sc[1][r] * 0.125f;
            float s2 = sc[2][r] * 0.125f, s3 = sc[3][r] * 0.125f;
            float mt = fmaxf(fmaxf(s0, s1), fmaxf(s2, s3));
            mt = fmaxf(mt, __shfl_xor(mt, 1));
            mt = fmaxf(mt, __shfl_xor(mt, 2));
            mt = fmaxf(mt, __shfl_xor(mt, 4));
            mt = fmaxf(mt, __shfl_xor(mt, 8));
            float mo = mreg[r], mn = fmaxf(mo, mt);
            float c = __expf(mo - mn);
            mreg[r] = mn; cf[r] = c;
            float p0 = __expf(s0 - mn), p1 = __expf(s1 - mn);
            float p2 = __expf(s2 - mn), p3 = __expf(s3 - mn);
            float ps = p0 + p1 + p2 + p3;
            ps += __shfl_xor(ps, 1);
            ps += __shfl_xor(ps, 2);
            ps += __shfl_xor(ps, 4);
            ps += __shfl_xor(ps, 8);
            lreg[r] = lreg[r] * c + ps;
            const int qrow = (w * 16 + l4 * 4 + r) * AST;
            Ss[qrow + l15]      = f2bf(p0);
            Ss[qrow + 16 + l15] = f2bf(p1);
            Ss[qrow + 32 + l15] = f2bf(p2);
            Ss[qrow + 48 + l15] = f2bf(p3);
        }
#pragma unroll
        for (int j = 0; j < 4; j++) {
            accO[j][0] *= cf[0]; accO[j][1] *= cf[1];
            accO[j][2] *= cf[2]; accO[j][3] *= cf[3];
        }

        const short8_t ap0 = *(const short8_t*)&Ss[(w * 16 + l15) * AST + l4 * 8];
        const short8_t ap1 = *(const short8_t*)&Ss[(w * 16 + l15) * AST + 32 + l4 * 8];
#pragma unroll
        for (int j = 0; j < 4; j++) {
            const int d = j * 16 + l15, dc = d >> 3;
            short8_t bv0 = *(const short8_t*)&Vt[d * AST + (((l4    ) + dc) & 7) * 8];
            short8_t bv1 = *(const short8_t*)&Vt[d * AST + (((l4 + 4) + dc) & 7) * 8];
            accO[j] = __builtin_amdgcn_mfma_f32_16x16x32_bf16(ap0, bv0, accO[j], 0, 0, 0);
            accO[j] = __builtin_amdgcn_mfma_f32_16x16x32_bf16(ap1, bv1, accO[j], 0, 0, 0);
        }
    }

    float inv[4];
#pragma unroll
    for (int r = 0; r < 4; r++) inv[r] = 1.0f / lreg[r];
#pragma unroll
    for (int j = 0; j < 4; j++)
#pragma unroll
        for (int r = 0; r < 4; r++)
            ctx[(size_t)(tb0 + q0 + w * 16 + l4 * 4 + r) * CD + h * 64 + j * 16 + l15] =
                f2bf(accO[j][r] * inv[r]);
}

// ----------------------------------------------------------- layernorm ----
__global__ __launch_bounds__(256) void ln_kernel(float* __restrict__ out,
    unsigned short* __restrict__ outb,
    const float* __restrict__ a, int lda,
    const float* __restrict__ b2,
    const float* __restrict__ g, const float* __restrict__ bb)
{
    const int t = blockIdx.x, tid = threadIdx.x;
    __shared__ float buf[CD];
    __shared__ float red[256];
    float l = 0.f;
    for (int d = tid; d < CD; d += 256) {
        float v = a[(size_t)t * lda + d];
        if (b2) v += b2[(size_t)t * CD + d];
        buf[d] = v; l += v;
    }
    red[tid] = l; __syncthreads();
    for (int o = 128; o > 0; o >>= 1) { if (tid < o) red[tid] += red[tid + o]; __syncthreads(); }
    const float mean = red[0] * (1.0f / CD); __syncthreads();
    float l2 = 0.f;
    for (int d = tid; d < CD; d += 256) { float dd = buf[d] - mean; l2 += dd * dd; }
    red[tid] = l2; __syncthreads();
    for (int o = 128; o > 0; o >>= 1) { if (tid < o) red[tid] += red[tid + o]; __syncthreads(); }
    const float inv = rsqrtf(red[0] * (1.0f / CD) + 1e-12f);
    for (int d = tid; d < CD; d += 256) {
        float v = (buf[d] - mean) * inv * g[d] + bb[d];
        out[(size_t)t * CD + d] = v;
        if (outb) outb[(size_t)t * CD + d] = f2bf(v);
    }
}

// --------------------------------------------- fused PKM top-k (both stages)
__device__ const unsigned char CCNT[32] = {32,16,10,8,6,5,4,4,3,3,2,2,2,2,2,2,
                                           1,1,1,1,1,1,1,1,1,1,1,1,1,1,1,1};

__global__ __launch_bounds__(128) void pkm_topk_kernel(const float* __restrict__ sc,
    float* __restrict__ w, int* __restrict__ ind)
{
    const int gid = blockIdx.x;            // t*PH + h
    const int tid = threadIdx.x;
    __shared__ float sv[256];
    __shared__ int   si_[256];
    __shared__ float cv[128];
    __shared__ int   ci[128];

    const float* s = sc + (size_t)gid * 256;
    sv[tid] = s[tid];             si_[tid] = tid;
    sv[tid + 128] = s[tid + 128]; si_[tid + 128] = tid;
    __syncthreads();

    for (int k = 2; k <= 128; k <<= 1) {
        for (int j = k >> 1; j > 0; j >>= 1) {
            const int hh = tid >> 6, p = tid & 63;
            const int i = ((p & ~(j - 1)) << 1) | (p & (j - 1));
            const int l = i | j;
            const int bi_ = hh * 128 + i, bl = hh * 128 + l;
            float av = sv[bi_], bv2 = sv[bl];
            int   ai = si_[bi_], bx = si_[bl];
            const bool agtb = (av > bv2) || (av == bv2 && ai < bx);
            const bool desc = ((i & k) == 0);
            if (agtb != desc) { sv[bi_] = bv2; sv[bl] = av; si_[bi_] = bx; si_[bl] = ai; }
            __syncthreads();
        }
    }

    {
        float val; int fi;
        if (tid < 119) {
            int tt = tid, ii = 0;
            while (tt >= (int)CCNT[ii]) { tt -= CCNT[ii]; ii++; }
            val = sv[ii] + sv[128 + tt];
            fi = ii * 32 + tt;
        } else { val = -3.0e38f; fi = 0x7FFFFFF; }
        cv[tid] = val; ci[tid] = fi;
    }
    __syncthreads();

    for (int k = 2; k <= 128; k <<= 1) {
        for (int j = k >> 1; j > 0; j >>= 1) {
            if (tid < 64) {
                const int p = tid;
                const int i = ((p & ~(j - 1)) << 1) | (p & (j - 1));
                const int l = i | j;
                float av = cv[i], bv2 = cv[l];
                int   ai = ci[i], bx = ci[l];
                const bool agtb = (av > bv2) || (av == bv2 && ai < bx);
                const bool desc = ((i & k) == 0);
                if (agtb != desc) { cv[i] = bv2; cv[l] = av; ci[i] = bx; ci[l] = ai; }
            }
            __syncthreads();
        }
    }

    if (tid < 32) {
        const float mx = cv[0];
        float e = __expf(cv[tid] - mx);
        float s2 = e;
        for (int o = 16; o > 0; o >>= 1) s2 += __shfl_xor(s2, o);
        const int fi = ci[tid];
        const int ii = fi >> 5, jj = fi & 31;
        w[(size_t)gid * KNN + tid] = e / s2;
        ind[(size_t)gid * KNN + tid] = si_[ii] * NK + si_[128 + jj];
    }
}

// ----------------------------------- fused PKM gather + residual + LN2 ----
// block per token: gather 128 weighted rows of valb into regs, add dense +
// attn residuals, layernorm, write d_out. Eliminates pkmo buffer.
__global__ __launch_bounds__(256) void ln2_pkm_kernel(
    const float* __restrict__ dense, const float* __restrict__ attnf,
    const float* __restrict__ wgt, const int* __restrict__ ind,
    const unsigned short* __restrict__ valb,
    const float* __restrict__ g, const float* __restrict__ bb,
    float* __restrict__ out)
{
    const int t = blockIdx.x, tid = threadIdx.x;
    __shared__ float ws[PH * KNN];
    __shared__ int   is[PH * KNN];
    __shared__ float red[256];
    if (tid < PH * KNN) {
        ws[tid] = wgt[(size_t)t * PH * KNN + tid];
        is[tid] = ind[(size_t)t * PH * KNN + tid];
    }
    __syncthreads();
    float a0 = 0.f, a1 = 0.f, a2 = 0.f;
#pragma unroll 4
    for (int i = 0; i < PH * KNN; i++) {
        const unsigned short* vr = valb + (size_t)is[i] * CD;
        const float wv = ws[i];
        a0 = fmaf(wv, bf2f(vr[tid]), a0);
        a1 = fmaf(wv, bf2f(vr[tid + 256]), a1);
        a2 = fmaf(wv, bf2f(vr[tid + 512]), a2);
    }
    const size_t base = (size_t)t * CD;
    float v0 = a0 + dense[base + tid]       + attnf[base + tid];
    float v1 = a1 + dense[base + tid + 256] + attnf[base + tid + 256];
    float v2 = a2 + dense[base + tid + 512] + attnf[base + tid + 512];

    red[tid] = v0 + v1 + v2; __syncthreads();
    for (int o = 128; o > 0; o >>= 1) { if (tid < o) red[tid] += red[tid + o]; __syncthreads(); }
    const float mean = red[0] * (1.0f / CD); __syncthreads();
    float d0 = v0 - mean, d1 = v1 - mean, d2 = v2 - mean;
    red[tid] = d0 * d0 + d1 * d1 + d2 * d2; __syncthreads();
    for (int o = 128; o > 0; o >>= 1) { if (tid < o) red[tid] += red[tid + o]; __syncthreads(); }
    const float inv = rsqrtf(red[0] * (1.0f / CD) + 1e-12f);
    out[base + tid]       = d0 * inv * g[tid]       + bb[tid];
    out[base + tid + 256] = d1 * inv * g[tid + 256] + bb[tid + 256];
    out[base + tid + 512] = d2 * inv * g[tid + 512] + bb[tid + 512];
}

// ------------------------------------------------------------- launch -----
extern "C" void kernel_launch(void* const* d_in, const int* in_sizes, int n_in,
                              void* d_out, int out_size, void* d_ws, size_t ws_size,
                              hipStream_t stream)
{
    const float* x      = (const float*)d_in[0];
    const float* Wq     = (const float*)d_in[1];
    const float* bq     = (const float*)d_in[2];
    const float* Wk     = (const float*)d_in[3];
    const float* bk     = (const float*)d_in[4];
    const float* Wv     = (const float*)d_in[5];
    const float* bv     = (const float*)d_in[6];
    const float* Wo     = (const float*)d_in[7];
    const float* bo     = (const float*)d_in[8];
    const float* ln1_g  = (const float*)d_in[9];
    const float* ln1_b  = (const float*)d_in[10];
    const float* Wi     = (const float*)d_in[11];
    const float* bi     = (const float*)d_in[12];
    const float* Wd     = (const float*)d_in[13];
    const float* bd     = (const float*)d_in[14];
    const float* ln2_g  = (const float*)d_in[15];
    const float* ln2_b  = (const float*)d_in[16];
    const float* Wpq    = (const float*)d_in[17];
    const float* bpq    = (const float*)d_in[18];
    const float* keys   = (const float*)d_in[19];
    const float* values = (const float*)d_in[20];

    char* W = (char*)d_ws;
    // region A: qkvb bf16 (9.44MB) -> sbuf fp32 (8.39MB)
    unsigned short* qkvb  = (unsigned short*)(W + 0);
    float*          sbuf  = (float*)(W + 0);
    // region B: attnf fp32 (6.29MB), alive LN1..LN2
    float*          attnf = (float*)(W + 9437184);
    // region C: ctxb bf16 (3.1MB) -> interb bf16 (12.58MB) -> wgt/ind
    unsigned short* ctxb  = (unsigned short*)(W + 15728640);
    unsigned short* interb= (unsigned short*)(W + 15728640);
    float*          wgt   = (float*)(W + 15728640);
    int*            ind   = (int*)(W + 16777216);
    // region D: xb/woout/dense (@28.3MB), attnb (@34.6MB), pqb (@37.7MB)
    unsigned short* xb    = (unsigned short*)(W + 28311552);
    float*          woout = (float*)(W + 28311552);
    float*          dense = (float*)(W + 28311552);
    unsigned short* attnb = (unsigned short*)(W + 34603008);
    unsigned short* pqb   = (unsigned short*)(W + 37748736);
    // keysb bf16 (0.5MB)
    unsigned short* keysb = (unsigned short*)(W + 46137344);
    // wt bf16 (26.74MB) -> valb bf16 (25.17MB) after last weight GEMM
    unsigned short* wt    = (unsigned short*)(W + 46661632);
    unsigned short* valb  = (unsigned short*)(W + 46661632);

    const dim3 blk(256);
    const size_t WOFF = 589824;   // 768*768

    // fused prep: weight transposes + x/keys bf16 conversion
    prep_kernel<<<8320, blk, 0, stream>>>(Wq, Wk, Wv, Wo, Wi, Wd, Wpq, wt,
                                          x, xb, keys, keysb);

    // merged QKV projection: [2048][2304] bf16  (TM=64 -> 576 blocks)
    gemm_lds<64, 1, 0, 0, 1><<<dim3(18, 32), blk, 0, stream>>>(
        xb, wt, bq, bk, bv, qkvb, nullptr, CT, 2304, CD, CD, 2304, 0);

    // flash attention (MFMA)
    attn_mfma<<<dim3(8, 12, 4), blk, 0, stream>>>(qkvb, ctxb);

    // output projection + LN1 (TM=32 -> 384 blocks)
    gemm_lds<32, 0, 0, 0, 0><<<dim3(6, 64), blk, 0, stream>>>(
        ctxb, wt + 3 * WOFF, bo, nullptr, nullptr, woout, nullptr, CT, CD, CD, CD, CD, 0);
    ln_kernel<<<CT, blk, 0, stream>>>(attnf, attnb, woout, CD, x, ln1_g, ln1_b);

    // FFN up (GELU, bf16 out)  (TM=64 -> 768 blocks, 3/CU)
    gemm_lds<64, 1, 1, 0, 0><<<dim3(24, 32), blk, 0, stream>>>(
        attnb, wt + 4 * WOFF, bi, nullptr, nullptr, interb, nullptr, CT, CFF, CD, CD, CFF, 0);

    // merged FFN down + PKM query proj (TM=64 -> 704 blocks, 2.75/CU)
    gemm_lds<64, 2, 0, 0, 2><<<dim3(22, 32), blk, 0, stream>>>(
        interb, wt + 4 * WOFF + 2359296, bd, bpq, nullptr, dense, pqb, CT, 2816, CFF, CFF, CD, 2048);

    // values -> bf16 (into dead wt region)
    cvt_bf16x4<<<2048, blk, 0, stream>>>(values, valb, (NK * NK * CD) / 4);

    // PKM scores: 8 batched GEMMs (TM=32 -> 512 blocks, 2/CU)
    gemm_lds<32, 0, 0, 1, 0><<<dim3(1, 64, 8), blk, 0, stream>>>(
        pqb, keysb, nullptr, nullptr, nullptr, sbuf, nullptr, CT, NK, HALF, 2048, PH * 2 * NK, 0);

    // fused two-stage top-k + softmax
    pkm_topk_kernel<<<CT * PH, dim3(128), 0, stream>>>(sbuf, wgt, ind);

    // fused gather + residual + LN2
    ln2_pkm_kernel<<<CT, blk, 0, stream>>>(dense, attnf, wgt, ind, valb,
                                           ln2_g, ln2_b, (float*)d_out);
}